// Round 2
// baseline (2234.749 us; speedup 1.0000x reference)
//
#include <hip/hip_runtime.h>

constexpr int NB = 2;
constexpr int NC = 48;
constexpr int NH = 256;
constexpr int NW = 256;
constexpr int NP = NH * NW;           // 65536
constexpr int NHEADS = 8;
constexpr int NCHD = 6;
constexpr int NHID = 96;

__device__ __forceinline__ float gelu_f(float v) {
  return 0.5f * v * (1.0f + erff(v * 0.70710678118654752f));
}

// ---------------- conv-descriptor branch ----------------
__global__ void k_conv_s2(const float* __restrict__ in, const float* __restrict__ w,
                          const float* __restrict__ bias, float* __restrict__ out,
                          int IH, int IW, int OH, int OW) {
  int idx = blockIdx.x * blockDim.x + threadIdx.x;
  int total = NB * NC * OH * OW;
  if (idx >= total) return;
  int ox = idx % OW;
  int t = idx / OW;
  int oy = t % OH; t /= OH;
  int oc = t % NC;
  int b = t / NC;
  const float* inb = in + (size_t)b * NC * IH * IW;
  const float* wr = w + (size_t)oc * NC * 9;
  float acc = bias[oc];
  for (int ky = 0; ky < 3; ++ky) {
    int iy = oy * 2 - 1 + ky;
    if ((unsigned)iy >= (unsigned)IH) continue;
    for (int kx = 0; kx < 3; ++kx) {
      int ix = ox * 2 - 1 + kx;
      if ((unsigned)ix >= (unsigned)IW) continue;
      const float* ip = inb + (size_t)iy * IW + ix;
      const float* wp = wr + ky * 3 + kx;
      #pragma unroll
      for (int ic = 0; ic < NC; ++ic)
        acc += ip[(size_t)ic * IH * IW] * wp[ic * 9];
    }
  }
  out[idx] = acc;
}

__global__ void k_lnpool(const float* __restrict__ in, const float* __restrict__ lw,
                         const float* __restrict__ lb, float* __restrict__ out,
                         int IH, int IW) {
  int OH = IH >> 1, OW = IW >> 1;
  int idx = blockIdx.x * blockDim.x + threadIdx.x;
  int total = NB * OH * OW;
  if (idx >= total) return;
  int ox = idx % OW;
  int t = idx / OW;
  int oy = t % OH;
  int b = t / OH;
  const float* inb = in + (size_t)b * NC * IH * IW;
  float mu[4], rs[4];
  #pragma unroll
  for (int q = 0; q < 4; ++q) {
    int iy = oy * 2 + (q >> 1), ix = ox * 2 + (q & 1);
    float s = 0.f, ss = 0.f;
    for (int c = 0; c < NC; ++c) {
      float v = inb[((size_t)c * IH + iy) * IW + ix];
      s += v; ss += v * v;
    }
    float m = s * (1.f / NC);
    mu[q] = m;
    rs[q] = rsqrtf(fmaxf(ss * (1.f / NC) - m * m, 0.f) + 1e-5f);
  }
  for (int c = 0; c < NC; ++c) {
    float best = 0.f;  // relu >= 0 so 0 == max of relu'd window
    float wv = lw[c], bv = lb[c];
    #pragma unroll
    for (int q = 0; q < 4; ++q) {
      int iy = oy * 2 + (q >> 1), ix = ox * 2 + (q & 1);
      float v = inb[((size_t)c * IH + iy) * IW + ix];
      v = (v - mu[q]) * rs[q] * wv + bv;
      best = fmaxf(best, fmaxf(v, 0.f));
    }
    out[((size_t)(b * NC + c) * OH + oy) * OW + ox] = best;
  }
}

__global__ void k_head(const float* __restrict__ p3, const float* __restrict__ l2qw,
                       const float* __restrict__ l2qb, float* __restrict__ q0m) {
  __shared__ float xd[NC], q0[NC];
  int b = blockIdx.x, t = threadIdx.x;
  if (t < NC) {
    float s = 0.f;
    for (int i = 0; i < 16; ++i) s += p3[(b * NC + t) * 16 + i];
    xd[t] = gelu_f(s * (1.f / 16.f));
  }
  __syncthreads();
  if (t < NC) {
    float a = l2qb[t];
    for (int c = 0; c < NC; ++c) a += xd[c] * l2qw[t * NC + c];
    q0[t] = a;
  }
  __syncthreads();
  if (t < NHEADS * NCHD * NCHD) {
    int h = t / 36, r = t % 36, c = r / 6, d = r % 6;
    q0m[b * 288 + t] = q0[h * 6 + c] * q0[h * 6 + d];
  }
}

// ---------------- LN stats over channels ----------------
__global__ void k_lnstats(const float* __restrict__ x, float2* __restrict__ stats) {
  int idx = blockIdx.x * blockDim.x + threadIdx.x;  // b*NP + p
  if (idx >= NB * NP) return;
  int b = idx / NP, p = idx % NP;
  const float* xb = x + (size_t)b * NC * NP + p;
  float s = 0.f, ss = 0.f;
  #pragma unroll
  for (int c = 0; c < NC; ++c) { float v = xb[(size_t)c * NP]; s += v; ss += v * v; }
  float mu = s * (1.f / NC);
  float var = fmaxf(ss * (1.f / NC) - mu * mu, 0.f);
  stats[idx] = make_float2(mu, rsqrtf(var + 1e-5f));
}

// ---------------- channel-mix (1x1 conv) with fused LN on input ----------------
__global__ void k_chmix_ln(const float* __restrict__ x, const float2* __restrict__ stats,
                           const float* __restrict__ lnw, const float* __restrict__ lnb,
                           const float* __restrict__ w, float* __restrict__ out, int nout) {
  int idx = blockIdx.x * blockDim.x + threadIdx.x;
  if (idx >= NB * NP) return;
  int b = idx / NP, p = idx % NP;
  float2 st = stats[idx];
  const float* xb = x + (size_t)b * NC * NP + p;
  float xr[NC];
  #pragma unroll
  for (int c = 0; c < NC; ++c)
    xr[c] = (xb[(size_t)c * NP] - st.x) * st.y * lnw[c] + lnb[c];
  float* ob = out + (size_t)b * nout * NP + p;
  for (int o = 0; o < nout; ++o) {
    const float* wr = w + o * NC;
    float a = 0.f;
    #pragma unroll
    for (int c = 0; c < NC; ++c) a += wr[c] * xr[c];
    ob[(size_t)o * NP] = a;
  }
}

// ---------------- depthwise 3x3 on 144 channels ----------------
__global__ void k_dw144(const float* __restrict__ in, const float* __restrict__ w9,
                        float* __restrict__ out) {
  int idx = blockIdx.x * blockDim.x + threadIdx.x;
  if (idx >= NB * 144 * NP) return;
  int p = idx % NP;
  int ch = (idx / NP) % 144;
  int y = p >> 8, x = p & 255;
  const float* ib = in + (size_t)(idx - p);  // (b,ch)-plane base
  const float* wp = w9 + ch * 9;
  float a = 0.f;
  #pragma unroll
  for (int ky = 0; ky < 3; ++ky) {
    int iy = y + ky - 1;
    if ((unsigned)iy >= (unsigned)NH) continue;
    #pragma unroll
    for (int kx = 0; kx < 3; ++kx) {
      int ix = x + kx - 1;
      if ((unsigned)ix >= (unsigned)NW) continue;
      a += ib[iy * NW + ix] * wp[ky * 3 + kx];
    }
  }
  out[idx] = a;
}

// ---------------- per-channel L2 norms of q,k ----------------
__global__ void k_norms(const float* __restrict__ qkvd, float* __restrict__ norms) {
  int bc = blockIdx.x;  // b*96 + ch
  int b = bc / 96, ch = bc % 96;
  const float* pch = qkvd + (size_t)(b * 144 + ch) * NP;
  float ss = 0.f;
  for (int i = threadIdx.x; i < NP; i += 256) { float v = pch[i]; ss += v * v; }
  int lane = threadIdx.x & 63, wid = threadIdx.x >> 6;
  #pragma unroll
  for (int off = 32; off; off >>= 1) ss += __shfl_down(ss, off, 64);
  __shared__ float sr[4];
  if (lane == 0) sr[wid] = ss;
  __syncthreads();
  if (threadIdx.x == 0) norms[bc] = sqrtf(sr[0] + sr[1] + sr[2] + sr[3]);
}

// ---------------- per-head 6x6 Gram matrix (segmented partials) ----------------
__global__ void k_gram(const float* __restrict__ qkvd, float* __restrict__ spart) {
  int gid = blockIdx.x;  // b*64 + h*8 + seg
  int seg = gid & 7, h = (gid >> 3) & 7, b = gid >> 6;
  const float* qb = qkvd + (size_t)(b * 144 + h * 6) * NP;
  const float* kb = qkvd + (size_t)(b * 144 + 48 + h * 6) * NP;
  float acc[36];
  #pragma unroll
  for (int j = 0; j < 36; ++j) acc[j] = 0.f;
  for (int i = seg * 8192 + threadIdx.x; i < (seg + 1) * 8192; i += 256) {
    float qv[6], kv[6];
    #pragma unroll
    for (int c = 0; c < 6; ++c) { qv[c] = qb[(size_t)c * NP + i]; kv[c] = kb[(size_t)c * NP + i]; }
    #pragma unroll
    for (int c = 0; c < 6; ++c)
      #pragma unroll
      for (int d = 0; d < 6; ++d) acc[c * 6 + d] += qv[c] * kv[d];
  }
  int lane = threadIdx.x & 63, wid = threadIdx.x >> 6;
  __shared__ float sr[4 * 36];
  #pragma unroll
  for (int j = 0; j < 36; ++j) {
    float v = acc[j];
    #pragma unroll
    for (int off = 32; off; off >>= 1) v += __shfl_down(v, off, 64);
    if (lane == 0) sr[wid * 36 + j] = v;
  }
  __syncthreads();
  if (threadIdx.x < 36)
    spart[gid * 36 + threadIdx.x] =
        sr[threadIdx.x] + sr[36 + threadIdx.x] + sr[72 + threadIdx.x] + sr[108 + threadIdx.x];
}

// ---------------- attention softmax (tiny) ----------------
__global__ void k_attn(const float* __restrict__ spart, const float* __restrict__ norms,
                       const float* __restrict__ temp, const float* __restrict__ q0m,
                       float* __restrict__ A) {
  int b = blockIdx.x, t = threadIdx.x;
  if (t >= 48) return;
  int h = t / 6, c = t % 6;
  float nq = fmaxf(norms[b * 96 + h * 6 + c], 1e-12f);
  float tm = temp[h];
  float lg[6];
  #pragma unroll
  for (int d = 0; d < 6; ++d) {
    float s = 0.f;
    for (int seg = 0; seg < 8; ++seg)
      s += spart[(size_t)((b * 64 + h * 8 + seg) * 36) + c * 6 + d];
    float nk = fmaxf(norms[b * 96 + 48 + h * 6 + d], 1e-12f);
    lg[d] = (s / (nq * nk)) * tm * q0m[b * 288 + h * 36 + c * 6 + d];
  }
  float m = lg[0];
  #pragma unroll
  for (int d = 1; d < 6; ++d) m = fmaxf(m, lg[d]);
  float sum = 0.f;
  #pragma unroll
  for (int d = 0; d < 6; ++d) { lg[d] = expf(lg[d] - m); sum += lg[d]; }
  float inv = 1.f / sum;
  #pragma unroll
  for (int d = 0; d < 6; ++d) A[b * 288 + h * 36 + c * 6 + d] = lg[d] * inv;
}

// ---------------- fc mix over the raw-reshape scramble ----------------
// flat f-index within batch: f = p*144 + g*6 + c2  == linear qkvd memory.
__global__ __launch_bounds__(384) void k_fc(const float* __restrict__ qkvd,
                                            const float* __restrict__ fcw,
                                            const float* __restrict__ fcb,
                                            float* __restrict__ fconv) {
  __shared__ float sin_[9216];   // 64 pixels * 144
  __shared__ float sout[3456];   // 54 ch * 64 pixels
  int blk = blockIdx.x;
  int b = blk >> 10, p0 = (blk & 1023) << 6;
  const float* src = qkvd + (size_t)b * 144 * NP + (size_t)p0 * 144;
  for (int i = threadIdx.x; i < 9216; i += 384) sin_[i] = src[i];
  __syncthreads();
  int pl = threadIdx.x / 6, c2 = threadIdx.x % 6;
  float xv[24];
  #pragma unroll
  for (int g = 0; g < 24; ++g) xv[g] = sin_[pl * 144 + g * 6 + c2];
  #pragma unroll
  for (int o = 0; o < 9; ++o) {
    float a = fcb[o];
    #pragma unroll
    for (int g = 0; g < 24; ++g) a += fcw[o * 24 + g] * xv[g];
    sout[(c2 * 9 + o) * 64 + pl] = a;
  }
  __syncthreads();
  for (int i = threadIdx.x; i < 3456; i += 384) {
    int ch = i >> 6, pl2 = i & 63;
    fconv[(size_t)(b * 54 + ch) * NP + p0 + pl2] = sout[i];
  }
}

// ---------------- grouped dep conv 54->48, groups=6 ----------------
__global__ void k_depconv(const float* __restrict__ fconv, const float* __restrict__ dw,
                          const float* __restrict__ db, float* __restrict__ outconv) {
  int idx = blockIdx.x * blockDim.x + threadIdx.x;
  if (idx >= NB * NC * NP) return;
  int p = idx % NP;
  int oc = (idx / NP) % NC;
  int b = idx / (NC * NP);
  int g = oc >> 3;
  int y = p >> 8, x = p & 255;
  const float* fb = fconv + (size_t)(b * 54 + g * 9) * NP;
  const float* wp = dw + oc * 81;
  float a = db[oc];
  for (int j = 0; j < 9; ++j) {
    const float* fj = fb + (size_t)j * NP;
    const float* wj = wp + j * 9;
    #pragma unroll
    for (int ky = 0; ky < 3; ++ky) {
      int iy = y + ky - 1;
      if ((unsigned)iy >= (unsigned)NH) continue;
      #pragma unroll
      for (int kx = 0; kx < 3; ++kx) {
        int ix = x + kx - 1;
        if ((unsigned)ix >= (unsigned)NW) continue;
        a += fj[iy * NW + ix] * wj[ky * 3 + kx];
      }
    }
  }
  outconv[idx] = a;
}

// ---------------- fused attn@V + proj + out_conv + residual ----------------
__global__ void k_proj(const float* __restrict__ qkvd, const float* __restrict__ A,
                       const float* __restrict__ projw, const float* __restrict__ x,
                       const float* __restrict__ outconv, float* __restrict__ x1) {
  int idx = blockIdx.x * blockDim.x + threadIdx.x;  // exact NB*NP
  int b = idx / NP, p = idx % NP;
  __shared__ float sA[288];
  for (int i = threadIdx.x; i < 288; i += 256) sA[i] = A[b * 288 + i];
  __syncthreads();
  float v[48];
  const float* vb = qkvd + (size_t)(b * 144 + 96) * NP + p;
  #pragma unroll
  for (int j = 0; j < 48; ++j) v[j] = vb[(size_t)j * NP];
  float av[48];
  #pragma unroll
  for (int h = 0; h < 8; ++h)
    #pragma unroll
    for (int c = 0; c < 6; ++c) {
      float a = 0.f;
      #pragma unroll
      for (int d = 0; d < 6; ++d) a += sA[h * 36 + c * 6 + d] * v[h * 6 + d];
      av[h * 6 + c] = a;
    }
  const float* xb = x + (size_t)b * NC * NP + p;
  const float* ob = outconv + (size_t)b * NC * NP + p;
  float* x1b = x1 + (size_t)b * NC * NP + p;
  for (int o = 0; o < 48; ++o) {
    const float* wr = projw + o * 48;
    float a = 0.f;
    #pragma unroll
    for (int c = 0; c < 48; ++c) a += wr[c] * av[c];
    x1b[(size_t)o * NP] = xb[(size_t)o * NP] + a + ob[(size_t)o * NP];
  }
}

// ---------------- FF: 3-dilation depthwise + gelu gate ----------------
__global__ void k_ffdw(const float* __restrict__ y, const float* __restrict__ w1,
                       const float* __restrict__ w2, const float* __restrict__ w3,
                       float* __restrict__ z) {
  int idx = blockIdx.x * blockDim.x + threadIdx.x;
  if (idx >= NB * NHID * NP) return;
  int p = idx % NP;
  int ch = (idx / NP) % NHID;
  int b = idx / (NHID * NP);
  int yy = p >> 8, xx = p & 255;
  const float* y1 = y + (size_t)(b * 288 + ch) * NP;
  const float* y2 = y1 + (size_t)NHID * NP;
  const float* y3 = y2 + (size_t)NHID * NP;
  const float* wp1 = w1 + ch * 9;
  const float* wp2 = w2 + ch * 9;
  const float* wp3 = w3 + ch * 9;
  float c1 = 0.f, c2 = 0.f, c3 = 0.f;
  #pragma unroll
  for (int ky = 0; ky < 3; ++ky)
    #pragma unroll
    for (int kx = 0; kx < 3; ++kx) {
      int wi = ky * 3 + kx;
      { int iy = yy + ky - 1, ix = xx + kx - 1;
        if ((unsigned)iy < (unsigned)NH && (unsigned)ix < (unsigned)NW)
          c1 += y1[iy * NW + ix] * wp1[wi]; }
      { int iy = yy + 2 * (ky - 1), ix = xx + 2 * (kx - 1);
        if ((unsigned)iy < (unsigned)NH && (unsigned)ix < (unsigned)NW)
          c2 += y2[iy * NW + ix] * wp2[wi]; }
      { int iy = yy + 3 * (ky - 1), ix = xx + 3 * (kx - 1);
        if ((unsigned)iy < (unsigned)NH && (unsigned)ix < (unsigned)NW)
          c3 += y3[iy * NW + ix] * wp3[wi]; }
    }
  z[idx] = gelu_f(c1) * c2 * c3;
}

// ---------------- pout + residual -> d_out ----------------
__global__ void k_pout(const float* __restrict__ z, const float* __restrict__ poutw,
                       const float* __restrict__ x1, float* __restrict__ outp) {
  int idx = blockIdx.x * blockDim.x + threadIdx.x;  // exact NB*NP
  int b = idx / NP, p = idx % NP;
  float zr[96];
  const float* zb = z + (size_t)b * NHID * NP + p;
  #pragma unroll
  for (int j = 0; j < 96; ++j) zr[j] = zb[(size_t)j * NP];
  const float* x1b = x1 + (size_t)b * NC * NP + p;
  float* ob = outp + (size_t)b * NC * NP + p;
  for (int o = 0; o < 48; ++o) {
    const float* wr = poutw + o * 96;
    float a = 0.f;
    #pragma unroll
    for (int j = 0; j < 96; ++j) a += wr[j] * zr[j];
    ob[(size_t)o * NP] = x1b[(size_t)o * NP] + a;
  }
}

// ---------------- workspace layout (floats) ----------------
constexpr size_t SZ_QKV = (size_t)NB * 144 * NP;       // 18,874,368
constexpr size_t SZ_CHW = (size_t)NB * NC * NP;        // 6,291,456
constexpr size_t OFF_QKV0 = 0;
constexpr size_t OFF_QKVD = OFF_QKV0 + SZ_QKV;
constexpr size_t OFF_FCONV = OFF_QKVD + SZ_QKV;        // y reuses [0, OFF_FCONV)
constexpr size_t SZ_FCONV = (size_t)NB * 54 * NP;
constexpr size_t OFF_OUTCONV = OFF_FCONV + SZ_FCONV;   // z reuses [OFF_FCONV, +NB*96*NP)
constexpr size_t OFF_X1 = OFF_OUTCONV + SZ_CHW;
constexpr size_t OFF_STATS = OFF_X1 + SZ_CHW;
constexpr size_t OFF_T1 = OFF_STATS + (size_t)NB * NP * 2;
constexpr size_t OFF_P1 = OFF_T1 + (size_t)NB * NC * 128 * 128;
constexpr size_t OFF_T2 = OFF_P1 + (size_t)NB * NC * 64 * 64;
constexpr size_t OFF_P2 = OFF_T2 + (size_t)NB * NC * 32 * 32;
constexpr size_t OFF_T3 = OFF_P2 + (size_t)NB * NC * 16 * 16;
constexpr size_t OFF_P3 = OFF_T3 + (size_t)NB * NC * 8 * 8;
constexpr size_t OFF_Q0M = OFF_P3 + (size_t)NB * NC * 4 * 4;
constexpr size_t OFF_NORMS = OFF_Q0M + 576;
constexpr size_t OFF_SPART = OFF_NORMS + 192;
constexpr size_t OFF_A = OFF_SPART + (size_t)NB * 64 * 36;

extern "C" void kernel_launch(void* const* d_in, const int* in_sizes, int n_in,
                              void* d_out, int out_size, void* d_ws, size_t ws_size,
                              hipStream_t stream) {
  const float* x     = (const float*)d_in[0];
  const float* ln1w  = (const float*)d_in[1];
  const float* ln1b  = (const float*)d_in[2];
  const float* qkvw  = (const float*)d_in[3];
  const float* qkvdw = (const float*)d_in[4];
  const float* projw = (const float*)d_in[5];
  const float* fcw   = (const float*)d_in[6];
  const float* fcb   = (const float*)d_in[7];
  const float* depw  = (const float*)d_in[8];
  const float* depb  = (const float*)d_in[9];
  const float* l2qw  = (const float*)d_in[10];
  const float* l2qb  = (const float*)d_in[11];
  const float* temp  = (const float*)d_in[12];
  const float* ln2w  = (const float*)d_in[13];
  const float* ln2b  = (const float*)d_in[14];
  const float* pinw  = (const float*)d_in[15];
  const float* dw1   = (const float*)d_in[16];
  const float* dw2   = (const float*)d_in[17];
  const float* dw3   = (const float*)d_in[18];
  const float* poutw = (const float*)d_in[19];
  const float* cvw0  = (const float*)d_in[20];
  const float* cvb0  = (const float*)d_in[21];
  const float* clw0  = (const float*)d_in[22];
  const float* clb0  = (const float*)d_in[23];
  const float* cvw1  = (const float*)d_in[24];
  const float* cvb1  = (const float*)d_in[25];
  const float* clw1  = (const float*)d_in[26];
  const float* clb1  = (const float*)d_in[27];
  const float* cvw2  = (const float*)d_in[28];
  const float* cvb2  = (const float*)d_in[29];
  const float* clw2  = (const float*)d_in[30];
  const float* clb2  = (const float*)d_in[31];

  float* ws = (float*)d_ws;
  float* qkv0 = ws + OFF_QKV0;
  float* qkvd = ws + OFF_QKVD;
  float* fconv = ws + OFF_FCONV;
  float* outconv = ws + OFF_OUTCONV;
  float* x1 = ws + OFF_X1;
  float2* stats = (float2*)(ws + OFF_STATS);
  float* t1 = ws + OFF_T1;
  float* p1 = ws + OFF_P1;
  float* t2 = ws + OFF_T2;
  float* p2 = ws + OFF_P2;
  float* t3 = ws + OFF_T3;
  float* p3 = ws + OFF_P3;
  float* q0m = ws + OFF_Q0M;
  float* norms = ws + OFF_NORMS;
  float* spart = ws + OFF_SPART;
  float* A = ws + OFF_A;
  float* ybuf = ws + OFF_QKV0;   // reuse qkv0+qkvd (exactly NB*288*NP)
  float* zbuf = ws + OFF_FCONV;  // reuse fconv+outconv (NB*96*NP fits)

  // conv-descriptor branch
  k_conv_s2<<<6144, 256, 0, stream>>>(x, cvw0, cvb0, t1, 256, 256, 128, 128);
  k_lnpool<<<32, 256, 0, stream>>>(t1, clw0, clb0, p1, 128, 128);
  k_conv_s2<<<384, 256, 0, stream>>>(p1, cvw1, cvb1, t2, 64, 64, 32, 32);
  k_lnpool<<<2, 256, 0, stream>>>(t2, clw1, clb1, p2, 32, 32);
  k_conv_s2<<<24, 256, 0, stream>>>(p2, cvw2, cvb2, t3, 16, 16, 8, 8);
  k_lnpool<<<1, 256, 0, stream>>>(t3, clw2, clb2, p3, 8, 8);
  k_head<<<2, 320, 0, stream>>>(p3, l2qw, l2qb, q0m);

  // attention
  k_lnstats<<<512, 256, 0, stream>>>(x, stats);
  k_chmix_ln<<<512, 256, 0, stream>>>(x, stats, ln1w, ln1b, qkvw, qkv0, 144);
  k_dw144<<<73728, 256, 0, stream>>>(qkv0, qkvdw, qkvd);
  k_norms<<<192, 256, 0, stream>>>(qkvd, norms);
  k_gram<<<128, 256, 0, stream>>>(qkvd, spart);
  k_attn<<<2, 64, 0, stream>>>(spart, norms, temp, q0m, A);
  k_fc<<<2048, 384, 0, stream>>>(qkvd, fcw, fcb, fconv);
  k_depconv<<<24576, 256, 0, stream>>>(fconv, depw, depb, outconv);
  k_proj<<<512, 256, 0, stream>>>(qkvd, A, projw, x, outconv, x1);

  // feedforward
  k_lnstats<<<512, 256, 0, stream>>>(x1, stats);
  k_chmix_ln<<<512, 256, 0, stream>>>(x1, stats, ln2w, ln2b, pinw, ybuf, 288);
  k_ffdw<<<49152, 256, 0, stream>>>(ybuf, dw1, dw2, dw3, zbuf);
  k_pout<<<512, 256, 0, stream>>>(zbuf, poutw, x1, (float*)d_out);
}

// Round 3
// 1523.902 us; speedup vs baseline: 1.4665x; 1.4665x over previous
//
#include <hip/hip_runtime.h>

constexpr int NB = 2;
constexpr int NC = 48;
constexpr int NH = 256;
constexpr int NW = 256;
constexpr int NP = NH * NW;           // 65536
constexpr int NHEADS = 8;
constexpr int NCHD = 6;
constexpr int NHID = 96;

__device__ __forceinline__ float gelu_f(float v) {
  return 0.5f * v * (1.0f + erff(v * 0.70710678118654752f));
}

// ---------------- conv-descriptor branch: LDS-tiled stride-2 3x3 conv ----------------
// Each block: 8x8 output tile, ALL 48 output channels, one batch.
// LDS stages 48ch x 17x17 input patch (row stride 20 -> <=4-way bank aliasing).
// grid = NB * (OH/8) * (OW/8), block = 256 (4 waves x 12 oc each; lane = pixel).
__global__ __launch_bounds__(256) void k_conv_s2_tile(const float* __restrict__ in,
                                                      const float* __restrict__ w,
                                                      const float* __restrict__ bias,
                                                      float* __restrict__ out,
                                                      int IH, int IW, int OH, int OW) {
  __shared__ float lds[48 * 340];  // 340 = 17 rows * 20 (padded) ... 65280 B
  int tilesX = OW >> 3;
  int tilesY = OH >> 3;
  int blk = blockIdx.x;
  int tx = blk % tilesX;
  int t = blk / tilesX;
  int ty = t % tilesY;
  int b = t / tilesY;
  int oy0 = ty * 8, ox0 = tx * 8;
  int iy0 = oy0 * 2 - 1, ix0 = ox0 * 2 - 1;
  const float* inb = in + (size_t)b * NC * IH * IW;

  for (int i = threadIdx.x; i < 48 * 17 * 20; i += 256) {
    int cc = i % 20;
    int rr = (i / 20) % 17;
    int ic = i / 340;
    float v = 0.f;
    int iy = iy0 + rr, ix = ix0 + cc;
    if (cc < 17 && (unsigned)iy < (unsigned)IH && (unsigned)ix < (unsigned)IW)
      v = inb[((size_t)ic * IH + iy) * IW + ix];
    lds[ic * 340 + rr * 20 + cc] = v;
  }
  __syncthreads();

  int lane = threadIdx.x & 63;
  int oy = lane >> 3, ox = lane & 7;
  int ocb = __builtin_amdgcn_readfirstlane((threadIdx.x >> 6) * 12);
  float acc[12];
  #pragma unroll
  for (int j = 0; j < 12; ++j) acc[j] = bias[ocb + j];
  int pbase = oy * 40 + ox * 2;

  for (int ic = 0; ic < 48; ++ic) {
    float in9[9];
    const float* lp = lds + ic * 340 + pbase;
    #pragma unroll
    for (int ky = 0; ky < 3; ++ky)
      #pragma unroll
      for (int kx = 0; kx < 3; ++kx)
        in9[ky * 3 + kx] = lp[ky * 20 + kx];
    const float* wpc = w + (size_t)(ocb * 48 + ic) * 9;
    #pragma unroll
    for (int j = 0; j < 12; ++j) {
      const float* wp = wpc + (size_t)j * 48 * 9;
      float a = acc[j];
      #pragma unroll
      for (int k = 0; k < 9; ++k) a = fmaf(wp[k], in9[k], a);
      acc[j] = a;
    }
  }

  float* ob = out + (size_t)b * NC * OH * OW;
  #pragma unroll
  for (int j = 0; j < 12; ++j)
    ob[((size_t)(ocb + j) * OH + oy0 + oy) * OW + ox0 + ox] = acc[j];
}

__global__ void k_lnpool(const float* __restrict__ in, const float* __restrict__ lw,
                         const float* __restrict__ lb, float* __restrict__ out,
                         int IH, int IW) {
  int OH = IH >> 1, OW = IW >> 1;
  int idx = blockIdx.x * blockDim.x + threadIdx.x;
  int total = NB * OH * OW;
  if (idx >= total) return;
  int ox = idx % OW;
  int t = idx / OW;
  int oy = t % OH;
  int b = t / OH;
  const float* inb = in + (size_t)b * NC * IH * IW;
  float mu[4], rs[4];
  #pragma unroll
  for (int q = 0; q < 4; ++q) {
    int iy = oy * 2 + (q >> 1), ix = ox * 2 + (q & 1);
    float s = 0.f, ss = 0.f;
    for (int c = 0; c < NC; ++c) {
      float v = inb[((size_t)c * IH + iy) * IW + ix];
      s += v; ss += v * v;
    }
    float m = s * (1.f / NC);
    mu[q] = m;
    rs[q] = rsqrtf(fmaxf(ss * (1.f / NC) - m * m, 0.f) + 1e-5f);
  }
  for (int c = 0; c < NC; ++c) {
    float best = 0.f;  // relu >= 0 so 0 == max of relu'd window
    float wv = lw[c], bv = lb[c];
    #pragma unroll
    for (int q = 0; q < 4; ++q) {
      int iy = oy * 2 + (q >> 1), ix = ox * 2 + (q & 1);
      float v = inb[((size_t)c * IH + iy) * IW + ix];
      v = (v - mu[q]) * rs[q] * wv + bv;
      best = fmaxf(best, fmaxf(v, 0.f));
    }
    out[((size_t)(b * NC + c) * OH + oy) * OW + ox] = best;
  }
}

__global__ void k_head(const float* __restrict__ p3, const float* __restrict__ l2qw,
                       const float* __restrict__ l2qb, float* __restrict__ q0m) {
  __shared__ float xd[NC], q0[NC];
  int b = blockIdx.x, t = threadIdx.x;
  if (t < NC) {
    float s = 0.f;
    for (int i = 0; i < 16; ++i) s += p3[(b * NC + t) * 16 + i];
    xd[t] = gelu_f(s * (1.f / 16.f));
  }
  __syncthreads();
  if (t < NC) {
    float a = l2qb[t];
    for (int c = 0; c < NC; ++c) a += xd[c] * l2qw[t * NC + c];
    q0[t] = a;
  }
  __syncthreads();
  if (t < NHEADS * NCHD * NCHD) {
    int h = t / 36, r = t % 36, c = r / 6, d = r % 6;
    q0m[b * 288 + t] = q0[h * 6 + c] * q0[h * 6 + d];
  }
}

// ---------------- LN stats over channels ----------------
__global__ void k_lnstats(const float* __restrict__ x, float2* __restrict__ stats) {
  int idx = blockIdx.x * blockDim.x + threadIdx.x;  // b*NP + p
  if (idx >= NB * NP) return;
  int b = idx / NP, p = idx % NP;
  const float* xb = x + (size_t)b * NC * NP + p;
  float s = 0.f, ss = 0.f;
  #pragma unroll
  for (int c = 0; c < NC; ++c) { float v = xb[(size_t)c * NP]; s += v; ss += v * v; }
  float mu = s * (1.f / NC);
  float var = fmaxf(ss * (1.f / NC) - mu * mu, 0.f);
  stats[idx] = make_float2(mu, rsqrtf(var + 1e-5f));
}

// ---------------- channel-mix (1x1 conv) with fused LN on input ----------------
__global__ void k_chmix_ln(const float* __restrict__ x, const float2* __restrict__ stats,
                           const float* __restrict__ lnw, const float* __restrict__ lnb,
                           const float* __restrict__ w, float* __restrict__ out, int nout) {
  int idx = blockIdx.x * blockDim.x + threadIdx.x;
  if (idx >= NB * NP) return;
  int b = idx / NP, p = idx % NP;
  float2 st = stats[idx];
  const float* xb = x + (size_t)b * NC * NP + p;
  float xr[NC];
  #pragma unroll
  for (int c = 0; c < NC; ++c)
    xr[c] = (xb[(size_t)c * NP] - st.x) * st.y * lnw[c] + lnb[c];
  float* ob = out + (size_t)b * nout * NP + p;
  for (int o = 0; o < nout; ++o) {
    const float* wr = w + o * NC;
    float a = 0.f;
    #pragma unroll
    for (int c = 0; c < NC; ++c) a += wr[c] * xr[c];
    ob[(size_t)o * NP] = a;
  }
}

// ---------------- depthwise 3x3 on 144 channels ----------------
__global__ void k_dw144(const float* __restrict__ in, const float* __restrict__ w9,
                        float* __restrict__ out) {
  int idx = blockIdx.x * blockDim.x + threadIdx.x;
  if (idx >= NB * 144 * NP) return;
  int p = idx % NP;
  int ch = (idx / NP) % 144;
  int y = p >> 8, x = p & 255;
  const float* ib = in + (size_t)(idx - p);  // (b,ch)-plane base
  const float* wp = w9 + ch * 9;
  float a = 0.f;
  #pragma unroll
  for (int ky = 0; ky < 3; ++ky) {
    int iy = y + ky - 1;
    if ((unsigned)iy >= (unsigned)NH) continue;
    #pragma unroll
    for (int kx = 0; kx < 3; ++kx) {
      int ix = x + kx - 1;
      if ((unsigned)ix >= (unsigned)NW) continue;
      a += ib[iy * NW + ix] * wp[ky * 3 + kx];
    }
  }
  out[idx] = a;
}

// ---------------- per-channel L2 norms of q,k ----------------
__global__ void k_norms(const float* __restrict__ qkvd, float* __restrict__ norms) {
  int bc = blockIdx.x;  // b*96 + ch
  int b = bc / 96, ch = bc % 96;
  const float* pch = qkvd + (size_t)(b * 144 + ch) * NP;
  float ss = 0.f;
  for (int i = threadIdx.x; i < NP; i += 256) { float v = pch[i]; ss += v * v; }
  int lane = threadIdx.x & 63, wid = threadIdx.x >> 6;
  #pragma unroll
  for (int off = 32; off; off >>= 1) ss += __shfl_down(ss, off, 64);
  __shared__ float sr[4];
  if (lane == 0) sr[wid] = ss;
  __syncthreads();
  if (threadIdx.x == 0) norms[bc] = sqrtf(sr[0] + sr[1] + sr[2] + sr[3]);
}

// ---------------- per-head 6x6 Gram matrix (segmented partials) ----------------
__global__ void k_gram(const float* __restrict__ qkvd, float* __restrict__ spart) {
  int gid = blockIdx.x;  // b*64 + h*8 + seg
  int seg = gid & 7, h = (gid >> 3) & 7, b = gid >> 6;
  const float* qb = qkvd + (size_t)(b * 144 + h * 6) * NP;
  const float* kb = qkvd + (size_t)(b * 144 + 48 + h * 6) * NP;
  float acc[36];
  #pragma unroll
  for (int j = 0; j < 36; ++j) acc[j] = 0.f;
  for (int i = seg * 8192 + threadIdx.x; i < (seg + 1) * 8192; i += 256) {
    float qv[6], kv[6];
    #pragma unroll
    for (int c = 0; c < 6; ++c) { qv[c] = qb[(size_t)c * NP + i]; kv[c] = kb[(size_t)c * NP + i]; }
    #pragma unroll
    for (int c = 0; c < 6; ++c)
      #pragma unroll
      for (int d = 0; d < 6; ++d) acc[c * 6 + d] += qv[c] * kv[d];
  }
  int lane = threadIdx.x & 63, wid = threadIdx.x >> 6;
  __shared__ float sr[4 * 36];
  #pragma unroll
  for (int j = 0; j < 36; ++j) {
    float v = acc[j];
    #pragma unroll
    for (int off = 32; off; off >>= 1) v += __shfl_down(v, off, 64);
    if (lane == 0) sr[wid * 36 + j] = v;
  }
  __syncthreads();
  if (threadIdx.x < 36)
    spart[gid * 36 + threadIdx.x] =
        sr[threadIdx.x] + sr[36 + threadIdx.x] + sr[72 + threadIdx.x] + sr[108 + threadIdx.x];
}

// ---------------- attention softmax (tiny) ----------------
__global__ void k_attn(const float* __restrict__ spart, const float* __restrict__ norms,
                       const float* __restrict__ temp, const float* __restrict__ q0m,
                       float* __restrict__ A) {
  int b = blockIdx.x, t = threadIdx.x;
  if (t >= 48) return;
  int h = t / 6, c = t % 6;
  float nq = fmaxf(norms[b * 96 + h * 6 + c], 1e-12f);
  float tm = temp[h];
  float lg[6];
  #pragma unroll
  for (int d = 0; d < 6; ++d) {
    float s = 0.f;
    for (int seg = 0; seg < 8; ++seg)
      s += spart[(size_t)((b * 64 + h * 8 + seg) * 36) + c * 6 + d];
    float nk = fmaxf(norms[b * 96 + 48 + h * 6 + d], 1e-12f);
    lg[d] = (s / (nq * nk)) * tm * q0m[b * 288 + h * 36 + c * 6 + d];
  }
  float m = lg[0];
  #pragma unroll
  for (int d = 1; d < 6; ++d) m = fmaxf(m, lg[d]);
  float sum = 0.f;
  #pragma unroll
  for (int d = 0; d < 6; ++d) { lg[d] = expf(lg[d] - m); sum += lg[d]; }
  float inv = 1.f / sum;
  #pragma unroll
  for (int d = 0; d < 6; ++d) A[b * 288 + h * 36 + c * 6 + d] = lg[d] * inv;
}

// ---------------- fc mix over the raw-reshape scramble ----------------
// flat f-index within batch: f = p*144 + g*6 + c2  == linear qkvd memory.
__global__ __launch_bounds__(384) void k_fc(const float* __restrict__ qkvd,
                                            const float* __restrict__ fcw,
                                            const float* __restrict__ fcb,
                                            float* __restrict__ fconv) {
  __shared__ float sin_[9216];   // 64 pixels * 144
  __shared__ float sout[3456];   // 54 ch * 64 pixels
  int blk = blockIdx.x;
  int b = blk >> 10, p0 = (blk & 1023) << 6;
  const float* src = qkvd + (size_t)b * 144 * NP + (size_t)p0 * 144;
  for (int i = threadIdx.x; i < 9216; i += 384) sin_[i] = src[i];
  __syncthreads();
  int pl = threadIdx.x / 6, c2 = threadIdx.x % 6;
  float xv[24];
  #pragma unroll
  for (int g = 0; g < 24; ++g) xv[g] = sin_[pl * 144 + g * 6 + c2];
  #pragma unroll
  for (int o = 0; o < 9; ++o) {
    float a = fcb[o];
    #pragma unroll
    for (int g = 0; g < 24; ++g) a += fcw[o * 24 + g] * xv[g];
    sout[(c2 * 9 + o) * 64 + pl] = a;
  }
  __syncthreads();
  for (int i = threadIdx.x; i < 3456; i += 384) {
    int ch = i >> 6, pl2 = i & 63;
    fconv[(size_t)(b * 54 + ch) * NP + p0 + pl2] = sout[i];
  }
}

// ---------------- grouped dep conv 54->48, groups=6 ----------------
__global__ void k_depconv(const float* __restrict__ fconv, const float* __restrict__ dw,
                          const float* __restrict__ db, float* __restrict__ outconv) {
  int idx = blockIdx.x * blockDim.x + threadIdx.x;
  if (idx >= NB * NC * NP) return;
  int p = idx % NP;
  int oc = (idx / NP) % NC;
  int b = idx / (NC * NP);
  int g = oc >> 3;
  int y = p >> 8, x = p & 255;
  const float* fb = fconv + (size_t)(b * 54 + g * 9) * NP;
  const float* wp = dw + oc * 81;
  float a = db[oc];
  for (int j = 0; j < 9; ++j) {
    const float* fj = fb + (size_t)j * NP;
    const float* wj = wp + j * 9;
    #pragma unroll
    for (int ky = 0; ky < 3; ++ky) {
      int iy = y + ky - 1;
      if ((unsigned)iy >= (unsigned)NH) continue;
      #pragma unroll
      for (int kx = 0; kx < 3; ++kx) {
        int ix = x + kx - 1;
        if ((unsigned)ix >= (unsigned)NW) continue;
        a += fj[iy * NW + ix] * wj[ky * 3 + kx];
      }
    }
  }
  outconv[idx] = a;
}

// ---------------- fused attn@V + proj + out_conv + residual ----------------
__global__ void k_proj(const float* __restrict__ qkvd, const float* __restrict__ A,
                       const float* __restrict__ projw, const float* __restrict__ x,
                       const float* __restrict__ outconv, float* __restrict__ x1) {
  int idx = blockIdx.x * blockDim.x + threadIdx.x;  // exact NB*NP
  int b = idx / NP, p = idx % NP;
  __shared__ float sA[288];
  for (int i = threadIdx.x; i < 288; i += 256) sA[i] = A[b * 288 + i];
  __syncthreads();
  float v[48];
  const float* vb = qkvd + (size_t)(b * 144 + 96) * NP + p;
  #pragma unroll
  for (int j = 0; j < 48; ++j) v[j] = vb[(size_t)j * NP];
  float av[48];
  #pragma unroll
  for (int h = 0; h < 8; ++h)
    #pragma unroll
    for (int c = 0; c < 6; ++c) {
      float a = 0.f;
      #pragma unroll
      for (int d = 0; d < 6; ++d) a += sA[h * 36 + c * 6 + d] * v[h * 6 + d];
      av[h * 6 + c] = a;
    }
  const float* xb = x + (size_t)b * NC * NP + p;
  const float* ob = outconv + (size_t)b * NC * NP + p;
  float* x1b = x1 + (size_t)b * NC * NP + p;
  for (int o = 0; o < 48; ++o) {
    const float* wr = projw + o * 48;
    float a = 0.f;
    #pragma unroll
    for (int c = 0; c < 48; ++c) a += wr[c] * av[c];
    x1b[(size_t)o * NP] = xb[(size_t)o * NP] + a + ob[(size_t)o * NP];
  }
}

// ---------------- FF: 3-dilation depthwise + gelu gate ----------------
__global__ void k_ffdw(const float* __restrict__ y, const float* __restrict__ w1,
                       const float* __restrict__ w2, const float* __restrict__ w3,
                       float* __restrict__ z) {
  int idx = blockIdx.x * blockDim.x + threadIdx.x;
  if (idx >= NB * NHID * NP) return;
  int p = idx % NP;
  int ch = (idx / NP) % NHID;
  int b = idx / (NHID * NP);
  int yy = p >> 8, xx = p & 255;
  const float* y1 = y + (size_t)(b * 288 + ch) * NP;
  const float* y2 = y1 + (size_t)NHID * NP;
  const float* y3 = y2 + (size_t)NHID * NP;
  const float* wp1 = w1 + ch * 9;
  const float* wp2 = w2 + ch * 9;
  const float* wp3 = w3 + ch * 9;
  float c1 = 0.f, c2 = 0.f, c3 = 0.f;
  #pragma unroll
  for (int ky = 0; ky < 3; ++ky)
    #pragma unroll
    for (int kx = 0; kx < 3; ++kx) {
      int wi = ky * 3 + kx;
      { int iy = yy + ky - 1, ix = xx + kx - 1;
        if ((unsigned)iy < (unsigned)NH && (unsigned)ix < (unsigned)NW)
          c1 += y1[iy * NW + ix] * wp1[wi]; }
      { int iy = yy + 2 * (ky - 1), ix = xx + 2 * (kx - 1);
        if ((unsigned)iy < (unsigned)NH && (unsigned)ix < (unsigned)NW)
          c2 += y2[iy * NW + ix] * wp2[wi]; }
      { int iy = yy + 3 * (ky - 1), ix = xx + 3 * (kx - 1);
        if ((unsigned)iy < (unsigned)NH && (unsigned)ix < (unsigned)NW)
          c3 += y3[iy * NW + ix] * wp3[wi]; }
    }
  z[idx] = gelu_f(c1) * c2 * c3;
}

// ---------------- pout + residual -> d_out ----------------
__global__ void k_pout(const float* __restrict__ z, const float* __restrict__ poutw,
                       const float* __restrict__ x1, float* __restrict__ outp) {
  int idx = blockIdx.x * blockDim.x + threadIdx.x;  // exact NB*NP
  int b = idx / NP, p = idx % NP;
  float zr[96];
  const float* zb = z + (size_t)b * NHID * NP + p;
  #pragma unroll
  for (int j = 0; j < 96; ++j) zr[j] = zb[(size_t)j * NP];
  const float* x1b = x1 + (size_t)b * NC * NP + p;
  float* ob = outp + (size_t)b * NC * NP + p;
  for (int o = 0; o < 48; ++o) {
    const float* wr = poutw + o * 96;
    float a = 0.f;
    #pragma unroll
    for (int j = 0; j < 96; ++j) a += wr[j] * zr[j];
    ob[(size_t)o * NP] = x1b[(size_t)o * NP] + a;
  }
}

// ---------------- workspace layout (floats) ----------------
constexpr size_t SZ_QKV = (size_t)NB * 144 * NP;       // 18,874,368
constexpr size_t SZ_CHW = (size_t)NB * NC * NP;        // 6,291,456
constexpr size_t OFF_QKV0 = 0;
constexpr size_t OFF_QKVD = OFF_QKV0 + SZ_QKV;
constexpr size_t OFF_FCONV = OFF_QKVD + SZ_QKV;        // y reuses [0, OFF_FCONV)
constexpr size_t SZ_FCONV = (size_t)NB * 54 * NP;
constexpr size_t OFF_OUTCONV = OFF_FCONV + SZ_FCONV;   // z reuses [OFF_FCONV, +NB*96*NP)
constexpr size_t OFF_X1 = OFF_OUTCONV + SZ_CHW;
constexpr size_t OFF_STATS = OFF_X1 + SZ_CHW;
constexpr size_t OFF_T1 = OFF_STATS + (size_t)NB * NP * 2;
constexpr size_t OFF_P1 = OFF_T1 + (size_t)NB * NC * 128 * 128;
constexpr size_t OFF_T2 = OFF_P1 + (size_t)NB * NC * 64 * 64;
constexpr size_t OFF_P2 = OFF_T2 + (size_t)NB * NC * 32 * 32;
constexpr size_t OFF_T3 = OFF_P2 + (size_t)NB * NC * 16 * 16;
constexpr size_t OFF_P3 = OFF_T3 + (size_t)NB * NC * 8 * 8;
constexpr size_t OFF_Q0M = OFF_P3 + (size_t)NB * NC * 4 * 4;
constexpr size_t OFF_NORMS = OFF_Q0M + 576;
constexpr size_t OFF_SPART = OFF_NORMS + 192;
constexpr size_t OFF_A = OFF_SPART + (size_t)NB * 64 * 36;

extern "C" void kernel_launch(void* const* d_in, const int* in_sizes, int n_in,
                              void* d_out, int out_size, void* d_ws, size_t ws_size,
                              hipStream_t stream) {
  const float* x     = (const float*)d_in[0];
  const float* ln1w  = (const float*)d_in[1];
  const float* ln1b  = (const float*)d_in[2];
  const float* qkvw  = (const float*)d_in[3];
  const float* qkvdw = (const float*)d_in[4];
  const float* projw = (const float*)d_in[5];
  const float* fcw   = (const float*)d_in[6];
  const float* fcb   = (const float*)d_in[7];
  const float* depw  = (const float*)d_in[8];
  const float* depb  = (const float*)d_in[9];
  const float* l2qw  = (const float*)d_in[10];
  const float* l2qb  = (const float*)d_in[11];
  const float* temp  = (const float*)d_in[12];
  const float* ln2w  = (const float*)d_in[13];
  const float* ln2b  = (const float*)d_in[14];
  const float* pinw  = (const float*)d_in[15];
  const float* dw1   = (const float*)d_in[16];
  const float* dw2   = (const float*)d_in[17];
  const float* dw3   = (const float*)d_in[18];
  const float* poutw = (const float*)d_in[19];
  const float* cvw0  = (const float*)d_in[20];
  const float* cvb0  = (const float*)d_in[21];
  const float* clw0  = (const float*)d_in[22];
  const float* clb0  = (const float*)d_in[23];
  const float* cvw1  = (const float*)d_in[24];
  const float* cvb1  = (const float*)d_in[25];
  const float* clw1  = (const float*)d_in[26];
  const float* clb1  = (const float*)d_in[27];
  const float* cvw2  = (const float*)d_in[28];
  const float* cvb2  = (const float*)d_in[29];
  const float* clw2  = (const float*)d_in[30];
  const float* clb2  = (const float*)d_in[31];

  float* ws = (float*)d_ws;
  float* qkv0 = ws + OFF_QKV0;
  float* qkvd = ws + OFF_QKVD;
  float* fconv = ws + OFF_FCONV;
  float* outconv = ws + OFF_OUTCONV;
  float* x1 = ws + OFF_X1;
  float2* stats = (float2*)(ws + OFF_STATS);
  float* t1 = ws + OFF_T1;
  float* p1 = ws + OFF_P1;
  float* t2 = ws + OFF_T2;
  float* p2 = ws + OFF_P2;
  float* t3 = ws + OFF_T3;
  float* p3 = ws + OFF_P3;
  float* q0m = ws + OFF_Q0M;
  float* norms = ws + OFF_NORMS;
  float* spart = ws + OFF_SPART;
  float* A = ws + OFF_A;
  float* ybuf = ws + OFF_QKV0;   // reuse qkv0+qkvd (exactly NB*288*NP)
  float* zbuf = ws + OFF_FCONV;  // reuse fconv+outconv (NB*96*NP fits)

  // conv-descriptor branch (LDS-tiled convs)
  k_conv_s2_tile<<<512, 256, 0, stream>>>(x, cvw0, cvb0, t1, 256, 256, 128, 128);
  k_lnpool<<<32, 256, 0, stream>>>(t1, clw0, clb0, p1, 128, 128);
  k_conv_s2_tile<<<32, 256, 0, stream>>>(p1, cvw1, cvb1, t2, 64, 64, 32, 32);
  k_lnpool<<<2, 256, 0, stream>>>(t2, clw1, clb1, p2, 32, 32);
  k_conv_s2_tile<<<2, 256, 0, stream>>>(p2, cvw2, cvb2, t3, 16, 16, 8, 8);
  k_lnpool<<<1, 256, 0, stream>>>(t3, clw2, clb2, p3, 8, 8);
  k_head<<<2, 320, 0, stream>>>(p3, l2qw, l2qb, q0m);

  // attention
  k_lnstats<<<512, 256, 0, stream>>>(x, stats);
  k_chmix_ln<<<512, 256, 0, stream>>>(x, stats, ln1w, ln1b, qkvw, qkv0, 144);
  k_dw144<<<73728, 256, 0, stream>>>(qkv0, qkvdw, qkvd);
  k_norms<<<192, 256, 0, stream>>>(qkvd, norms);
  k_gram<<<128, 256, 0, stream>>>(qkvd, spart);
  k_attn<<<2, 64, 0, stream>>>(spart, norms, temp, q0m, A);
  k_fc<<<2048, 384, 0, stream>>>(qkvd, fcw, fcb, fconv);
  k_depconv<<<24576, 256, 0, stream>>>(fconv, depw, depb, outconv);
  k_proj<<<512, 256, 0, stream>>>(qkvd, A, projw, x, outconv, x1);

  // feedforward
  k_lnstats<<<512, 256, 0, stream>>>(x1, stats);
  k_chmix_ln<<<512, 256, 0, stream>>>(x1, stats, ln2w, ln2b, pinw, ybuf, 288);
  k_ffdw<<<49152, 256, 0, stream>>>(ybuf, dw1, dw2, dw3, zbuf);
  k_pout<<<512, 256, 0, stream>>>(zbuf, poutw, x1, (float*)d_out);
}

// Round 4
// 1199.264 us; speedup vs baseline: 1.8634x; 1.2707x over previous
//
#include <hip/hip_runtime.h>

constexpr int NB = 2;
constexpr int NC = 48;
constexpr int NH = 256;
constexpr int NW = 256;
constexpr int NP = NH * NW;           // 65536
constexpr int NHEADS = 8;
constexpr int NCHD = 6;
constexpr int NHID = 96;

__device__ __forceinline__ float gelu_f(float v) {
  return 0.5f * v * (1.0f + erff(v * 0.70710678118654752f));
}

// ---------------- conv-descriptor branch: LDS-tiled stride-2 3x3 conv ----------------
__global__ __launch_bounds__(256) void k_conv_s2_tile(const float* __restrict__ in,
                                                      const float* __restrict__ w,
                                                      const float* __restrict__ bias,
                                                      float* __restrict__ out,
                                                      int IH, int IW, int OH, int OW) {
  __shared__ float lds[48 * 340];  // 340 = 17 rows * 20 (padded) ... 65280 B
  int tilesX = OW >> 3;
  int tilesY = OH >> 3;
  int blk = blockIdx.x;
  int tx = blk % tilesX;
  int t = blk / tilesX;
  int ty = t % tilesY;
  int b = t / tilesY;
  int oy0 = ty * 8, ox0 = tx * 8;
  int iy0 = oy0 * 2 - 1, ix0 = ox0 * 2 - 1;
  const float* inb = in + (size_t)b * NC * IH * IW;

  for (int i = threadIdx.x; i < 48 * 17 * 20; i += 256) {
    int cc = i % 20;
    int rr = (i / 20) % 17;
    int ic = i / 340;
    float v = 0.f;
    int iy = iy0 + rr, ix = ix0 + cc;
    if (cc < 17 && (unsigned)iy < (unsigned)IH && (unsigned)ix < (unsigned)IW)
      v = inb[((size_t)ic * IH + iy) * IW + ix];
    lds[ic * 340 + rr * 20 + cc] = v;
  }
  __syncthreads();

  int lane = threadIdx.x & 63;
  int oy = lane >> 3, ox = lane & 7;
  int ocb = __builtin_amdgcn_readfirstlane((threadIdx.x >> 6) * 12);
  float acc[12];
  #pragma unroll
  for (int j = 0; j < 12; ++j) acc[j] = bias[ocb + j];
  int pbase = oy * 40 + ox * 2;

  for (int ic = 0; ic < 48; ++ic) {
    float in9[9];
    const float* lp = lds + ic * 340 + pbase;
    #pragma unroll
    for (int ky = 0; ky < 3; ++ky)
      #pragma unroll
      for (int kx = 0; kx < 3; ++kx)
        in9[ky * 3 + kx] = lp[ky * 20 + kx];
    const float* wpc = w + (size_t)(ocb * 48 + ic) * 9;
    #pragma unroll
    for (int j = 0; j < 12; ++j) {
      const float* wp = wpc + (size_t)j * 48 * 9;
      float a = acc[j];
      #pragma unroll
      for (int k = 0; k < 9; ++k) a = fmaf(wp[k], in9[k], a);
      acc[j] = a;
    }
  }

  float* ob = out + (size_t)b * NC * OH * OW;
  #pragma unroll
  for (int j = 0; j < 12; ++j)
    ob[((size_t)(ocb + j) * OH + oy0 + oy) * OW + ox0 + ox] = acc[j];
}

__global__ void k_lnpool(const float* __restrict__ in, const float* __restrict__ lw,
                         const float* __restrict__ lb, float* __restrict__ out,
                         int IH, int IW) {
  int OH = IH >> 1, OW = IW >> 1;
  int idx = blockIdx.x * blockDim.x + threadIdx.x;
  int total = NB * OH * OW;
  if (idx >= total) return;
  int ox = idx % OW;
  int t = idx / OW;
  int oy = t % OH;
  int b = t / OH;
  const float* inb = in + (size_t)b * NC * IH * IW;
  float mu[4], rs[4];
  #pragma unroll
  for (int q = 0; q < 4; ++q) {
    int iy = oy * 2 + (q >> 1), ix = ox * 2 + (q & 1);
    float s = 0.f, ss = 0.f;
    for (int c = 0; c < NC; ++c) {
      float v = inb[((size_t)c * IH + iy) * IW + ix];
      s += v; ss += v * v;
    }
    float m = s * (1.f / NC);
    mu[q] = m;
    rs[q] = rsqrtf(fmaxf(ss * (1.f / NC) - m * m, 0.f) + 1e-5f);
  }
  for (int c = 0; c < NC; ++c) {
    float best = 0.f;  // relu >= 0 so 0 == max of relu'd window
    float wv = lw[c], bv = lb[c];
    #pragma unroll
    for (int q = 0; q < 4; ++q) {
      int iy = oy * 2 + (q >> 1), ix = ox * 2 + (q & 1);
      float v = inb[((size_t)c * IH + iy) * IW + ix];
      v = (v - mu[q]) * rs[q] * wv + bv;
      best = fmaxf(best, fmaxf(v, 0.f));
    }
    out[((size_t)(b * NC + c) * OH + oy) * OW + ox] = best;
  }
}

__global__ void k_head(const float* __restrict__ p3, const float* __restrict__ l2qw,
                       const float* __restrict__ l2qb, float* __restrict__ q0m) {
  __shared__ float xd[NC], q0[NC];
  int b = blockIdx.x, t = threadIdx.x;
  if (t < NC) {
    float s = 0.f;
    for (int i = 0; i < 16; ++i) s += p3[(b * NC + t) * 16 + i];
    xd[t] = gelu_f(s * (1.f / 16.f));
  }
  __syncthreads();
  if (t < NC) {
    float a = l2qb[t];
    for (int c = 0; c < NC; ++c) a += xd[c] * l2qw[t * NC + c];
    q0[t] = a;
  }
  __syncthreads();
  if (t < NHEADS * NCHD * NCHD) {
    int h = t / 36, r = t % 36, c = r / 6, d = r % 6;
    q0m[b * 288 + t] = q0[h * 6 + c] * q0[h * 6 + d];
  }
}

// ---------------- channel-mix (1x1 conv) with LN fully fused (stats inline) ----------------
__global__ __launch_bounds__(256, 4) void k_chmix_ln(const float* __restrict__ x,
                                                     const float* __restrict__ lnw,
                                                     const float* __restrict__ lnb,
                                                     const float* __restrict__ w,
                                                     float* __restrict__ out, int nout) {
  int idx = blockIdx.x * blockDim.x + threadIdx.x;
  if (idx >= NB * NP) return;
  int b = idx / NP, p = idx % NP;
  const float* xb = x + (size_t)b * NC * NP + p;
  float xr[NC];
  float s = 0.f, ss = 0.f;
  #pragma unroll
  for (int c = 0; c < NC; ++c) {
    float v = xb[(size_t)c * NP];
    xr[c] = v; s += v; ss += v * v;
  }
  float mu = s * (1.f / NC);
  float rstd = rsqrtf(fmaxf(ss * (1.f / NC) - mu * mu, 0.f) + 1e-5f);
  #pragma unroll
  for (int c = 0; c < NC; ++c)
    xr[c] = (xr[c] - mu) * rstd * lnw[c] + lnb[c];
  float* ob = out + (size_t)b * nout * NP + p;
  for (int o = 0; o < nout; ++o) {
    const float* wr = w + o * NC;
    float a = 0.f;
    #pragma unroll
    for (int c = 0; c < NC; ++c) a = fmaf(wr[c], xr[c], a);
    ob[(size_t)o * NP] = a;
  }
}

// ---------------- depthwise 3x3 on 144 channels ----------------
__global__ void k_dw144(const float* __restrict__ in, const float* __restrict__ w9,
                        float* __restrict__ out) {
  int idx = blockIdx.x * blockDim.x + threadIdx.x;
  if (idx >= NB * 144 * NP) return;
  int p = idx % NP;
  int ch = (idx / NP) % 144;
  int y = p >> 8, x = p & 255;
  const float* ib = in + (size_t)(idx - p);  // (b,ch)-plane base
  const float* wp = w9 + ch * 9;
  float a = 0.f;
  #pragma unroll
  for (int ky = 0; ky < 3; ++ky) {
    int iy = y + ky - 1;
    if ((unsigned)iy >= (unsigned)NH) continue;
    #pragma unroll
    for (int kx = 0; kx < 3; ++kx) {
      int ix = x + kx - 1;
      if ((unsigned)ix >= (unsigned)NW) continue;
      a += ib[iy * NW + ix] * wp[ky * 3 + kx];
    }
  }
  out[idx] = a;
}

// ---------------- per-channel L2 norms of q,k ----------------
__global__ void k_norms(const float* __restrict__ qkvd, float* __restrict__ norms) {
  int bc = blockIdx.x;  // b*96 + ch
  int b = bc / 96, ch = bc % 96;
  const float* pch = qkvd + (size_t)(b * 144 + ch) * NP;
  float ss = 0.f;
  for (int i = threadIdx.x; i < NP; i += 256) { float v = pch[i]; ss += v * v; }
  int lane = threadIdx.x & 63, wid = threadIdx.x >> 6;
  #pragma unroll
  for (int off = 32; off; off >>= 1) ss += __shfl_down(ss, off, 64);
  __shared__ float sr[4];
  if (lane == 0) sr[wid] = ss;
  __syncthreads();
  if (threadIdx.x == 0) norms[bc] = sqrtf(sr[0] + sr[1] + sr[2] + sr[3]);
}

// ---------------- per-head 6x6 Gram matrix (segmented partials) ----------------
__global__ void k_gram(const float* __restrict__ qkvd, float* __restrict__ spart) {
  int gid = blockIdx.x;  // b*64 + h*8 + seg
  int seg = gid & 7, h = (gid >> 3) & 7, b = gid >> 6;
  const float* qb = qkvd + (size_t)(b * 144 + h * 6) * NP;
  const float* kb = qkvd + (size_t)(b * 144 + 48 + h * 6) * NP;
  float acc[36];
  #pragma unroll
  for (int j = 0; j < 36; ++j) acc[j] = 0.f;
  for (int i = seg * 8192 + threadIdx.x; i < (seg + 1) * 8192; i += 256) {
    float qv[6], kv[6];
    #pragma unroll
    for (int c = 0; c < 6; ++c) { qv[c] = qb[(size_t)c * NP + i]; kv[c] = kb[(size_t)c * NP + i]; }
    #pragma unroll
    for (int c = 0; c < 6; ++c)
      #pragma unroll
      for (int d = 0; d < 6; ++d) acc[c * 6 + d] += qv[c] * kv[d];
  }
  int lane = threadIdx.x & 63, wid = threadIdx.x >> 6;
  __shared__ float sr[4 * 36];
  #pragma unroll
  for (int j = 0; j < 36; ++j) {
    float v = acc[j];
    #pragma unroll
    for (int off = 32; off; off >>= 1) v += __shfl_down(v, off, 64);
    if (lane == 0) sr[wid * 36 + j] = v;
  }
  __syncthreads();
  if (threadIdx.x < 36)
    spart[gid * 36 + threadIdx.x] =
        sr[threadIdx.x] + sr[36 + threadIdx.x] + sr[72 + threadIdx.x] + sr[108 + threadIdx.x];
}

// ---------------- attention softmax (tiny) ----------------
__global__ void k_attn(const float* __restrict__ spart, const float* __restrict__ norms,
                       const float* __restrict__ temp, const float* __restrict__ q0m,
                       float* __restrict__ A) {
  int b = blockIdx.x, t = threadIdx.x;
  if (t >= 48) return;
  int h = t / 6, c = t % 6;
  float nq = fmaxf(norms[b * 96 + h * 6 + c], 1e-12f);
  float tm = temp[h];
  float lg[6];
  #pragma unroll
  for (int d = 0; d < 6; ++d) {
    float s = 0.f;
    for (int seg = 0; seg < 8; ++seg)
      s += spart[(size_t)((b * 64 + h * 8 + seg) * 36) + c * 6 + d];
    float nk = fmaxf(norms[b * 96 + 48 + h * 6 + d], 1e-12f);
    lg[d] = (s / (nq * nk)) * tm * q0m[b * 288 + h * 36 + c * 6 + d];
  }
  float m = lg[0];
  #pragma unroll
  for (int d = 1; d < 6; ++d) m = fmaxf(m, lg[d]);
  float sum = 0.f;
  #pragma unroll
  for (int d = 0; d < 6; ++d) { lg[d] = expf(lg[d] - m); sum += lg[d]; }
  float inv = 1.f / sum;
  #pragma unroll
  for (int d = 0; d < 6; ++d) A[b * 288 + h * 36 + c * 6 + d] = lg[d] * inv;
}

// ---------------- fc mix over the raw-reshape scramble ----------------
__global__ __launch_bounds__(384) void k_fc(const float* __restrict__ qkvd,
                                            const float* __restrict__ fcw,
                                            const float* __restrict__ fcb,
                                            float* __restrict__ fconv) {
  __shared__ float sin_[9216];   // 64 pixels * 144
  __shared__ float sout[3456];   // 54 ch * 64 pixels
  int blk = blockIdx.x;
  int b = blk >> 10, p0 = (blk & 1023) << 6;
  const float* src = qkvd + (size_t)b * 144 * NP + (size_t)p0 * 144;
  for (int i = threadIdx.x; i < 9216; i += 384) sin_[i] = src[i];
  __syncthreads();
  int pl = threadIdx.x / 6, c2 = threadIdx.x % 6;
  float xv[24];
  #pragma unroll
  for (int g = 0; g < 24; ++g) xv[g] = sin_[pl * 144 + g * 6 + c2];
  #pragma unroll
  for (int o = 0; o < 9; ++o) {
    float a = fcb[o];
    #pragma unroll
    for (int g = 0; g < 24; ++g) a += fcw[o * 24 + g] * xv[g];
    sout[(c2 * 9 + o) * 64 + pl] = a;
  }
  __syncthreads();
  for (int i = threadIdx.x; i < 3456; i += 384) {
    int ch = i >> 6, pl2 = i & 63;
    fconv[(size_t)(b * 54 + ch) * NP + p0 + pl2] = sout[i];
  }
}

// ---------------- grouped dep conv 54->48, groups=6 ----------------
__global__ void k_depconv(const float* __restrict__ fconv, const float* __restrict__ dw,
                          const float* __restrict__ db, float* __restrict__ outconv) {
  int idx = blockIdx.x * blockDim.x + threadIdx.x;
  if (idx >= NB * NC * NP) return;
  int p = idx % NP;
  int oc = (idx / NP) % NC;
  int b = idx / (NC * NP);
  int g = oc >> 3;
  int y = p >> 8, x = p & 255;
  const float* fb = fconv + (size_t)(b * 54 + g * 9) * NP;
  const float* wp = dw + oc * 81;
  float a = db[oc];
  for (int j = 0; j < 9; ++j) {
    const float* fj = fb + (size_t)j * NP;
    const float* wj = wp + j * 9;
    #pragma unroll
    for (int ky = 0; ky < 3; ++ky) {
      int iy = y + ky - 1;
      if ((unsigned)iy >= (unsigned)NH) continue;
      #pragma unroll
      for (int kx = 0; kx < 3; ++kx) {
        int ix = x + kx - 1;
        if ((unsigned)ix >= (unsigned)NW) continue;
        a += fj[iy * NW + ix] * wj[ky * 3 + kx];
      }
    }
  }
  outconv[idx] = a;
}

// ---------------- fused attn@V + proj + out_conv + residual ----------------
// Streams v per head (6 regs), scatters through projw into acc[48]; no big live arrays.
__global__ __launch_bounds__(256, 4) void k_proj(const float* __restrict__ qkvd,
                                                 const float* __restrict__ A,
                                                 const float* __restrict__ projw,
                                                 const float* __restrict__ x,
                                                 const float* __restrict__ outconv,
                                                 float* __restrict__ x1) {
  int idx = blockIdx.x * blockDim.x + threadIdx.x;  // exact NB*NP
  int b = idx / NP, p = idx % NP;
  __shared__ float sA[288];
  for (int i = threadIdx.x; i < 288; i += 256) sA[i] = A[b * 288 + i];
  __syncthreads();
  const float* vb = qkvd + (size_t)(b * 144 + 96) * NP + p;
  float acc[48];
  #pragma unroll
  for (int o = 0; o < 48; ++o) acc[o] = 0.f;
  for (int h = 0; h < 8; ++h) {
    float v6[6];
    #pragma unroll
    for (int d = 0; d < 6; ++d) v6[d] = vb[(size_t)(h * 6 + d) * NP];
    #pragma unroll
    for (int c = 0; c < 6; ++c) {
      float av = 0.f;
      #pragma unroll
      for (int d = 0; d < 6; ++d) av = fmaf(sA[h * 36 + c * 6 + d], v6[d], av);
      const float* wc = projw + h * 6 + c;  // projw[o*48 + (h*6+c)]
      #pragma unroll
      for (int o = 0; o < 48; ++o) acc[o] = fmaf(wc[o * 48], av, acc[o]);
    }
  }
  const float* xb = x + (size_t)b * NC * NP + p;
  const float* ob = outconv + (size_t)b * NC * NP + p;
  float* x1b = x1 + (size_t)b * NC * NP + p;
  #pragma unroll
  for (int o = 0; o < 48; ++o)
    x1b[(size_t)o * NP] = xb[(size_t)o * NP] + acc[o] + ob[(size_t)o * NP];
}

// ---------------- FF: 3-dilation depthwise + gelu gate ----------------
__global__ void k_ffdw(const float* __restrict__ y, const float* __restrict__ w1,
                       const float* __restrict__ w2, const float* __restrict__ w3,
                       float* __restrict__ z) {
  int idx = blockIdx.x * blockDim.x + threadIdx.x;
  if (idx >= NB * NHID * NP) return;
  int p = idx % NP;
  int ch = (idx / NP) % NHID;
  int b = idx / (NHID * NP);
  int yy = p >> 8, xx = p & 255;
  const float* y1 = y + (size_t)(b * 288 + ch) * NP;
  const float* y2 = y1 + (size_t)NHID * NP;
  const float* y3 = y2 + (size_t)NHID * NP;
  const float* wp1 = w1 + ch * 9;
  const float* wp2 = w2 + ch * 9;
  const float* wp3 = w3 + ch * 9;
  float c1 = 0.f, c2 = 0.f, c3 = 0.f;
  #pragma unroll
  for (int ky = 0; ky < 3; ++ky)
    #pragma unroll
    for (int kx = 0; kx < 3; ++kx) {
      int wi = ky * 3 + kx;
      { int iy = yy + ky - 1, ix = xx + kx - 1;
        if ((unsigned)iy < (unsigned)NH && (unsigned)ix < (unsigned)NW)
          c1 += y1[iy * NW + ix] * wp1[wi]; }
      { int iy = yy + 2 * (ky - 1), ix = xx + 2 * (kx - 1);
        if ((unsigned)iy < (unsigned)NH && (unsigned)ix < (unsigned)NW)
          c2 += y2[iy * NW + ix] * wp2[wi]; }
      { int iy = yy + 3 * (ky - 1), ix = xx + 3 * (kx - 1);
        if ((unsigned)iy < (unsigned)NH && (unsigned)ix < (unsigned)NW)
          c3 += y3[iy * NW + ix] * wp3[wi]; }
    }
  z[idx] = gelu_f(c1) * c2 * c3;
}

// ---------------- pout + residual -> d_out (streamed, acc[48]) ----------------
__global__ __launch_bounds__(256, 4) void k_pout(const float* __restrict__ z,
                                                 const float* __restrict__ poutw,
                                                 const float* __restrict__ x1,
                                                 float* __restrict__ outp) {
  int idx = blockIdx.x * blockDim.x + threadIdx.x;  // exact NB*NP
  int b = idx / NP, p = idx % NP;
  const float* zb = z + (size_t)b * NHID * NP + p;
  float acc[48];
  #pragma unroll
  for (int o = 0; o < 48; ++o) acc[o] = 0.f;
  for (int j = 0; j < 96; ++j) {
    float zv = zb[(size_t)j * NP];
    const float* wc = poutw + j;  // poutw[o*96 + j]
    #pragma unroll
    for (int o = 0; o < 48; ++o) acc[o] = fmaf(wc[o * 96], zv, acc[o]);
  }
  const float* x1b = x1 + (size_t)b * NC * NP + p;
  float* ob = outp + (size_t)b * NC * NP + p;
  #pragma unroll
  for (int o = 0; o < 48; ++o)
    ob[(size_t)o * NP] = x1b[(size_t)o * NP] + acc[o];
}

// ---------------- workspace layout (floats) ----------------
constexpr size_t SZ_QKV = (size_t)NB * 144 * NP;       // 18,874,368
constexpr size_t SZ_CHW = (size_t)NB * NC * NP;        // 6,291,456
constexpr size_t OFF_QKV0 = 0;
constexpr size_t OFF_QKVD = OFF_QKV0 + SZ_QKV;
constexpr size_t OFF_FCONV = OFF_QKVD + SZ_QKV;        // y reuses [0, OFF_FCONV)
constexpr size_t SZ_FCONV = (size_t)NB * 54 * NP;
constexpr size_t OFF_OUTCONV = OFF_FCONV + SZ_FCONV;   // z reuses [OFF_FCONV, +NB*96*NP)
constexpr size_t OFF_X1 = OFF_OUTCONV + SZ_CHW;
constexpr size_t OFF_STATS = OFF_X1 + SZ_CHW;          // (stats slot retained, unused)
constexpr size_t OFF_T1 = OFF_STATS + (size_t)NB * NP * 2;
constexpr size_t OFF_P1 = OFF_T1 + (size_t)NB * NC * 128 * 128;
constexpr size_t OFF_T2 = OFF_P1 + (size_t)NB * NC * 64 * 64;
constexpr size_t OFF_P2 = OFF_T2 + (size_t)NB * NC * 32 * 32;
constexpr size_t OFF_T3 = OFF_P2 + (size_t)NB * NC * 16 * 16;
constexpr size_t OFF_P3 = OFF_T3 + (size_t)NB * NC * 8 * 8;
constexpr size_t OFF_Q0M = OFF_P3 + (size_t)NB * NC * 4 * 4;
constexpr size_t OFF_NORMS = OFF_Q0M + 576;
constexpr size_t OFF_SPART = OFF_NORMS + 192;
constexpr size_t OFF_A = OFF_SPART + (size_t)NB * 64 * 36;

extern "C" void kernel_launch(void* const* d_in, const int* in_sizes, int n_in,
                              void* d_out, int out_size, void* d_ws, size_t ws_size,
                              hipStream_t stream) {
  const float* x     = (const float*)d_in[0];
  const float* ln1w  = (const float*)d_in[1];
  const float* ln1b  = (const float*)d_in[2];
  const float* qkvw  = (const float*)d_in[3];
  const float* qkvdw = (const float*)d_in[4];
  const float* projw = (const float*)d_in[5];
  const float* fcw   = (const float*)d_in[6];
  const float* fcb   = (const float*)d_in[7];
  const float* depw  = (const float*)d_in[8];
  const float* depb  = (const float*)d_in[9];
  const float* l2qw  = (const float*)d_in[10];
  const float* l2qb  = (const float*)d_in[11];
  const float* temp  = (const float*)d_in[12];
  const float* ln2w  = (const float*)d_in[13];
  const float* ln2b  = (const float*)d_in[14];
  const float* pinw  = (const float*)d_in[15];
  const float* dw1   = (const float*)d_in[16];
  const float* dw2   = (const float*)d_in[17];
  const float* dw3   = (const float*)d_in[18];
  const float* poutw = (const float*)d_in[19];
  const float* cvw0  = (const float*)d_in[20];
  const float* cvb0  = (const float*)d_in[21];
  const float* clw0  = (const float*)d_in[22];
  const float* clb0  = (const float*)d_in[23];
  const float* cvw1  = (const float*)d_in[24];
  const float* cvb1  = (const float*)d_in[25];
  const float* clw1  = (const float*)d_in[26];
  const float* clb1  = (const float*)d_in[27];
  const float* cvw2  = (const float*)d_in[28];
  const float* cvb2  = (const float*)d_in[29];
  const float* clw2  = (const float*)d_in[30];
  const float* clb2  = (const float*)d_in[31];

  float* ws = (float*)d_ws;
  float* qkv0 = ws + OFF_QKV0;
  float* qkvd = ws + OFF_QKVD;
  float* fconv = ws + OFF_FCONV;
  float* outconv = ws + OFF_OUTCONV;
  float* x1 = ws + OFF_X1;
  float* t1 = ws + OFF_T1;
  float* p1 = ws + OFF_P1;
  float* t2 = ws + OFF_T2;
  float* p2 = ws + OFF_P2;
  float* t3 = ws + OFF_T3;
  float* p3 = ws + OFF_P3;
  float* q0m = ws + OFF_Q0M;
  float* norms = ws + OFF_NORMS;
  float* spart = ws + OFF_SPART;
  float* A = ws + OFF_A;
  float* ybuf = ws + OFF_QKV0;   // reuse qkv0+qkvd (exactly NB*288*NP)
  float* zbuf = ws + OFF_FCONV;  // reuse fconv+outconv (NB*96*NP fits)

  // conv-descriptor branch (LDS-tiled convs)
  k_conv_s2_tile<<<512, 256, 0, stream>>>(x, cvw0, cvb0, t1, 256, 256, 128, 128);
  k_lnpool<<<32, 256, 0, stream>>>(t1, clw0, clb0, p1, 128, 128);
  k_conv_s2_tile<<<32, 256, 0, stream>>>(p1, cvw1, cvb1, t2, 64, 64, 32, 32);
  k_lnpool<<<2, 256, 0, stream>>>(t2, clw1, clb1, p2, 32, 32);
  k_conv_s2_tile<<<2, 256, 0, stream>>>(p2, cvw2, cvb2, t3, 16, 16, 8, 8);
  k_lnpool<<<1, 256, 0, stream>>>(t3, clw2, clb2, p3, 8, 8);
  k_head<<<2, 320, 0, stream>>>(p3, l2qw, l2qb, q0m);

  // attention
  k_chmix_ln<<<512, 256, 0, stream>>>(x, ln1w, ln1b, qkvw, qkv0, 144);
  k_dw144<<<73728, 256, 0, stream>>>(qkv0, qkvdw, qkvd);
  k_norms<<<192, 256, 0, stream>>>(qkvd, norms);
  k_gram<<<128, 256, 0, stream>>>(qkvd, spart);
  k_attn<<<2, 64, 0, stream>>>(spart, norms, temp, q0m, A);
  k_fc<<<2048, 384, 0, stream>>>(qkvd, fcw, fcb, fconv);
  k_depconv<<<24576, 256, 0, stream>>>(fconv, depw, depb, outconv);
  k_proj<<<512, 256, 0, stream>>>(qkvd, A, projw, x, outconv, x1);

  // feedforward
  k_chmix_ln<<<512, 256, 0, stream>>>(x1, ln2w, ln2b, pinw, ybuf, 288);
  k_ffdw<<<49152, 256, 0, stream>>>(ybuf, dw1, dw2, dw3, zbuf);
  k_pout<<<512, 256, 0, stream>>>(zbuf, poutw, x1, (float*)d_out);
}

// Round 5
// 881.392 us; speedup vs baseline: 2.5355x; 1.3606x over previous
//
#include <hip/hip_runtime.h>

constexpr int NB = 2;
constexpr int NC = 48;
constexpr int NH = 256;
constexpr int NW = 256;
constexpr int NP = NH * NW;           // 65536
constexpr int NHEADS = 8;
constexpr int NCHD = 6;
constexpr int NHID = 96;

__device__ __forceinline__ float gelu_f(float v) {
  return 0.5f * v * (1.0f + erff(v * 0.70710678118654752f));
}

// ---------------- conv-descriptor branch: LDS-tiled stride-2 3x3 conv ----------------
__global__ __launch_bounds__(256) void k_conv_s2_tile(const float* __restrict__ in,
                                                      const float* __restrict__ w,
                                                      const float* __restrict__ bias,
                                                      float* __restrict__ out,
                                                      int IH, int IW, int OH, int OW) {
  __shared__ float lds[48 * 340];  // 340 = 17 rows * 20 (padded) ... 65280 B
  int tilesX = OW >> 3;
  int tilesY = OH >> 3;
  int blk = blockIdx.x;
  int tx = blk % tilesX;
  int t = blk / tilesX;
  int ty = t % tilesY;
  int b = t / tilesY;
  int oy0 = ty * 8, ox0 = tx * 8;
  int iy0 = oy0 * 2 - 1, ix0 = ox0 * 2 - 1;
  const float* inb = in + (size_t)b * NC * IH * IW;

  for (int i = threadIdx.x; i < 48 * 17 * 20; i += 256) {
    int cc = i % 20;
    int rr = (i / 20) % 17;
    int ic = i / 340;
    float v = 0.f;
    int iy = iy0 + rr, ix = ix0 + cc;
    if (cc < 17 && (unsigned)iy < (unsigned)IH && (unsigned)ix < (unsigned)IW)
      v = inb[((size_t)ic * IH + iy) * IW + ix];
    lds[ic * 340 + rr * 20 + cc] = v;
  }
  __syncthreads();

  int lane = threadIdx.x & 63;
  int oy = lane >> 3, ox = lane & 7;
  int ocb = __builtin_amdgcn_readfirstlane((threadIdx.x >> 6) * 12);
  float acc[12];
  #pragma unroll
  for (int j = 0; j < 12; ++j) acc[j] = bias[ocb + j];
  int pbase = oy * 40 + ox * 2;

  for (int ic = 0; ic < 48; ++ic) {
    float in9[9];
    const float* lp = lds + ic * 340 + pbase;
    #pragma unroll
    for (int ky = 0; ky < 3; ++ky)
      #pragma unroll
      for (int kx = 0; kx < 3; ++kx)
        in9[ky * 3 + kx] = lp[ky * 20 + kx];
    const float* wpc = w + (size_t)(ocb * 48 + ic) * 9;
    #pragma unroll
    for (int j = 0; j < 12; ++j) {
      const float* wp = wpc + (size_t)j * 48 * 9;
      float a = acc[j];
      #pragma unroll
      for (int k = 0; k < 9; ++k) a = fmaf(wp[k], in9[k], a);
      acc[j] = a;
    }
  }

  float* ob = out + (size_t)b * NC * OH * OW;
  #pragma unroll
  for (int j = 0; j < 12; ++j)
    ob[((size_t)(ocb + j) * OH + oy0 + oy) * OW + ox0 + ox] = acc[j];
}

__global__ void k_lnpool(const float* __restrict__ in, const float* __restrict__ lw,
                         const float* __restrict__ lb, float* __restrict__ out,
                         int IH, int IW) {
  int OH = IH >> 1, OW = IW >> 1;
  int idx = blockIdx.x * blockDim.x + threadIdx.x;
  int total = NB * OH * OW;
  if (idx >= total) return;
  int ox = idx % OW;
  int t = idx / OW;
  int oy = t % OH;
  int b = t / OH;
  const float* inb = in + (size_t)b * NC * IH * IW;
  float mu[4], rs[4];
  #pragma unroll
  for (int q = 0; q < 4; ++q) {
    int iy = oy * 2 + (q >> 1), ix = ox * 2 + (q & 1);
    float s = 0.f, ss = 0.f;
    for (int c = 0; c < NC; ++c) {
      float v = inb[((size_t)c * IH + iy) * IW + ix];
      s += v; ss += v * v;
    }
    float m = s * (1.f / NC);
    mu[q] = m;
    rs[q] = rsqrtf(fmaxf(ss * (1.f / NC) - m * m, 0.f) + 1e-5f);
  }
  for (int c = 0; c < NC; ++c) {
    float best = 0.f;  // relu >= 0 so 0 == max of relu'd window
    float wv = lw[c], bv = lb[c];
    #pragma unroll
    for (int q = 0; q < 4; ++q) {
      int iy = oy * 2 + (q >> 1), ix = ox * 2 + (q & 1);
      float v = inb[((size_t)c * IH + iy) * IW + ix];
      v = (v - mu[q]) * rs[q] * wv + bv;
      best = fmaxf(best, fmaxf(v, 0.f));
    }
    out[((size_t)(b * NC + c) * OH + oy) * OW + ox] = best;
  }
}

__global__ void k_head(const float* __restrict__ p3, const float* __restrict__ l2qw,
                       const float* __restrict__ l2qb, float* __restrict__ q0m) {
  __shared__ float xd[NC], q0[NC];
  int b = blockIdx.x, t = threadIdx.x;
  if (t < NC) {
    float s = 0.f;
    for (int i = 0; i < 16; ++i) s += p3[(b * NC + t) * 16 + i];
    xd[t] = gelu_f(s * (1.f / 16.f));
  }
  __syncthreads();
  if (t < NC) {
    float a = l2qb[t];
    for (int c = 0; c < NC; ++c) a += xd[c] * l2qw[t * NC + c];
    q0[t] = a;
  }
  __syncthreads();
  if (t < NHEADS * NCHD * NCHD) {
    int h = t / 36, r = t % 36, c = r / 6, d = r % 6;
    q0m[b * 288 + t] = q0[h * 6 + c] * q0[h * 6 + d];
  }
}

// ---------------- channel-mix (1x1 conv) with LN fused; o-split for occupancy ----------------
__global__ __launch_bounds__(256, 4) void k_chmix_ln(const float* __restrict__ x,
                                                     const float* __restrict__ lnw,
                                                     const float* __restrict__ lnb,
                                                     const float* __restrict__ w,
                                                     float* __restrict__ out,
                                                     int nout, int ochunk) {
  int bid = blockIdx.x;
  int osub = bid >> 9;                           // blocks 512..1023 handle second half
  int idx = ((bid & 511) << 8) + threadIdx.x;    // b*NP + p
  int b = idx / NP, p = idx % NP;
  const float* xb = x + (size_t)b * NC * NP + p;
  float xr[NC];
  float s = 0.f, ss = 0.f;
  #pragma unroll
  for (int c = 0; c < NC; ++c) {
    float v = xb[(size_t)c * NP];
    xr[c] = v; s += v; ss += v * v;
  }
  float mu = s * (1.f / NC);
  float rstd = rsqrtf(fmaxf(ss * (1.f / NC) - mu * mu, 0.f) + 1e-5f);
  #pragma unroll
  for (int c = 0; c < NC; ++c)
    xr[c] = (xr[c] - mu) * rstd * lnw[c] + lnb[c];
  float* ob = out + (size_t)b * nout * NP + p;
  int o0 = osub * ochunk, o1 = o0 + ochunk;
  for (int o = o0; o < o1; ++o) {
    const float* wr = w + o * NC;
    float a = 0.f;
    #pragma unroll
    for (int c = 0; c < NC; ++c) a = fmaf(wr[c], xr[c], a);
    ob[(size_t)o * NP] = a;
  }
}

// ---------------- depthwise 3x3 on 144 channels (row-tiled LDS) ----------------
// block = 1 row x 256 px of one (b,ch) plane; stage 3 rows (264-wide, zero-padded).
__global__ __launch_bounds__(256) void k_dw144(const float* __restrict__ in,
                                               const float* __restrict__ w9,
                                               float* __restrict__ out) {
  __shared__ float lds[3 * 264];
  int blk = blockIdx.x;
  int yy = blk & 255;
  int ch = (blk >> 8) % 144;
  int b = blk / (144 * 256);
  const float* ib = in + (size_t)(b * 144 + ch) * NP;
  for (int i = threadIdx.x; i < 3 * 264; i += 256) {
    int c = i % 264, r = i / 264;
    int iy = yy + r - 1, ix = c - 4;
    float v = 0.f;
    if ((unsigned)iy < (unsigned)NH && (unsigned)ix < (unsigned)NW)
      v = ib[iy * NW + ix];
    lds[i] = v;
  }
  __syncthreads();
  int x = threadIdx.x;
  const float* wp = w9 + ch * 9;   // wave-uniform -> scalar loads
  float a = 0.f;
  #pragma unroll
  for (int r = 0; r < 3; ++r)
    #pragma unroll
    for (int dx = 0; dx < 3; ++dx)
      a = fmaf(lds[r * 264 + x + 3 + dx], wp[r * 3 + dx], a);
  out[(size_t)(b * 144 + ch) * NP + yy * NW + x] = a;
}

// ---------------- per-channel L2 norms of q,k ----------------
__global__ void k_norms(const float* __restrict__ qkvd, float* __restrict__ norms) {
  int bc = blockIdx.x;  // b*96 + ch
  int b = bc / 96, ch = bc % 96;
  const float* pch = qkvd + (size_t)(b * 144 + ch) * NP;
  float ss = 0.f;
  for (int i = threadIdx.x; i < NP; i += 256) { float v = pch[i]; ss += v * v; }
  int lane = threadIdx.x & 63, wid = threadIdx.x >> 6;
  #pragma unroll
  for (int off = 32; off; off >>= 1) ss += __shfl_down(ss, off, 64);
  __shared__ float sr[4];
  if (lane == 0) sr[wid] = ss;
  __syncthreads();
  if (threadIdx.x == 0) norms[bc] = sqrtf(sr[0] + sr[1] + sr[2] + sr[3]);
}

// ---------------- per-head 6x6 Gram matrix (segmented partials) ----------------
__global__ void k_gram(const float* __restrict__ qkvd, float* __restrict__ spart) {
  int gid = blockIdx.x;  // b*64 + h*8 + seg
  int seg = gid & 7, h = (gid >> 3) & 7, b = gid >> 6;
  const float* qb = qkvd + (size_t)(b * 144 + h * 6) * NP;
  const float* kb = qkvd + (size_t)(b * 144 + 48 + h * 6) * NP;
  float acc[36];
  #pragma unroll
  for (int j = 0; j < 36; ++j) acc[j] = 0.f;
  for (int i = seg * 8192 + threadIdx.x; i < (seg + 1) * 8192; i += 256) {
    float qv[6], kv[6];
    #pragma unroll
    for (int c = 0; c < 6; ++c) { qv[c] = qb[(size_t)c * NP + i]; kv[c] = kb[(size_t)c * NP + i]; }
    #pragma unroll
    for (int c = 0; c < 6; ++c)
      #pragma unroll
      for (int d = 0; d < 6; ++d) acc[c * 6 + d] += qv[c] * kv[d];
  }
  int lane = threadIdx.x & 63, wid = threadIdx.x >> 6;
  __shared__ float sr[4 * 36];
  #pragma unroll
  for (int j = 0; j < 36; ++j) {
    float v = acc[j];
    #pragma unroll
    for (int off = 32; off; off >>= 1) v += __shfl_down(v, off, 64);
    if (lane == 0) sr[wid * 36 + j] = v;
  }
  __syncthreads();
  if (threadIdx.x < 36)
    spart[gid * 36 + threadIdx.x] =
        sr[threadIdx.x] + sr[36 + threadIdx.x] + sr[72 + threadIdx.x] + sr[108 + threadIdx.x];
}

// ---------------- attention softmax (tiny) ----------------
__global__ void k_attn(const float* __restrict__ spart, const float* __restrict__ norms,
                       const float* __restrict__ temp, const float* __restrict__ q0m,
                       float* __restrict__ A) {
  int b = blockIdx.x, t = threadIdx.x;
  if (t >= 48) return;
  int h = t / 6, c = t % 6;
  float nq = fmaxf(norms[b * 96 + h * 6 + c], 1e-12f);
  float tm = temp[h];
  float lg[6];
  #pragma unroll
  for (int d = 0; d < 6; ++d) {
    float s = 0.f;
    for (int seg = 0; seg < 8; ++seg)
      s += spart[(size_t)((b * 64 + h * 8 + seg) * 36) + c * 6 + d];
    float nk = fmaxf(norms[b * 96 + 48 + h * 6 + d], 1e-12f);
    lg[d] = (s / (nq * nk)) * tm * q0m[b * 288 + h * 36 + c * 6 + d];
  }
  float m = lg[0];
  #pragma unroll
  for (int d = 1; d < 6; ++d) m = fmaxf(m, lg[d]);
  float sum = 0.f;
  #pragma unroll
  for (int d = 0; d < 6; ++d) { lg[d] = expf(lg[d] - m); sum += lg[d]; }
  float inv = 1.f / sum;
  #pragma unroll
  for (int d = 0; d < 6; ++d) A[b * 288 + h * 36 + c * 6 + d] = lg[d] * inv;
}

// ---------------- fc mix over the raw-reshape scramble ----------------
__global__ __launch_bounds__(384) void k_fc(const float* __restrict__ qkvd,
                                            const float* __restrict__ fcw,
                                            const float* __restrict__ fcb,
                                            float* __restrict__ fconv) {
  __shared__ float sin_[9216];   // 64 pixels * 144
  __shared__ float sout[3456];   // 54 ch * 64 pixels
  int blk = blockIdx.x;
  int b = blk >> 10, p0 = (blk & 1023) << 6;
  const float* src = qkvd + (size_t)b * 144 * NP + (size_t)p0 * 144;
  for (int i = threadIdx.x; i < 9216; i += 384) sin_[i] = src[i];
  __syncthreads();
  int pl = threadIdx.x / 6, c2 = threadIdx.x % 6;
  float xv[24];
  #pragma unroll
  for (int g = 0; g < 24; ++g) xv[g] = sin_[pl * 144 + g * 6 + c2];
  #pragma unroll
  for (int o = 0; o < 9; ++o) {
    float a = fcb[o];
    #pragma unroll
    for (int g = 0; g < 24; ++g) a += fcw[o * 24 + g] * xv[g];
    sout[(c2 * 9 + o) * 64 + pl] = a;
  }
  __syncthreads();
  for (int i = threadIdx.x; i < 3456; i += 384) {
    int ch = i >> 6, pl2 = i & 63;
    fconv[(size_t)(b * 54 + ch) * NP + p0 + pl2] = sout[i];
  }
}

// ---------------- grouped dep conv 54->48, groups=6 (row-tiled LDS, 8 oc/block) ----------------
// block = 1 row x 256 px for one (b,group); stages 9 planes x 3 rows; computes 8 output chans.
__global__ __launch_bounds__(256) void k_depconv(const float* __restrict__ fconv,
                                                 const float* __restrict__ dw,
                                                 const float* __restrict__ db,
                                                 float* __restrict__ outconv) {
  __shared__ float lds[27 * 264];  // 28512 B
  int blk = blockIdx.x;            // b*6*256 + g*256 + yy
  int yy = blk & 255;
  int g = (blk >> 8) % 6;
  int b = blk / (6 * 256);
  const float* fb = fconv + (size_t)(b * 54 + g * 9) * NP;
  for (int i = threadIdx.x; i < 27 * 264; i += 256) {
    int c = i % 264;
    int r = (i / 264) % 3;
    int j = i / 792;
    int iy = yy + r - 1, ix = c - 4;
    float v = 0.f;
    if ((unsigned)iy < (unsigned)NH && (unsigned)ix < (unsigned)NW)
      v = fb[(size_t)j * NP + iy * NW + ix];
    lds[i] = v;
  }
  __syncthreads();
  int x = threadIdx.x;
  float acc[8];
  #pragma unroll
  for (int o = 0; o < 8; ++o) acc[o] = db[g * 8 + o];
  const float* wg = dw + (size_t)(g * 8) * 81;  // weights for oc = g*8 .. g*8+7
  #pragma unroll
  for (int j = 0; j < 9; ++j) {
    #pragma unroll
    for (int r = 0; r < 3; ++r)
      #pragma unroll
      for (int dx = 0; dx < 3; ++dx) {
        float tv = lds[(j * 3 + r) * 264 + x + 3 + dx];
        int wi = j * 9 + r * 3 + dx;
        #pragma unroll
        for (int o = 0; o < 8; ++o)
          acc[o] = fmaf(tv, wg[o * 81 + wi], acc[o]);
      }
  }
  float* ob = outconv + ((size_t)(b * NC + g * 8) * NH + yy) * NW + x;
  #pragma unroll
  for (int o = 0; o < 8; ++o) ob[(size_t)o * NP] = acc[o];
}

// ---------------- fused attn@V + proj + out_conv + residual ----------------
__global__ __launch_bounds__(256, 4) void k_proj(const float* __restrict__ qkvd,
                                                 const float* __restrict__ A,
                                                 const float* __restrict__ projw,
                                                 const float* __restrict__ x,
                                                 const float* __restrict__ outconv,
                                                 float* __restrict__ x1) {
  int idx = blockIdx.x * blockDim.x + threadIdx.x;  // exact NB*NP
  int b = idx / NP, p = idx % NP;
  __shared__ float sA[288];
  for (int i = threadIdx.x; i < 288; i += 256) sA[i] = A[b * 288 + i];
  __syncthreads();
  const float* vb = qkvd + (size_t)(b * 144 + 96) * NP + p;
  float acc[48];
  #pragma unroll
  for (int o = 0; o < 48; ++o) acc[o] = 0.f;
  for (int h = 0; h < 8; ++h) {
    float v6[6];
    #pragma unroll
    for (int d = 0; d < 6; ++d) v6[d] = vb[(size_t)(h * 6 + d) * NP];
    #pragma unroll
    for (int c = 0; c < 6; ++c) {
      float av = 0.f;
      #pragma unroll
      for (int d = 0; d < 6; ++d) av = fmaf(sA[h * 36 + c * 6 + d], v6[d], av);
      const float* wc = projw + h * 6 + c;  // projw[o*48 + (h*6+c)]
      #pragma unroll
      for (int o = 0; o < 48; ++o) acc[o] = fmaf(wc[o * 48], av, acc[o]);
    }
  }
  const float* xb = x + (size_t)b * NC * NP + p;
  const float* ob = outconv + (size_t)b * NC * NP + p;
  float* x1b = x1 + (size_t)b * NC * NP + p;
  #pragma unroll
  for (int o = 0; o < 48; ++o)
    x1b[(size_t)o * NP] = xb[(size_t)o * NP] + acc[o] + ob[(size_t)o * NP];
}

// ---------------- FF: 3-dilation depthwise + gelu gate (row-tiled LDS) ----------------
// block = 1 row x 256 px of one (b,ch); stage 9 rows (3 per branch, dilated), 264-wide.
__global__ __launch_bounds__(256) void k_ffdw(const float* __restrict__ y,
                                              const float* __restrict__ w1,
                                              const float* __restrict__ w2,
                                              const float* __restrict__ w3,
                                              float* __restrict__ z) {
  __shared__ float lds[9 * 264];
  int blk = blockIdx.x;            // b*NHID*NH + ch*NH ... laid out: yy fastest
  int yy = blk & 255;
  int ch = (blk >> 8) % NHID;
  int b = blk / (NHID * 256);
  const float* yb = y + (size_t)(b * 288 + ch) * NP;
  for (int i = threadIdx.x; i < 9 * 264; i += 256) {
    int c = i % 264;
    int r = i / 264;       // 0..8
    int br = r / 3;        // branch 0,1,2
    int rr = r % 3;        // tap row
    int dil = br + 1;
    int iy = yy + (rr - 1) * dil;
    int ix = c - 4;
    float v = 0.f;
    if ((unsigned)iy < (unsigned)NH && (unsigned)ix < (unsigned)NW)
      v = yb[(size_t)(br * NHID) * NP + iy * NW + ix];
    lds[i] = v;
  }
  __syncthreads();
  int x = threadIdx.x;
  const float* wp1 = w1 + ch * 9;   // wave-uniform -> scalar loads
  const float* wp2 = w2 + ch * 9;
  const float* wp3 = w3 + ch * 9;
  float c1 = 0.f, c2 = 0.f, c3 = 0.f;
  #pragma unroll
  for (int r = 0; r < 3; ++r)
    #pragma unroll
    for (int dx = 0; dx < 3; ++dx) {
      int wi = r * 3 + dx;
      c1 = fmaf(lds[(0 + r) * 264 + x + 4 + (dx - 1) * 1], wp1[wi], c1);
      c2 = fmaf(lds[(3 + r) * 264 + x + 4 + (dx - 1) * 2], wp2[wi], c2);
      c3 = fmaf(lds[(6 + r) * 264 + x + 4 + (dx - 1) * 3], wp3[wi], c3);
    }
  z[(size_t)(b * NHID + ch) * NP + yy * NW + x] = gelu_f(c1) * c2 * c3;
}

// ---------------- pout + residual -> d_out (streamed, acc[48]) ----------------
__global__ __launch_bounds__(256, 4) void k_pout(const float* __restrict__ z,
                                                 const float* __restrict__ poutw,
                                                 const float* __restrict__ x1,
                                                 float* __restrict__ outp) {
  int idx = blockIdx.x * blockDim.x + threadIdx.x;  // exact NB*NP
  int b = idx / NP, p = idx % NP;
  const float* zb = z + (size_t)b * NHID * NP + p;
  float acc[48];
  #pragma unroll
  for (int o = 0; o < 48; ++o) acc[o] = 0.f;
  for (int j = 0; j < 96; ++j) {
    float zv = zb[(size_t)j * NP];
    const float* wc = poutw + j;  // poutw[o*96 + j]
    #pragma unroll
    for (int o = 0; o < 48; ++o) acc[o] = fmaf(wc[o * 96], zv, acc[o]);
  }
  const float* x1b = x1 + (size_t)b * NC * NP + p;
  float* ob = outp + (size_t)b * NC * NP + p;
  #pragma unroll
  for (int o = 0; o < 48; ++o)
    ob[(size_t)o * NP] = x1b[(size_t)o * NP] + acc[o];
}

// ---------------- workspace layout (floats) ----------------
constexpr size_t SZ_QKV = (size_t)NB * 144 * NP;       // 18,874,368
constexpr size_t SZ_CHW = (size_t)NB * NC * NP;        // 6,291,456
constexpr size_t OFF_QKV0 = 0;
constexpr size_t OFF_QKVD = OFF_QKV0 + SZ_QKV;
constexpr size_t OFF_FCONV = OFF_QKVD + SZ_QKV;        // y reuses [0, OFF_FCONV)
constexpr size_t SZ_FCONV = (size_t)NB * 54 * NP;
constexpr size_t OFF_OUTCONV = OFF_FCONV + SZ_FCONV;   // z reuses [OFF_FCONV, +NB*96*NP)
constexpr size_t OFF_X1 = OFF_OUTCONV + SZ_CHW;
constexpr size_t OFF_STATS = OFF_X1 + SZ_CHW;          // (stats slot retained, unused)
constexpr size_t OFF_T1 = OFF_STATS + (size_t)NB * NP * 2;
constexpr size_t OFF_P1 = OFF_T1 + (size_t)NB * NC * 128 * 128;
constexpr size_t OFF_T2 = OFF_P1 + (size_t)NB * NC * 64 * 64;
constexpr size_t OFF_P2 = OFF_T2 + (size_t)NB * NC * 32 * 32;
constexpr size_t OFF_T3 = OFF_P2 + (size_t)NB * NC * 16 * 16;
constexpr size_t OFF_P3 = OFF_T3 + (size_t)NB * NC * 8 * 8;
constexpr size_t OFF_Q0M = OFF_P3 + (size_t)NB * NC * 4 * 4;
constexpr size_t OFF_NORMS = OFF_Q0M + 576;
constexpr size_t OFF_SPART = OFF_NORMS + 192;
constexpr size_t OFF_A = OFF_SPART + (size_t)NB * 64 * 36;

extern "C" void kernel_launch(void* const* d_in, const int* in_sizes, int n_in,
                              void* d_out, int out_size, void* d_ws, size_t ws_size,
                              hipStream_t stream) {
  const float* x     = (const float*)d_in[0];
  const float* ln1w  = (const float*)d_in[1];
  const float* ln1b  = (const float*)d_in[2];
  const float* qkvw  = (const float*)d_in[3];
  const float* qkvdw = (const float*)d_in[4];
  const float* projw = (const float*)d_in[5];
  const float* fcw   = (const float*)d_in[6];
  const float* fcb   = (const float*)d_in[7];
  const float* depw  = (const float*)d_in[8];
  const float* depb  = (const float*)d_in[9];
  const float* l2qw  = (const float*)d_in[10];
  const float* l2qb  = (const float*)d_in[11];
  const float* temp  = (const float*)d_in[12];
  const float* ln2w  = (const float*)d_in[13];
  const float* ln2b  = (const float*)d_in[14];
  const float* pinw  = (const float*)d_in[15];
  const float* dw1   = (const float*)d_in[16];
  const float* dw2   = (const float*)d_in[17];
  const float* dw3   = (const float*)d_in[18];
  const float* poutw = (const float*)d_in[19];
  const float* cvw0  = (const float*)d_in[20];
  const float* cvb0  = (const float*)d_in[21];
  const float* clw0  = (const float*)d_in[22];
  const float* clb0  = (const float*)d_in[23];
  const float* cvw1  = (const float*)d_in[24];
  const float* cvb1  = (const float*)d_in[25];
  const float* clw1  = (const float*)d_in[26];
  const float* clb1  = (const float*)d_in[27];
  const float* cvw2  = (const float*)d_in[28];
  const float* cvb2  = (const float*)d_in[29];
  const float* clw2  = (const float*)d_in[30];
  const float* clb2  = (const float*)d_in[31];

  float* ws = (float*)d_ws;
  float* qkv0 = ws + OFF_QKV0;
  float* qkvd = ws + OFF_QKVD;
  float* fconv = ws + OFF_FCONV;
  float* outconv = ws + OFF_OUTCONV;
  float* x1 = ws + OFF_X1;
  float* t1 = ws + OFF_T1;
  float* p1 = ws + OFF_P1;
  float* t2 = ws + OFF_T2;
  float* p2 = ws + OFF_P2;
  float* t3 = ws + OFF_T3;
  float* p3 = ws + OFF_P3;
  float* q0m = ws + OFF_Q0M;
  float* norms = ws + OFF_NORMS;
  float* spart = ws + OFF_SPART;
  float* A = ws + OFF_A;
  float* ybuf = ws + OFF_QKV0;   // reuse qkv0+qkvd (exactly NB*288*NP)
  float* zbuf = ws + OFF_FCONV;  // reuse fconv+outconv (NB*96*NP fits)

  // conv-descriptor branch (LDS-tiled convs)
  k_conv_s2_tile<<<512, 256, 0, stream>>>(x, cvw0, cvb0, t1, 256, 256, 128, 128);
  k_lnpool<<<32, 256, 0, stream>>>(t1, clw0, clb0, p1, 128, 128);
  k_conv_s2_tile<<<32, 256, 0, stream>>>(p1, cvw1, cvb1, t2, 64, 64, 32, 32);
  k_lnpool<<<2, 256, 0, stream>>>(t2, clw1, clb1, p2, 32, 32);
  k_conv_s2_tile<<<2, 256, 0, stream>>>(p2, cvw2, cvb2, t3, 16, 16, 8, 8);
  k_lnpool<<<1, 256, 0, stream>>>(t3, clw2, clb2, p3, 8, 8);
  k_head<<<2, 320, 0, stream>>>(p3, l2qw, l2qb, q0m);

  // attention
  k_chmix_ln<<<1024, 256, 0, stream>>>(x, ln1w, ln1b, qkvw, qkv0, 144, 72);
  k_dw144<<<73728, 256, 0, stream>>>(qkv0, qkvdw, qkvd);
  k_norms<<<192, 256, 0, stream>>>(qkvd, norms);
  k_gram<<<128, 256, 0, stream>>>(qkvd, spart);
  k_attn<<<2, 64, 0, stream>>>(spart, norms, temp, q0m, A);
  k_fc<<<2048, 384, 0, stream>>>(qkvd, fcw, fcb, fconv);
  k_depconv<<<3072, 256, 0, stream>>>(fconv, depw, depb, outconv);
  k_proj<<<512, 256, 0, stream>>>(qkvd, A, projw, x, outconv, x1);

  // feedforward
  k_chmix_ln<<<1024, 256, 0, stream>>>(x1, ln2w, ln2b, pinw, ybuf, 288, 144);
  k_ffdw<<<49152, 256, 0, stream>>>(ybuf, dw1, dw2, dw3, zbuf);
  k_pout<<<512, 256, 0, stream>>>(zbuf, poutw, x1, (float*)d_out);
}

// Round 7
// 745.339 us; speedup vs baseline: 2.9983x; 1.1825x over previous
//
#include <hip/hip_runtime.h>

constexpr int NB = 2;
constexpr int NC = 48;
constexpr int NH = 256;
constexpr int NW = 256;
constexpr int NP = NH * NW;           // 65536
constexpr int NHEADS = 8;
constexpr int NCHD = 6;
constexpr int NHID = 96;

__device__ __forceinline__ float gelu_f(float v) {
  return 0.5f * v * (1.0f + erff(v * 0.70710678118654752f));
}

// tap loop over a 12-float window (3x ds_read_b128), compile-time indices.
#define STENCIL_ROW(LROW, D, WVAL0, WVAL1, WVAL2, ACC)                        \
  {                                                                            \
    const float* lp = &lds[(LROW) * 272 + quad * 4];                           \
    float4 va = *(const float4*)lp;                                            \
    float4 vb = *(const float4*)(lp + 4);                                      \
    float4 vc = *(const float4*)(lp + 8);                                      \
    float v[12] = {va.x, va.y, va.z, va.w, vb.x, vb.y, vb.z, vb.w,             \
                   vc.x, vc.y, vc.z, vc.w};                                    \
    _Pragma("unroll") for (int jj = 0; jj < 4; ++jj) {                         \
      ACC[jj] = fmaf(v[jj - (D) + 4], WVAL0, ACC[jj]);                         \
      ACC[jj] = fmaf(v[jj + 4], WVAL1, ACC[jj]);                               \
      ACC[jj] = fmaf(v[jj + (D) + 4], WVAL2, ACC[jj]);                         \
    }                                                                          \
  }

// ---------------- conv-descriptor branch: LDS-tiled stride-2 3x3 conv ----------------
__global__ __launch_bounds__(256) void k_conv_s2_tile(const float* __restrict__ in,
                                                      const float* __restrict__ w,
                                                      const float* __restrict__ bias,
                                                      float* __restrict__ out,
                                                      int IH, int IW, int OH, int OW) {
  __shared__ float lds[48 * 340];  // 340 = 17 rows * 20 (padded) ... 65280 B
  int tilesX = OW >> 3;
  int tilesY = OH >> 3;
  int blk = blockIdx.x;
  int tx = blk % tilesX;
  int t = blk / tilesX;
  int ty = t % tilesY;
  int b = t / tilesY;
  int oy0 = ty * 8, ox0 = tx * 8;
  int iy0 = oy0 * 2 - 1, ix0 = ox0 * 2 - 1;
  const float* inb = in + (size_t)b * NC * IH * IW;

  for (int i = threadIdx.x; i < 48 * 17 * 20; i += 256) {
    int cc = i % 20;
    int rr = (i / 20) % 17;
    int ic = i / 340;
    float v = 0.f;
    int iy = iy0 + rr, ix = ix0 + cc;
    if (cc < 17 && (unsigned)iy < (unsigned)IH && (unsigned)ix < (unsigned)IW)
      v = inb[((size_t)ic * IH + iy) * IW + ix];
    lds[ic * 340 + rr * 20 + cc] = v;
  }
  __syncthreads();

  int lane = threadIdx.x & 63;
  int oy = lane >> 3, ox = lane & 7;
  int ocb = __builtin_amdgcn_readfirstlane((threadIdx.x >> 6) * 12);
  float acc[12];
  #pragma unroll
  for (int j = 0; j < 12; ++j) acc[j] = bias[ocb + j];
  int pbase = oy * 40 + ox * 2;

  for (int ic = 0; ic < 48; ++ic) {
    float in9[9];
    const float* lp = lds + ic * 340 + pbase;
    #pragma unroll
    for (int ky = 0; ky < 3; ++ky)
      #pragma unroll
      for (int kx = 0; kx < 3; ++kx)
        in9[ky * 3 + kx] = lp[ky * 20 + kx];
    const float* wpc = w + (size_t)(ocb * 48 + ic) * 9;
    #pragma unroll
    for (int j = 0; j < 12; ++j) {
      const float* wp = wpc + (size_t)j * 48 * 9;
      float a = acc[j];
      #pragma unroll
      for (int k = 0; k < 9; ++k) a = fmaf(wp[k], in9[k], a);
      acc[j] = a;
    }
  }

  float* ob = out + (size_t)b * NC * OH * OW;
  #pragma unroll
  for (int j = 0; j < 12; ++j)
    ob[((size_t)(ocb + j) * OH + oy0 + oy) * OW + ox0 + ox] = acc[j];
}

__global__ void k_lnpool(const float* __restrict__ in, const float* __restrict__ lw,
                         const float* __restrict__ lb, float* __restrict__ out,
                         int IH, int IW) {
  int OH = IH >> 1, OW = IW >> 1;
  int idx = blockIdx.x * blockDim.x + threadIdx.x;
  int total = NB * OH * OW;
  if (idx >= total) return;
  int ox = idx % OW;
  int t = idx / OW;
  int oy = t % OH;
  int b = t / OH;
  const float* inb = in + (size_t)b * NC * IH * IW;
  float mu[4], rs[4];
  #pragma unroll
  for (int q = 0; q < 4; ++q) {
    int iy = oy * 2 + (q >> 1), ix = ox * 2 + (q & 1);
    float s = 0.f, ss = 0.f;
    for (int c = 0; c < NC; ++c) {
      float v = inb[((size_t)c * IH + iy) * IW + ix];
      s += v; ss += v * v;
    }
    float m = s * (1.f / NC);
    mu[q] = m;
    rs[q] = rsqrtf(fmaxf(ss * (1.f / NC) - m * m, 0.f) + 1e-5f);
  }
  for (int c = 0; c < NC; ++c) {
    float best = 0.f;  // relu >= 0 so 0 == max of relu'd window
    float wv = lw[c], bv = lb[c];
    #pragma unroll
    for (int q = 0; q < 4; ++q) {
      int iy = oy * 2 + (q >> 1), ix = ox * 2 + (q & 1);
      float v = inb[((size_t)c * IH + iy) * IW + ix];
      v = (v - mu[q]) * rs[q] * wv + bv;
      best = fmaxf(best, fmaxf(v, 0.f));
    }
    out[((size_t)(b * NC + c) * OH + oy) * OW + ox] = best;
  }
}

__global__ void k_head(const float* __restrict__ p3, const float* __restrict__ l2qw,
                       const float* __restrict__ l2qb, float* __restrict__ q0m) {
  __shared__ float xd[NC], q0[NC];
  int b = blockIdx.x, t = threadIdx.x;
  if (t < NC) {
    float s = 0.f;
    for (int i = 0; i < 16; ++i) s += p3[(b * NC + t) * 16 + i];
    xd[t] = gelu_f(s * (1.f / 16.f));
  }
  __syncthreads();
  if (t < NC) {
    float a = l2qb[t];
    for (int c = 0; c < NC; ++c) a += xd[c] * l2qw[t * NC + c];
    q0[t] = a;
  }
  __syncthreads();
  if (t < NHEADS * NCHD * NCHD) {
    int h = t / 36, r = t % 36, c = r / 6, d = r % 6;
    q0m[b * 288 + t] = q0[h * 6 + c] * q0[h * 6 + d];
  }
}

// ---------------- channel-mix (1x1 conv) with LN fused; o-split for occupancy ----------------
__global__ __launch_bounds__(256, 4) void k_chmix_ln(const float* __restrict__ x,
                                                     const float* __restrict__ lnw,
                                                     const float* __restrict__ lnb,
                                                     const float* __restrict__ w,
                                                     float* __restrict__ out,
                                                     int nout, int ochunk) {
  int bid = blockIdx.x;
  int osub = bid >> 9;                           // blocks 512..1023 handle second half
  int idx = ((bid & 511) << 8) + threadIdx.x;    // b*NP + p
  int b = idx / NP, p = idx % NP;
  const float* xb = x + (size_t)b * NC * NP + p;
  float xr[NC];
  float s = 0.f, ss = 0.f;
  #pragma unroll
  for (int c = 0; c < NC; ++c) {
    float v = xb[(size_t)c * NP];
    xr[c] = v; s += v; ss += v * v;
  }
  float mu = s * (1.f / NC);
  float rstd = rsqrtf(fmaxf(ss * (1.f / NC) - mu * mu, 0.f) + 1e-5f);
  #pragma unroll
  for (int c = 0; c < NC; ++c)
    xr[c] = (xr[c] - mu) * rstd * lnw[c] + lnb[c];
  float* ob = out + (size_t)b * nout * NP + p;
  int o0 = osub * ochunk, o1 = o0 + ochunk;
  for (int o = o0; o < o1; ++o) {
    const float* wr = w + o * NC;
    float a = 0.f;
    #pragma unroll
    for (int c = 0; c < NC; ++c) a = fmaf(wr[c], xr[c], a);
    ob[(size_t)o * NP] = a;
  }
}

// ---------------- depthwise 3x3 on 144 channels (4-row stripe, float4) ----------------
// block = 4 rows x 256 px of one (b,ch); stage 6 rows x 272 (x in [-4,267], zero-pad).
__global__ __launch_bounds__(256) void k_dw144(const float* __restrict__ in,
                                               const float* __restrict__ w9,
                                               float* __restrict__ out) {
  __shared__ float lds[6 * 272];
  int blk = blockIdx.x;
  int rq = blk & 63;
  int ch = (blk >> 6) % 144;
  int b = blk / (144 * 64);
  int yy0 = rq * 4;
  const float* ib = in + (size_t)(b * 144 + ch) * NP;
  for (int i = threadIdx.x; i < 6 * 68; i += 256) {
    int sr = i / 68, c4 = i % 68;
    int iy = yy0 + sr - 1;
    float4 v = make_float4(0.f, 0.f, 0.f, 0.f);
    if ((unsigned)iy < (unsigned)NH && c4 >= 1 && c4 <= 64)
      v = *(const float4*)(ib + iy * NW + (c4 - 1) * 4);
    *(float4*)(&lds[sr * 272 + c4 * 4]) = v;
  }
  __syncthreads();
  int q = threadIdx.x >> 6;
  int quad = threadIdx.x & 63;
  const float* wp = w9 + ch * 9;   // wave-uniform -> scalar loads
  float acc[4] = {0.f, 0.f, 0.f, 0.f};
  #pragma unroll
  for (int rr = 0; rr < 3; ++rr)
    STENCIL_ROW(q + rr, 1, wp[rr * 3 + 0], wp[rr * 3 + 1], wp[rr * 3 + 2], acc);
  float4 o4 = make_float4(acc[0], acc[1], acc[2], acc[3]);
  *(float4*)(out + (size_t)(b * 144 + ch) * NP + (yy0 + q) * NW + quad * 4) = o4;
}

// ---------------- per-head Gram (36) + channel ssq (12) partials, fused ----------------
__global__ void k_gram(const float* __restrict__ qkvd, float* __restrict__ spart) {
  int gid = blockIdx.x;  // b*64 + h*8 + seg
  int seg = gid & 7, h = (gid >> 3) & 7, b = gid >> 6;
  const float* qb = qkvd + (size_t)(b * 144 + h * 6) * NP;
  const float* kb = qkvd + (size_t)(b * 144 + 48 + h * 6) * NP;
  float acc[48];
  #pragma unroll
  for (int j = 0; j < 48; ++j) acc[j] = 0.f;
  for (int i = seg * 8192 + threadIdx.x; i < (seg + 1) * 8192; i += 256) {
    float qv[6], kv[6];
    #pragma unroll
    for (int c = 0; c < 6; ++c) { qv[c] = qb[(size_t)c * NP + i]; kv[c] = kb[(size_t)c * NP + i]; }
    #pragma unroll
    for (int c = 0; c < 6; ++c)
      #pragma unroll
      for (int d = 0; d < 6; ++d) acc[c * 6 + d] = fmaf(qv[c], kv[d], acc[c * 6 + d]);
    #pragma unroll
    for (int c = 0; c < 6; ++c) acc[36 + c] = fmaf(qv[c], qv[c], acc[36 + c]);
    #pragma unroll
    for (int d = 0; d < 6; ++d) acc[42 + d] = fmaf(kv[d], kv[d], acc[42 + d]);
  }
  int lane = threadIdx.x & 63, wid = threadIdx.x >> 6;
  __shared__ float sr[4 * 48];
  #pragma unroll
  for (int j = 0; j < 48; ++j) {
    float v = acc[j];
    #pragma unroll
    for (int off = 32; off; off >>= 1) v += __shfl_down(v, off, 64);
    if (lane == 0) sr[wid * 48 + j] = v;
  }
  __syncthreads();
  if (threadIdx.x < 48)
    spart[gid * 48 + threadIdx.x] =
        sr[threadIdx.x] + sr[48 + threadIdx.x] + sr[96 + threadIdx.x] + sr[144 + threadIdx.x];
}

// ---------------- attention softmax (tiny; norms from ssq partials) ----------------
__global__ void k_attn(const float* __restrict__ spart, const float* __restrict__ temp,
                       const float* __restrict__ q0m, float* __restrict__ A) {
  int b = blockIdx.x, t = threadIdx.x;
  if (t >= 48) return;
  int h = t / 6, c = t % 6;
  float qs = 0.f;
  for (int seg = 0; seg < 8; ++seg)
    qs += spart[(size_t)((b * 64 + h * 8 + seg) * 48) + 36 + c];
  float nq = fmaxf(sqrtf(qs), 1e-12f);
  float tm = temp[h];
  float lg[6];
  #pragma unroll
  for (int d = 0; d < 6; ++d) {
    float s = 0.f, ks = 0.f;
    for (int seg = 0; seg < 8; ++seg) {
      const float* base = spart + (size_t)((b * 64 + h * 8 + seg) * 48);
      s += base[c * 6 + d];
      ks += base[42 + d];
    }
    float nk = fmaxf(sqrtf(ks), 1e-12f);
    lg[d] = (s / (nq * nk)) * tm * q0m[b * 288 + h * 36 + c * 6 + d];
  }
  float m = lg[0];
  #pragma unroll
  for (int d = 1; d < 6; ++d) m = fmaxf(m, lg[d]);
  float sum = 0.f;
  #pragma unroll
  for (int d = 0; d < 6; ++d) { lg[d] = expf(lg[d] - m); sum += lg[d]; }
  float inv = 1.f / sum;
  #pragma unroll
  for (int d = 0; d < 6; ++d) A[b * 288 + h * 36 + c * 6 + d] = lg[d] * inv;
}

// ---------------- fc mix over the raw-reshape scramble ----------------
__global__ __launch_bounds__(384) void k_fc(const float* __restrict__ qkvd,
                                            const float* __restrict__ fcw,
                                            const float* __restrict__ fcb,
                                            float* __restrict__ fconv) {
  __shared__ float sin_[9216];   // 64 pixels * 144
  __shared__ float sout[3456];   // 54 ch * 64 pixels
  int blk = blockIdx.x;
  int b = blk >> 10, p0 = (blk & 1023) << 6;
  const float* src = qkvd + (size_t)b * 144 * NP + (size_t)p0 * 144;
  for (int i = threadIdx.x; i < 9216; i += 384) sin_[i] = src[i];
  __syncthreads();
  int pl = threadIdx.x / 6, c2 = threadIdx.x % 6;
  float xv[24];
  #pragma unroll
  for (int g = 0; g < 24; ++g) xv[g] = sin_[pl * 144 + g * 6 + c2];
  #pragma unroll
  for (int o = 0; o < 9; ++o) {
    float a = fcb[o];
    #pragma unroll
    for (int g = 0; g < 24; ++g) a += fcw[o * 24 + g] * xv[g];
    sout[(c2 * 9 + o) * 64 + pl] = a;
  }
  __syncthreads();
  for (int i = threadIdx.x; i < 3456; i += 384) {
    int ch = i >> 6, pl2 = i & 63;
    fconv[(size_t)(b * 54 + ch) * NP + p0 + pl2] = sout[i];
  }
}

// ---------------- grouped dep conv 54->48 (4-row stripe, 9 planes, 8 oc, float4) ----------------
__global__ __launch_bounds__(256) void k_depconv(const float* __restrict__ fconv,
                                                 const float* __restrict__ dw,
                                                 const float* __restrict__ db,
                                                 float* __restrict__ outconv) {
  __shared__ float lds[9 * 6 * 272];  // 58752 B
  int blk = blockIdx.x;               // b*6*64 + g*64 + rq
  int rq = blk & 63;
  int g = (blk >> 6) % 6;
  int b = blk / (6 * 64);
  int yy0 = rq * 4;
  const float* fb = fconv + (size_t)(b * 54 + g * 9) * NP;
  for (int i = threadIdx.x; i < 9 * 6 * 68; i += 256) {
    int j = i / 408;
    int rem = i % 408;
    int sr = rem / 68, c4 = rem % 68;
    int iy = yy0 + sr - 1;
    float4 v = make_float4(0.f, 0.f, 0.f, 0.f);
    if ((unsigned)iy < (unsigned)NH && c4 >= 1 && c4 <= 64)
      v = *(const float4*)(fb + (size_t)j * NP + iy * NW + (c4 - 1) * 4);
    *(float4*)(&lds[(j * 6 + sr) * 272 + c4 * 4]) = v;
  }
  __syncthreads();
  int q = threadIdx.x >> 6;
  int quad = threadIdx.x & 63;
  float acc[8][4];
  #pragma unroll
  for (int o = 0; o < 8; ++o) {
    float bv = db[g * 8 + o];
    #pragma unroll
    for (int jj = 0; jj < 4; ++jj) acc[o][jj] = bv;
  }
  const float* wg = dw + (size_t)(g * 8) * 81;
  #pragma unroll
  for (int j = 0; j < 9; ++j) {
    #pragma unroll
    for (int rr = 0; rr < 3; ++rr) {
      const float* lp = &lds[((j * 6) + q + rr) * 272 + quad * 4];
      float4 va = *(const float4*)lp;
      float4 vb = *(const float4*)(lp + 4);
      float4 vc = *(const float4*)(lp + 8);
      float v[12] = {va.x, va.y, va.z, va.w, vb.x, vb.y, vb.z, vb.w,
                     vc.x, vc.y, vc.z, vc.w};
      #pragma unroll
      for (int dxi = 0; dxi < 3; ++dxi) {
        int wi = j * 9 + rr * 3 + dxi;
        #pragma unroll
        for (int o = 0; o < 8; ++o) {
          float wv = wg[o * 81 + wi];
          #pragma unroll
          for (int jj = 0; jj < 4; ++jj)
            acc[o][jj] = fmaf(v[jj + dxi + 3], wv, acc[o][jj]);
        }
      }
    }
  }
  float* ob = outconv + ((size_t)(b * NC + g * 8) * NH + yy0 + q) * NW + quad * 4;
  #pragma unroll
  for (int o = 0; o < 8; ++o)
    *(float4*)(ob + (size_t)o * NP) = make_float4(acc[o][0], acc[o][1], acc[o][2], acc[o][3]);
}

// ---------------- fused attn@V + proj + out_conv + residual ----------------
__global__ __launch_bounds__(256, 4) void k_proj(const float* __restrict__ qkvd,
                                                 const float* __restrict__ A,
                                                 const float* __restrict__ projw,
                                                 const float* __restrict__ x,
                                                 const float* __restrict__ outconv,
                                                 float* __restrict__ x1) {
  int idx = blockIdx.x * blockDim.x + threadIdx.x;  // exact NB*NP
  int b = idx / NP, p = idx % NP;
  __shared__ float sA[288];
  for (int i = threadIdx.x; i < 288; i += 256) sA[i] = A[b * 288 + i];
  __syncthreads();
  const float* vb = qkvd + (size_t)(b * 144 + 96) * NP + p;
  float acc[48];
  #pragma unroll
  for (int o = 0; o < 48; ++o) acc[o] = 0.f;
  for (int h = 0; h < 8; ++h) {
    float v6[6];
    #pragma unroll
    for (int d = 0; d < 6; ++d) v6[d] = vb[(size_t)(h * 6 + d) * NP];
    #pragma unroll
    for (int c = 0; c < 6; ++c) {
      float av = 0.f;
      #pragma unroll
      for (int d = 0; d < 6; ++d) av = fmaf(sA[h * 36 + c * 6 + d], v6[d], av);
      const float* wc = projw + h * 6 + c;  // projw[o*48 + (h*6+c)]
      #pragma unroll
      for (int o = 0; o < 48; ++o) acc[o] = fmaf(wc[o * 48], av, acc[o]);
    }
  }
  const float* xb = x + (size_t)b * NC * NP + p;
  const float* ob = outconv + (size_t)b * NC * NP + p;
  float* x1b = x1 + (size_t)b * NC * NP + p;
  #pragma unroll
  for (int o = 0; o < 48; ++o)
    x1b[(size_t)o * NP] = xb[(size_t)o * NP] + acc[o] + ob[(size_t)o * NP];
}

// ---------------- FF: 3-dilation depthwise + gelu gate (4-row stripe, float4) ----------------
// stage 24 rows: br1 rows[0..5]=yy0-1..+4, br2 rows[6..13]=yy0-2..+5, br3 rows[14..23]=yy0-3..+6
__global__ __launch_bounds__(256) void k_ffdw(const float* __restrict__ y,
                                              const float* __restrict__ w1,
                                              const float* __restrict__ w2,
                                              const float* __restrict__ w3,
                                              float* __restrict__ z) {
  __shared__ float lds[24 * 272];  // 26112 B
  int blk = blockIdx.x;
  int rq = blk & 63;
  int ch = (blk >> 6) % NHID;
  int b = blk / (NHID * 64);
  int yy0 = rq * 4;
  const float* yb = y + (size_t)(b * 288 + ch) * NP;
  for (int i = threadIdx.x; i < 24 * 68; i += 256) {
    int sr = i / 68, c4 = i % 68;
    int br, iy;
    if (sr < 6)       { br = 0; iy = yy0 + sr - 1; }
    else if (sr < 14) { br = 1; iy = yy0 + sr - 8; }
    else              { br = 2; iy = yy0 + sr - 17; }
    float4 v = make_float4(0.f, 0.f, 0.f, 0.f);
    if ((unsigned)iy < (unsigned)NH && c4 >= 1 && c4 <= 64)
      v = *(const float4*)(yb + (size_t)(br * NHID) * NP + iy * NW + (c4 - 1) * 4);
    *(float4*)(&lds[sr * 272 + c4 * 4]) = v;
  }
  __syncthreads();
  int q = threadIdx.x >> 6;
  int quad = threadIdx.x & 63;
  const float* wp1 = w1 + ch * 9;   // wave-uniform -> scalar loads
  const float* wp2 = w2 + ch * 9;
  const float* wp3 = w3 + ch * 9;
  float c1[4] = {0.f, 0.f, 0.f, 0.f};
  float c2[4] = {0.f, 0.f, 0.f, 0.f};
  float c3[4] = {0.f, 0.f, 0.f, 0.f};
  #pragma unroll
  for (int rr = 0; rr < 3; ++rr)
    STENCIL_ROW(0 + q + rr * 1, 1, wp1[rr * 3 + 0], wp1[rr * 3 + 1], wp1[rr * 3 + 2], c1);
  #pragma unroll
  for (int rr = 0; rr < 3; ++rr)
    STENCIL_ROW(6 + q + rr * 2, 2, wp2[rr * 3 + 0], wp2[rr * 3 + 1], wp2[rr * 3 + 2], c2);
  #pragma unroll
  for (int rr = 0; rr < 3; ++rr)
    STENCIL_ROW(14 + q + rr * 3, 3, wp3[rr * 3 + 0], wp3[rr * 3 + 1], wp3[rr * 3 + 2], c3);
  float4 o4;
  o4.x = gelu_f(c1[0]) * c2[0] * c3[0];
  o4.y = gelu_f(c1[1]) * c2[1] * c3[1];
  o4.z = gelu_f(c1[2]) * c2[2] * c3[2];
  o4.w = gelu_f(c1[3]) * c2[3] * c3[3];
  *(float4*)(z + (size_t)(b * NHID + ch) * NP + (yy0 + q) * NW + quad * 4) = o4;
}

// ---------------- pout + residual -> d_out (streamed, acc[48]) ----------------
__global__ __launch_bounds__(256, 4) void k_pout(const float* __restrict__ z,
                                                 const float* __restrict__ poutw,
                                                 const float* __restrict__ x1,
                                                 float* __restrict__ outp) {
  int idx = blockIdx.x * blockDim.x + threadIdx.x;  // exact NB*NP
  int b = idx / NP, p = idx % NP;
  const float* zb = z + (size_t)b * NHID * NP + p;
  float acc[48];
  #pragma unroll
  for (int o = 0; o < 48; ++o) acc[o] = 0.f;
  for (int j = 0; j < 96; ++j) {
    float zv = zb[(size_t)j * NP];
    const float* wc = poutw + j;  // poutw[o*96 + j]
    #pragma unroll
    for (int o = 0; o < 48; ++o) acc[o] = fmaf(wc[o * 96], zv, acc[o]);
  }
  const float* x1b = x1 + (size_t)b * NC * NP + p;
  float* ob = outp + (size_t)b * NC * NP + p;
  #pragma unroll
  for (int o = 0; o < 48; ++o)
    ob[(size_t)o * NP] = x1b[(size_t)o * NP] + acc[o];
}

// ---------------- workspace layout (floats) ----------------
constexpr size_t SZ_QKV = (size_t)NB * 144 * NP;       // 18,874,368
constexpr size_t SZ_CHW = (size_t)NB * NC * NP;        // 6,291,456
constexpr size_t OFF_QKV0 = 0;
constexpr size_t OFF_QKVD = OFF_QKV0 + SZ_QKV;
constexpr size_t OFF_FCONV = OFF_QKVD + SZ_QKV;        // y reuses [0, OFF_FCONV)
constexpr size_t SZ_FCONV = (size_t)NB * 54 * NP;
constexpr size_t OFF_OUTCONV = OFF_FCONV + SZ_FCONV;   // z reuses [OFF_FCONV, +NB*96*NP)
constexpr size_t OFF_X1 = OFF_OUTCONV + SZ_CHW;
constexpr size_t OFF_STATS = OFF_X1 + SZ_CHW;          // (slot retained, unused)
constexpr size_t OFF_T1 = OFF_STATS + (size_t)NB * NP * 2;
constexpr size_t OFF_P1 = OFF_T1 + (size_t)NB * NC * 128 * 128;
constexpr size_t OFF_T2 = OFF_P1 + (size_t)NB * NC * 64 * 64;
constexpr size_t OFF_P2 = OFF_T2 + (size_t)NB * NC * 32 * 32;
constexpr size_t OFF_T3 = OFF_P2 + (size_t)NB * NC * 16 * 16;
constexpr size_t OFF_P3 = OFF_T3 + (size_t)NB * NC * 8 * 8;
constexpr size_t OFF_Q0M = OFF_P3 + (size_t)NB * NC * 4 * 4;
constexpr size_t OFF_NORMS = OFF_Q0M + 576;            // unused now
constexpr size_t OFF_SPART = OFF_NORMS + 192;
constexpr size_t OFF_A = OFF_SPART + (size_t)NB * 64 * 48;

extern "C" void kernel_launch(void* const* d_in, const int* in_sizes, int n_in,
                              void* d_out, int out_size, void* d_ws, size_t ws_size,
                              hipStream_t stream) {
  const float* x     = (const float*)d_in[0];
  const float* ln1w  = (const float*)d_in[1];
  const float* ln1b  = (const float*)d_in[2];
  const float* qkvw  = (const float*)d_in[3];
  const float* qkvdw = (const float*)d_in[4];
  const float* projw = (const float*)d_in[5];
  const float* fcw   = (const float*)d_in[6];
  const float* fcb   = (const float*)d_in[7];
  const float* depw  = (const float*)d_in[8];
  const float* depb  = (const float*)d_in[9];
  const float* l2qw  = (const float*)d_in[10];
  const float* l2qb  = (const float*)d_in[11];
  const float* temp  = (const float*)d_in[12];
  const float* ln2w  = (const float*)d_in[13];
  const float* ln2b  = (const float*)d_in[14];
  const float* pinw  = (const float*)d_in[15];
  const float* dw1   = (const float*)d_in[16];
  const float* dw2   = (const float*)d_in[17];
  const float* dw3   = (const float*)d_in[18];
  const float* poutw = (const float*)d_in[19];
  const float* cvw0  = (const float*)d_in[20];
  const float* cvb0  = (const float*)d_in[21];
  const float* clw0  = (const float*)d_in[22];
  const float* clb0  = (const float*)d_in[23];
  const float* cvw1  = (const float*)d_in[24];
  const float* cvb1  = (const float*)d_in[25];
  const float* clw1  = (const float*)d_in[26];
  const float* clb1  = (const float*)d_in[27];
  const float* cvw2  = (const float*)d_in[28];
  const float* cvb2  = (const float*)d_in[29];
  const float* clw2  = (const float*)d_in[30];
  const float* clb2  = (const float*)d_in[31];

  float* ws = (float*)d_ws;
  float* qkv0 = ws + OFF_QKV0;
  float* qkvd = ws + OFF_QKVD;
  float* fconv = ws + OFF_FCONV;
  float* outconv = ws + OFF_OUTCONV;
  float* x1 = ws + OFF_X1;
  float* t1 = ws + OFF_T1;
  float* p1 = ws + OFF_P1;
  float* t2 = ws + OFF_T2;
  float* p2 = ws + OFF_P2;
  float* t3 = ws + OFF_T3;
  float* p3 = ws + OFF_P3;
  float* q0m = ws + OFF_Q0M;
  float* spart = ws + OFF_SPART;
  float* A = ws + OFF_A;
  float* ybuf = ws + OFF_QKV0;   // reuse qkv0+qkvd (exactly NB*288*NP)
  float* zbuf = ws + OFF_FCONV;  // reuse fconv+outconv (NB*96*NP fits)

  // conv-descriptor branch (LDS-tiled convs)
  k_conv_s2_tile<<<512, 256, 0, stream>>>(x, cvw0, cvb0, t1, 256, 256, 128, 128);
  k_lnpool<<<32, 256, 0, stream>>>(t1, clw0, clb0, p1, 128, 128);
  k_conv_s2_tile<<<32, 256, 0, stream>>>(p1, cvw1, cvb1, t2, 64, 64, 32, 32);
  k_lnpool<<<2, 256, 0, stream>>>(t2, clw1, clb1, p2, 32, 32);
  k_conv_s2_tile<<<2, 256, 0, stream>>>(p2, cvw2, cvb2, t3, 16, 16, 8, 8);
  k_lnpool<<<1, 256, 0, stream>>>(t3, clw2, clb2, p3, 8, 8);
  k_head<<<2, 320, 0, stream>>>(p3, l2qw, l2qb, q0m);

  // attention
  k_chmix_ln<<<1024, 256, 0, stream>>>(x, ln1w, ln1b, qkvw, qkv0, 144, 72);
  k_dw144<<<18432, 256, 0, stream>>>(qkv0, qkvdw, qkvd);
  k_gram<<<128, 256, 0, stream>>>(qkvd, spart);
  k_attn<<<2, 64, 0, stream>>>(spart, temp, q0m, A);
  k_fc<<<2048, 384, 0, stream>>>(qkvd, fcw, fcb, fconv);
  k_depconv<<<768, 256, 0, stream>>>(fconv, depw, depb, outconv);
  k_proj<<<512, 256, 0, stream>>>(qkvd, A, projw, x, outconv, x1);

  // feedforward
  k_chmix_ln<<<1024, 256, 0, stream>>>(x1, ln2w, ln2b, pinw, ybuf, 288, 144);
  k_ffdw<<<12288, 256, 0, stream>>>(ybuf, dw1, dw2, dw3, zbuf);
  k_pout<<<512, 256, 0, stream>>>(zbuf, poutw, x1, (float*)d_out);
}

// Round 8
// 700.970 us; speedup vs baseline: 3.1881x; 1.0633x over previous
//
#include <hip/hip_runtime.h>

constexpr int NB = 2;
constexpr int NC = 48;
constexpr int NH = 256;
constexpr int NW = 256;
constexpr int NP = NH * NW;           // 65536
constexpr int NHEADS = 8;
constexpr int NCHD = 6;
constexpr int NHID = 96;

__device__ __forceinline__ float gelu_f(float v) {
  return 0.5f * v * (1.0f + erff(v * 0.70710678118654752f));
}

// tap loop over a 12-float window (3x ds_read_b128), compile-time indices.
#define STENCIL_ROW(LROW, D, WVAL0, WVAL1, WVAL2, ACC)                        \
  {                                                                            \
    const float* lp = &lds[(LROW) * 272 + quad * 4];                           \
    float4 va = *(const float4*)lp;                                            \
    float4 vb = *(const float4*)(lp + 4);                                      \
    float4 vc = *(const float4*)(lp + 8);                                      \
    float v[12] = {va.x, va.y, va.z, va.w, vb.x, vb.y, vb.z, vb.w,             \
                   vc.x, vc.y, vc.z, vc.w};                                    \
    _Pragma("unroll") for (int jj = 0; jj < 4; ++jj) {                         \
      ACC[jj] = fmaf(v[jj - (D) + 4], WVAL0, ACC[jj]);                         \
      ACC[jj] = fmaf(v[jj + 4], WVAL1, ACC[jj]);                               \
      ACC[jj] = fmaf(v[jj + (D) + 4], WVAL2, ACC[jj]);                         \
    }                                                                          \
  }

// ---------------- conv-descriptor branch: LDS-tiled stride-2 3x3 conv ----------------
__global__ __launch_bounds__(256) void k_conv_s2_tile(const float* __restrict__ in,
                                                      const float* __restrict__ w,
                                                      const float* __restrict__ bias,
                                                      float* __restrict__ out,
                                                      int IH, int IW, int OH, int OW) {
  __shared__ float lds[48 * 340];  // 340 = 17 rows * 20 (padded) ... 65280 B
  int tilesX = OW >> 3;
  int tilesY = OH >> 3;
  int blk = blockIdx.x;
  int tx = blk % tilesX;
  int t = blk / tilesX;
  int ty = t % tilesY;
  int b = t / tilesY;
  int oy0 = ty * 8, ox0 = tx * 8;
  int iy0 = oy0 * 2 - 1, ix0 = ox0 * 2 - 1;
  const float* inb = in + (size_t)b * NC * IH * IW;

  for (int i = threadIdx.x; i < 48 * 17 * 20; i += 256) {
    int cc = i % 20;
    int rr = (i / 20) % 17;
    int ic = i / 340;
    float v = 0.f;
    int iy = iy0 + rr, ix = ix0 + cc;
    if (cc < 17 && (unsigned)iy < (unsigned)IH && (unsigned)ix < (unsigned)IW)
      v = inb[((size_t)ic * IH + iy) * IW + ix];
    lds[ic * 340 + rr * 20 + cc] = v;
  }
  __syncthreads();

  int lane = threadIdx.x & 63;
  int oy = lane >> 3, ox = lane & 7;
  int ocb = __builtin_amdgcn_readfirstlane((threadIdx.x >> 6) * 12);
  float acc[12];
  #pragma unroll
  for (int j = 0; j < 12; ++j) acc[j] = bias[ocb + j];
  int pbase = oy * 40 + ox * 2;

  for (int ic = 0; ic < 48; ++ic) {
    float in9[9];
    const float* lp = lds + ic * 340 + pbase;
    #pragma unroll
    for (int ky = 0; ky < 3; ++ky)
      #pragma unroll
      for (int kx = 0; kx < 3; ++kx)
        in9[ky * 3 + kx] = lp[ky * 20 + kx];
    const float* wpc = w + (size_t)(ocb * 48 + ic) * 9;
    #pragma unroll
    for (int j = 0; j < 12; ++j) {
      const float* wp = wpc + (size_t)j * 48 * 9;
      float a = acc[j];
      #pragma unroll
      for (int k = 0; k < 9; ++k) a = fmaf(wp[k], in9[k], a);
      acc[j] = a;
    }
  }

  float* ob = out + (size_t)b * NC * OH * OW;
  #pragma unroll
  for (int j = 0; j < 12; ++j)
    ob[((size_t)(ocb + j) * OH + oy0 + oy) * OW + ox0 + ox] = acc[j];
}

__global__ void k_lnpool(const float* __restrict__ in, const float* __restrict__ lw,
                         const float* __restrict__ lb, float* __restrict__ out,
                         int IH, int IW) {
  int OH = IH >> 1, OW = IW >> 1;
  int idx = blockIdx.x * blockDim.x + threadIdx.x;
  int total = NB * OH * OW;
  if (idx >= total) return;
  int ox = idx % OW;
  int t = idx / OW;
  int oy = t % OH;
  int b = t / OH;
  const float* inb = in + (size_t)b * NC * IH * IW;
  float mu[4], rs[4];
  #pragma unroll
  for (int q = 0; q < 4; ++q) {
    int iy = oy * 2 + (q >> 1), ix = ox * 2 + (q & 1);
    float s = 0.f, ss = 0.f;
    for (int c = 0; c < NC; ++c) {
      float v = inb[((size_t)c * IH + iy) * IW + ix];
      s += v; ss += v * v;
    }
    float m = s * (1.f / NC);
    mu[q] = m;
    rs[q] = rsqrtf(fmaxf(ss * (1.f / NC) - m * m, 0.f) + 1e-5f);
  }
  for (int c = 0; c < NC; ++c) {
    float best = 0.f;  // relu >= 0 so 0 == max of relu'd window
    float wv = lw[c], bv = lb[c];
    #pragma unroll
    for (int q = 0; q < 4; ++q) {
      int iy = oy * 2 + (q >> 1), ix = ox * 2 + (q & 1);
      float v = inb[((size_t)c * IH + iy) * IW + ix];
      v = (v - mu[q]) * rs[q] * wv + bv;
      best = fmaxf(best, fmaxf(v, 0.f));
    }
    out[((size_t)(b * NC + c) * OH + oy) * OW + ox] = best;
  }
}

__global__ void k_head(const float* __restrict__ p3, const float* __restrict__ l2qw,
                       const float* __restrict__ l2qb, float* __restrict__ q0m) {
  __shared__ float xd[NC], q0[NC];
  int b = blockIdx.x, t = threadIdx.x;
  if (t < NC) {
    float s = 0.f;
    for (int i = 0; i < 16; ++i) s += p3[(b * NC + t) * 16 + i];
    xd[t] = gelu_f(s * (1.f / 16.f));
  }
  __syncthreads();
  if (t < NC) {
    float a = l2qb[t];
    for (int c = 0; c < NC; ++c) a += xd[c] * l2qw[t * NC + c];
    q0[t] = a;
  }
  __syncthreads();
  if (t < NHEADS * NCHD * NCHD) {
    int h = t / 36, r = t % 36, c = r / 6, d = r % 6;
    q0m[b * 288 + t] = q0[h * 6 + c] * q0[h * 6 + d];
  }
}

// ---------------- S[o] = sum_c W[o][c]*lnw[c], B[o] = sum_c W[o][c]*lnb[c] ----------------
__global__ void k_prep(const float* __restrict__ qkvw, const float* __restrict__ ln1w,
                       const float* __restrict__ ln1b, const float* __restrict__ pinw,
                       const float* __restrict__ ln2w, const float* __restrict__ ln2b,
                       float* __restrict__ SB) {
  int t = blockIdx.x * blockDim.x + threadIdx.x;
  if (t < 144) {
    float s = 0.f, bb = 0.f;
    for (int c = 0; c < 48; ++c) {
      float w = qkvw[t * 48 + c];
      s = fmaf(w, ln1w[c], s); bb = fmaf(w, ln1b[c], bb);
    }
    SB[t] = s; SB[144 + t] = bb;
  } else if (t < 144 + 288) {
    int o = t - 144;
    float s = 0.f, bb = 0.f;
    for (int c = 0; c < 48; ++c) {
      float w = pinw[o * 48 + c];
      s = fmaf(w, ln2w[c], s); bb = fmaf(w, ln2b[c], bb);
    }
    SB[288 + o] = s; SB[576 + o] = bb;
  }
}

// ---------------- per-pixel LN stats (vectorized x4) ----------------
__global__ __launch_bounds__(256) void k_lnstats4(const float* __restrict__ x,
                                                  float2* __restrict__ stats) {
  int idx = blockIdx.x * blockDim.x + threadIdx.x;   // NB*NP/4
  int b = idx / (NP / 4), p4 = idx % (NP / 4);
  const float* xb = x + (size_t)b * NC * NP + p4 * 4;
  float s[4] = {0.f, 0.f, 0.f, 0.f}, ss[4] = {0.f, 0.f, 0.f, 0.f};
  #pragma unroll
  for (int c = 0; c < NC; ++c) {
    float4 v = *(const float4*)(xb + (size_t)c * NP);
    s[0] += v.x; ss[0] = fmaf(v.x, v.x, ss[0]);
    s[1] += v.y; ss[1] = fmaf(v.y, v.y, ss[1]);
    s[2] += v.z; ss[2] = fmaf(v.z, v.z, ss[2]);
    s[3] += v.w; ss[3] = fmaf(v.w, v.w, ss[3]);
  }
  float4 r0, r1;
  float mu0 = s[0] * (1.f / NC); r0.x = mu0;
  r0.y = rsqrtf(fmaxf(ss[0] * (1.f / NC) - mu0 * mu0, 0.f) + 1e-5f);
  float mu1 = s[1] * (1.f / NC); r0.z = mu1;
  r0.w = rsqrtf(fmaxf(ss[1] * (1.f / NC) - mu1 * mu1, 0.f) + 1e-5f);
  float mu2 = s[2] * (1.f / NC); r1.x = mu2;
  r1.y = rsqrtf(fmaxf(ss[2] * (1.f / NC) - mu2 * mu2, 0.f) + 1e-5f);
  float mu3 = s[3] * (1.f / NC); r1.z = mu3;
  r1.w = rsqrtf(fmaxf(ss[3] * (1.f / NC) - mu3 * mu3, 0.f) + 1e-5f);
  float4* sp = (float4*)(stats + (size_t)b * NP + p4 * 4);
  sp[0] = r0; sp[1] = r1;
}

// ---------------- channel-mix GEMM: LDS x-tile, reg-blocked 12 oc x 4 px ----------------
// out[o][p] = rstd[p]*(sum_c W[o][c]*lnw[c]*x[c][p] - mu[p]*S[o]) + B[o]
__global__ __launch_bounds__(256) void k_chmix_gemm(const float* __restrict__ x,
                                                    const float* __restrict__ lnw,
                                                    const float* __restrict__ w,
                                                    const float* __restrict__ S,
                                                    const float* __restrict__ Bc,
                                                    const float2* __restrict__ stats,
                                                    float* __restrict__ out,
                                                    int nout, int nch) {
  __shared__ float lds[48 * 256];  // 49152 B
  int blk = blockIdx.x;
  int och = blk % nch;
  int pxt = (blk / nch) & 255;
  int b = blk / (nch * 256);
  int pxbase = pxt * 256;
  const float* xb = x + (size_t)b * NC * NP + pxbase;
  for (int i = threadIdx.x; i < 48 * 64; i += 256) {
    int k = i >> 6, c4 = i & 63;
    float4 v = *(const float4*)(xb + (size_t)k * NP + c4 * 4);
    float lw = lnw[k];  // wave-uniform
    v.x *= lw; v.y *= lw; v.z *= lw; v.w *= lw;
    *(float4*)&lds[k * 256 + c4 * 4] = v;
  }
  __syncthreads();
  int lane = threadIdx.x & 63;
  int obase = __builtin_amdgcn_readfirstlane(och * 48 + (threadIdx.x >> 6) * 12);
  float acc[12][4];
  #pragma unroll
  for (int j = 0; j < 12; ++j)
    #pragma unroll
    for (int jj = 0; jj < 4; ++jj) acc[j][jj] = 0.f;
  for (int k = 0; k < 48; ++k) {
    float4 xv = *(const float4*)&lds[k * 256 + lane * 4];
    const float* wr = w + (size_t)obase * 48 + k;
    #pragma unroll
    for (int j = 0; j < 12; ++j) {
      float wv = wr[j * 48];  // scalar load (uniform)
      acc[j][0] = fmaf(wv, xv.x, acc[j][0]);
      acc[j][1] = fmaf(wv, xv.y, acc[j][1]);
      acc[j][2] = fmaf(wv, xv.z, acc[j][2]);
      acc[j][3] = fmaf(wv, xv.w, acc[j][3]);
    }
  }
  const float2* sp = stats + (size_t)b * NP + pxbase + lane * 4;
  float2 st0 = sp[0], st1 = sp[1], st2 = sp[2], st3 = sp[3];
  float* ob = out + (size_t)b * nout * NP + pxbase + lane * 4;
  #pragma unroll
  for (int j = 0; j < 12; ++j) {
    int o = obase + j;
    float Sv = S[o], Bv = Bc[o];
    float4 r;
    r.x = fmaf(st0.y, acc[j][0] - st0.x * Sv, Bv);
    r.y = fmaf(st1.y, acc[j][1] - st1.x * Sv, Bv);
    r.z = fmaf(st2.y, acc[j][2] - st2.x * Sv, Bv);
    r.w = fmaf(st3.y, acc[j][3] - st3.x * Sv, Bv);
    *(float4*)(ob + (size_t)o * NP) = r;
  }
}

// ---------------- depthwise 3x3 on 144 channels (4-row stripe, float4) ----------------
__global__ __launch_bounds__(256) void k_dw144(const float* __restrict__ in,
                                               const float* __restrict__ w9,
                                               float* __restrict__ out) {
  __shared__ float lds[6 * 272];
  int blk = blockIdx.x;
  int rq = blk & 63;
  int ch = (blk >> 6) % 144;
  int b = blk / (144 * 64);
  int yy0 = rq * 4;
  const float* ib = in + (size_t)(b * 144 + ch) * NP;
  for (int i = threadIdx.x; i < 6 * 68; i += 256) {
    int sr = i / 68, c4 = i % 68;
    int iy = yy0 + sr - 1;
    float4 v = make_float4(0.f, 0.f, 0.f, 0.f);
    if ((unsigned)iy < (unsigned)NH && c4 >= 1 && c4 <= 64)
      v = *(const float4*)(ib + iy * NW + (c4 - 1) * 4);
    *(float4*)(&lds[sr * 272 + c4 * 4]) = v;
  }
  __syncthreads();
  int q = threadIdx.x >> 6;
  int quad = threadIdx.x & 63;
  const float* wp = w9 + ch * 9;   // wave-uniform -> scalar loads
  float acc[4] = {0.f, 0.f, 0.f, 0.f};
  #pragma unroll
  for (int rr = 0; rr < 3; ++rr)
    STENCIL_ROW(q + rr, 1, wp[rr * 3 + 0], wp[rr * 3 + 1], wp[rr * 3 + 2], acc);
  float4 o4 = make_float4(acc[0], acc[1], acc[2], acc[3]);
  *(float4*)(out + (size_t)(b * 144 + ch) * NP + (yy0 + q) * NW + quad * 4) = o4;
}

// ---------------- per-head Gram (36) + channel ssq (12) partials, fused ----------------
__global__ void k_gram(const float* __restrict__ qkvd, float* __restrict__ spart) {
  int gid = blockIdx.x;  // b*64 + h*8 + seg
  int seg = gid & 7, h = (gid >> 3) & 7, b = gid >> 6;
  const float* qb = qkvd + (size_t)(b * 144 + h * 6) * NP;
  const float* kb = qkvd + (size_t)(b * 144 + 48 + h * 6) * NP;
  float acc[48];
  #pragma unroll
  for (int j = 0; j < 48; ++j) acc[j] = 0.f;
  for (int i = seg * 8192 + threadIdx.x; i < (seg + 1) * 8192; i += 256) {
    float qv[6], kv[6];
    #pragma unroll
    for (int c = 0; c < 6; ++c) { qv[c] = qb[(size_t)c * NP + i]; kv[c] = kb[(size_t)c * NP + i]; }
    #pragma unroll
    for (int c = 0; c < 6; ++c)
      #pragma unroll
      for (int d = 0; d < 6; ++d) acc[c * 6 + d] = fmaf(qv[c], kv[d], acc[c * 6 + d]);
    #pragma unroll
    for (int c = 0; c < 6; ++c) acc[36 + c] = fmaf(qv[c], qv[c], acc[36 + c]);
    #pragma unroll
    for (int d = 0; d < 6; ++d) acc[42 + d] = fmaf(kv[d], kv[d], acc[42 + d]);
  }
  int lane = threadIdx.x & 63, wid = threadIdx.x >> 6;
  __shared__ float sr[4 * 48];
  #pragma unroll
  for (int j = 0; j < 48; ++j) {
    float v = acc[j];
    #pragma unroll
    for (int off = 32; off; off >>= 1) v += __shfl_down(v, off, 64);
    if (lane == 0) sr[wid * 48 + j] = v;
  }
  __syncthreads();
  if (threadIdx.x < 48)
    spart[gid * 48 + threadIdx.x] =
        sr[threadIdx.x] + sr[48 + threadIdx.x] + sr[96 + threadIdx.x] + sr[144 + threadIdx.x];
}

// ---------------- attention softmax (tiny; norms from ssq partials) ----------------
__global__ void k_attn(const float* __restrict__ spart, const float* __restrict__ temp,
                       const float* __restrict__ q0m, float* __restrict__ A) {
  int b = blockIdx.x, t = threadIdx.x;
  if (t >= 48) return;
  int h = t / 6, c = t % 6;
  float qs = 0.f;
  for (int seg = 0; seg < 8; ++seg)
    qs += spart[(size_t)((b * 64 + h * 8 + seg) * 48) + 36 + c];
  float nq = fmaxf(sqrtf(qs), 1e-12f);
  float tm = temp[h];
  float lg[6];
  #pragma unroll
  for (int d = 0; d < 6; ++d) {
    float s = 0.f, ks = 0.f;
    for (int seg = 0; seg < 8; ++seg) {
      const float* base = spart + (size_t)((b * 64 + h * 8 + seg) * 48);
      s += base[c * 6 + d];
      ks += base[42 + d];
    }
    float nk = fmaxf(sqrtf(ks), 1e-12f);
    lg[d] = (s / (nq * nk)) * tm * q0m[b * 288 + h * 36 + c * 6 + d];
  }
  float m = lg[0];
  #pragma unroll
  for (int d = 1; d < 6; ++d) m = fmaxf(m, lg[d]);
  float sum = 0.f;
  #pragma unroll
  for (int d = 0; d < 6; ++d) { lg[d] = expf(lg[d] - m); sum += lg[d]; }
  float inv = 1.f / sum;
  #pragma unroll
  for (int d = 0; d < 6; ++d) A[b * 288 + h * 36 + c * 6 + d] = lg[d] * inv;
}

// ---------------- fc mix over the raw-reshape scramble ----------------
__global__ __launch_bounds__(384) void k_fc(const float* __restrict__ qkvd,
                                            const float* __restrict__ fcw,
                                            const float* __restrict__ fcb,
                                            float* __restrict__ fconv) {
  __shared__ float sin_[9216];   // 64 pixels * 144
  __shared__ float sout[3456];   // 54 ch * 64 pixels
  int blk = blockIdx.x;
  int b = blk >> 10, p0 = (blk & 1023) << 6;
  const float* src = qkvd + (size_t)b * 144 * NP + (size_t)p0 * 144;
  for (int i = threadIdx.x; i < 9216; i += 384) sin_[i] = src[i];
  __syncthreads();
  int pl = threadIdx.x / 6, c2 = threadIdx.x % 6;
  float xv[24];
  #pragma unroll
  for (int g = 0; g < 24; ++g) xv[g] = sin_[pl * 144 + g * 6 + c2];
  #pragma unroll
  for (int o = 0; o < 9; ++o) {
    float a = fcb[o];
    #pragma unroll
    for (int g = 0; g < 24; ++g) a += fcw[o * 24 + g] * xv[g];
    sout[(c2 * 9 + o) * 64 + pl] = a;
  }
  __syncthreads();
  for (int i = threadIdx.x; i < 3456; i += 384) {
    int ch = i >> 6, pl2 = i & 63;
    fconv[(size_t)(b * 54 + ch) * NP + p0 + pl2] = sout[i];
  }
}

// ---------------- grouped dep conv 54->48 (4-row stripe, 9 planes, 8 oc, float4) ----------------
__global__ __launch_bounds__(256) void k_depconv(const float* __restrict__ fconv,
                                                 const float* __restrict__ dw,
                                                 const float* __restrict__ db,
                                                 float* __restrict__ outconv) {
  __shared__ float lds[9 * 6 * 272];  // 58752 B
  int blk = blockIdx.x;               // b*6*64 + g*64 + rq
  int rq = blk & 63;
  int g = (blk >> 6) % 6;
  int b = blk / (6 * 64);
  int yy0 = rq * 4;
  const float* fb = fconv + (size_t)(b * 54 + g * 9) * NP;
  for (int i = threadIdx.x; i < 9 * 6 * 68; i += 256) {
    int j = i / 408;
    int rem = i % 408;
    int sr = rem / 68, c4 = rem % 68;
    int iy = yy0 + sr - 1;
    float4 v = make_float4(0.f, 0.f, 0.f, 0.f);
    if ((unsigned)iy < (unsigned)NH && c4 >= 1 && c4 <= 64)
      v = *(const float4*)(fb + (size_t)j * NP + iy * NW + (c4 - 1) * 4);
    *(float4*)(&lds[(j * 6 + sr) * 272 + c4 * 4]) = v;
  }
  __syncthreads();
  int q = threadIdx.x >> 6;
  int quad = threadIdx.x & 63;
  float acc[8][4];
  #pragma unroll
  for (int o = 0; o < 8; ++o) {
    float bv = db[g * 8 + o];
    #pragma unroll
    for (int jj = 0; jj < 4; ++jj) acc[o][jj] = bv;
  }
  const float* wg = dw + (size_t)(g * 8) * 81;
  #pragma unroll
  for (int j = 0; j < 9; ++j) {
    #pragma unroll
    for (int rr = 0; rr < 3; ++rr) {
      const float* lp = &lds[((j * 6) + q + rr) * 272 + quad * 4];
      float4 va = *(const float4*)lp;
      float4 vb = *(const float4*)(lp + 4);
      float4 vc = *(const float4*)(lp + 8);
      float v[12] = {va.x, va.y, va.z, va.w, vb.x, vb.y, vb.z, vb.w,
                     vc.x, vc.y, vc.z, vc.w};
      #pragma unroll
      for (int dxi = 0; dxi < 3; ++dxi) {
        int wi = j * 9 + rr * 3 + dxi;
        #pragma unroll
        for (int o = 0; o < 8; ++o) {
          float wv = wg[o * 81 + wi];
          #pragma unroll
          for (int jj = 0; jj < 4; ++jj)
            acc[o][jj] = fmaf(v[jj + dxi + 3], wv, acc[o][jj]);
        }
      }
    }
  }
  float* ob = outconv + ((size_t)(b * NC + g * 8) * NH + yy0 + q) * NW + quad * 4;
  #pragma unroll
  for (int o = 0; o < 8; ++o)
    *(float4*)(ob + (size_t)o * NP) = make_float4(acc[o][0], acc[o][1], acc[o][2], acc[o][3]);
}

// ---------------- fused attn@V + proj + out_conv + residual ----------------
__global__ __launch_bounds__(256, 4) void k_proj(const float* __restrict__ qkvd,
                                                 const float* __restrict__ A,
                                                 const float* __restrict__ projw,
                                                 const float* __restrict__ x,
                                                 const float* __restrict__ outconv,
                                                 float* __restrict__ x1) {
  int idx = blockIdx.x * blockDim.x + threadIdx.x;  // exact NB*NP
  int b = idx / NP, p = idx % NP;
  __shared__ float sA[288];
  for (int i = threadIdx.x; i < 288; i += 256) sA[i] = A[b * 288 + i];
  __syncthreads();
  const float* vb = qkvd + (size_t)(b * 144 + 96) * NP + p;
  float acc[48];
  #pragma unroll
  for (int o = 0; o < 48; ++o) acc[o] = 0.f;
  for (int h = 0; h < 8; ++h) {
    float v6[6];
    #pragma unroll
    for (int d = 0; d < 6; ++d) v6[d] = vb[(size_t)(h * 6 + d) * NP];
    #pragma unroll
    for (int c = 0; c < 6; ++c) {
      float av = 0.f;
      #pragma unroll
      for (int d = 0; d < 6; ++d) av = fmaf(sA[h * 36 + c * 6 + d], v6[d], av);
      const float* wc = projw + h * 6 + c;  // projw[o*48 + (h*6+c)]
      #pragma unroll
      for (int o = 0; o < 48; ++o) acc[o] = fmaf(wc[o * 48], av, acc[o]);
    }
  }
  const float* xb = x + (size_t)b * NC * NP + p;
  const float* ob = outconv + (size_t)b * NC * NP + p;
  float* x1b = x1 + (size_t)b * NC * NP + p;
  #pragma unroll
  for (int o = 0; o < 48; ++o)
    x1b[(size_t)o * NP] = xb[(size_t)o * NP] + acc[o] + ob[(size_t)o * NP];
}

// ---------------- FF: 3-dilation depthwise + gelu gate (4-row stripe, float4) ----------------
__global__ __launch_bounds__(256) void k_ffdw(const float* __restrict__ y,
                                              const float* __restrict__ w1,
                                              const float* __restrict__ w2,
                                              const float* __restrict__ w3,
                                              float* __restrict__ z) {
  __shared__ float lds[24 * 272];  // 26112 B
  int blk = blockIdx.x;
  int rq = blk & 63;
  int ch = (blk >> 6) % NHID;
  int b = blk / (NHID * 64);
  int yy0 = rq * 4;
  const float* yb = y + (size_t)(b * 288 + ch) * NP;
  for (int i = threadIdx.x; i < 24 * 68; i += 256) {
    int sr = i / 68, c4 = i % 68;
    int br, iy;
    if (sr < 6)       { br = 0; iy = yy0 + sr - 1; }
    else if (sr < 14) { br = 1; iy = yy0 + sr - 8; }
    else              { br = 2; iy = yy0 + sr - 17; }
    float4 v = make_float4(0.f, 0.f, 0.f, 0.f);
    if ((unsigned)iy < (unsigned)NH && c4 >= 1 && c4 <= 64)
      v = *(const float4*)(yb + (size_t)(br * NHID) * NP + iy * NW + (c4 - 1) * 4);
    *(float4*)(&lds[sr * 272 + c4 * 4]) = v;
  }
  __syncthreads();
  int q = threadIdx.x >> 6;
  int quad = threadIdx.x & 63;
  const float* wp1 = w1 + ch * 9;   // wave-uniform -> scalar loads
  const float* wp2 = w2 + ch * 9;
  const float* wp3 = w3 + ch * 9;
  float c1[4] = {0.f, 0.f, 0.f, 0.f};
  float c2[4] = {0.f, 0.f, 0.f, 0.f};
  float c3[4] = {0.f, 0.f, 0.f, 0.f};
  #pragma unroll
  for (int rr = 0; rr < 3; ++rr)
    STENCIL_ROW(0 + q + rr * 1, 1, wp1[rr * 3 + 0], wp1[rr * 3 + 1], wp1[rr * 3 + 2], c1);
  #pragma unroll
  for (int rr = 0; rr < 3; ++rr)
    STENCIL_ROW(6 + q + rr * 2, 2, wp2[rr * 3 + 0], wp2[rr * 3 + 1], wp2[rr * 3 + 2], c2);
  #pragma unroll
  for (int rr = 0; rr < 3; ++rr)
    STENCIL_ROW(14 + q + rr * 3, 3, wp3[rr * 3 + 0], wp3[rr * 3 + 1], wp3[rr * 3 + 2], c3);
  float4 o4;
  o4.x = gelu_f(c1[0]) * c2[0] * c3[0];
  o4.y = gelu_f(c1[1]) * c2[1] * c3[1];
  o4.z = gelu_f(c1[2]) * c2[2] * c3[2];
  o4.w = gelu_f(c1[3]) * c2[3] * c3[3];
  *(float4*)(z + (size_t)(b * NHID + ch) * NP + (yy0 + q) * NW + quad * 4) = o4;
}

// ---------------- pout + residual -> d_out (streamed, acc[48]) ----------------
__global__ __launch_bounds__(256, 4) void k_pout(const float* __restrict__ z,
                                                 const float* __restrict__ poutw,
                                                 const float* __restrict__ x1,
                                                 float* __restrict__ outp) {
  int idx = blockIdx.x * blockDim.x + threadIdx.x;  // exact NB*NP
  int b = idx / NP, p = idx % NP;
  const float* zb = z + (size_t)b * NHID * NP + p;
  float acc[48];
  #pragma unroll
  for (int o = 0; o < 48; ++o) acc[o] = 0.f;
  for (int j = 0; j < 96; ++j) {
    float zv = zb[(size_t)j * NP];
    const float* wc = poutw + j;  // poutw[o*96 + j]
    #pragma unroll
    for (int o = 0; o < 48; ++o) acc[o] = fmaf(wc[o * 96], zv, acc[o]);
  }
  const float* x1b = x1 + (size_t)b * NC * NP + p;
  float* ob = outp + (size_t)b * NC * NP + p;
  #pragma unroll
  for (int o = 0; o < 48; ++o)
    ob[(size_t)o * NP] = x1b[(size_t)o * NP] + acc[o];
}

// ---------------- workspace layout (floats) ----------------
constexpr size_t SZ_QKV = (size_t)NB * 144 * NP;       // 18,874,368
constexpr size_t SZ_CHW = (size_t)NB * NC * NP;        // 6,291,456
constexpr size_t OFF_QKV0 = 0;
constexpr size_t OFF_QKVD = OFF_QKV0 + SZ_QKV;
constexpr size_t OFF_FCONV = OFF_QKVD + SZ_QKV;        // y reuses [0, OFF_FCONV)
constexpr size_t SZ_FCONV = (size_t)NB * 54 * NP;
constexpr size_t OFF_OUTCONV = OFF_FCONV + SZ_FCONV;   // z reuses [OFF_FCONV, +NB*96*NP)
constexpr size_t OFF_X1 = OFF_OUTCONV + SZ_CHW;
constexpr size_t OFF_STATS = OFF_X1 + SZ_CHW;          // float2 stats [NB*NP]
constexpr size_t OFF_T1 = OFF_STATS + (size_t)NB * NP * 2;
constexpr size_t OFF_P1 = OFF_T1 + (size_t)NB * NC * 128 * 128;
constexpr size_t OFF_T2 = OFF_P1 + (size_t)NB * NC * 64 * 64;
constexpr size_t OFF_P2 = OFF_T2 + (size_t)NB * NC * 32 * 32;
constexpr size_t OFF_T3 = OFF_P2 + (size_t)NB * NC * 16 * 16;   // reused for SB after conv branch
constexpr size_t OFF_P3 = OFF_T3 + (size_t)NB * NC * 8 * 8;
constexpr size_t OFF_Q0M = OFF_P3 + (size_t)NB * NC * 4 * 4;
constexpr size_t OFF_NORMS = OFF_Q0M + 576;            // unused
constexpr size_t OFF_SPART = OFF_NORMS + 192;
constexpr size_t OFF_A = OFF_SPART + (size_t)NB * 64 * 48;

extern "C" void kernel_launch(void* const* d_in, const int* in_sizes, int n_in,
                              void* d_out, int out_size, void* d_ws, size_t ws_size,
                              hipStream_t stream) {
  const float* x     = (const float*)d_in[0];
  const float* ln1w  = (const float*)d_in[1];
  const float* ln1b  = (const float*)d_in[2];
  const float* qkvw  = (const float*)d_in[3];
  const float* qkvdw = (const float*)d_in[4];
  const float* projw = (const float*)d_in[5];
  const float* fcw   = (const float*)d_in[6];
  const float* fcb   = (const float*)d_in[7];
  const float* depw  = (const float*)d_in[8];
  const float* depb  = (const float*)d_in[9];
  const float* l2qw  = (const float*)d_in[10];
  const float* l2qb  = (const float*)d_in[11];
  const float* temp  = (const float*)d_in[12];
  const float* ln2w  = (const float*)d_in[13];
  const float* ln2b  = (const float*)d_in[14];
  const float* pinw  = (const float*)d_in[15];
  const float* dw1   = (const float*)d_in[16];
  const float* dw2   = (const float*)d_in[17];
  const float* dw3   = (const float*)d_in[18];
  const float* poutw = (const float*)d_in[19];
  const float* cvw0  = (const float*)d_in[20];
  const float* cvb0  = (const float*)d_in[21];
  const float* clw0  = (const float*)d_in[22];
  const float* clb0  = (const float*)d_in[23];
  const float* cvw1  = (const float*)d_in[24];
  const float* cvb1  = (const float*)d_in[25];
  const float* clw1  = (const float*)d_in[26];
  const float* clb1  = (const float*)d_in[27];
  const float* cvw2  = (const float*)d_in[28];
  const float* cvb2  = (const float*)d_in[29];
  const float* clw2  = (const float*)d_in[30];
  const float* clb2  = (const float*)d_in[31];

  float* ws = (float*)d_ws;
  float* qkv0 = ws + OFF_QKV0;
  float* qkvd = ws + OFF_QKVD;
  float* fconv = ws + OFF_FCONV;
  float* outconv = ws + OFF_OUTCONV;
  float* x1 = ws + OFF_X1;
  float2* stats = (float2*)(ws + OFF_STATS);
  float* t1 = ws + OFF_T1;
  float* p1 = ws + OFF_P1;
  float* t2 = ws + OFF_T2;
  float* p2 = ws + OFF_P2;
  float* t3 = ws + OFF_T3;
  float* p3 = ws + OFF_P3;
  float* q0m = ws + OFF_Q0M;
  float* spart = ws + OFF_SPART;
  float* A = ws + OFF_A;
  float* SB = ws + OFF_T3;       // reuse t3 region after conv branch (864 floats)
  float* ybuf = ws + OFF_QKV0;   // reuse qkv0+qkvd (exactly NB*288*NP)
  float* zbuf = ws + OFF_FCONV;  // reuse fconv+outconv (NB*96*NP fits)

  // conv-descriptor branch (LDS-tiled convs)
  k_conv_s2_tile<<<512, 256, 0, stream>>>(x, cvw0, cvb0, t1, 256, 256, 128, 128);
  k_lnpool<<<32, 256, 0, stream>>>(t1, clw0, clb0, p1, 128, 128);
  k_conv_s2_tile<<<32, 256, 0, stream>>>(p1, cvw1, cvb1, t2, 64, 64, 32, 32);
  k_lnpool<<<2, 256, 0, stream>>>(t2, clw1, clb1, p2, 32, 32);
  k_conv_s2_tile<<<2, 256, 0, stream>>>(p2, cvw2, cvb2, t3, 16, 16, 8, 8);
  k_lnpool<<<1, 256, 0, stream>>>(t3, clw2, clb2, p3, 8, 8);
  k_head<<<2, 320, 0, stream>>>(p3, l2qw, l2qb, q0m);

  // LN folding setup (after conv branch frees t3 region)
  k_prep<<<2, 256, 0, stream>>>(qkvw, ln1w, ln1b, pinw, ln2w, ln2b, SB);

  // attention
  k_lnstats4<<<128, 256, 0, stream>>>(x, stats);
  k_chmix_gemm<<<1536, 256, 0, stream>>>(x, ln1w, qkvw, SB, SB + 144, stats, qkv0, 144, 3);
  k_dw144<<<18432, 256, 0, stream>>>(qkv0, qkvdw, qkvd);
  k_gram<<<128, 256, 0, stream>>>(qkvd, spart);
  k_attn<<<2, 64, 0, stream>>>(spart, temp, q0m, A);
  k_fc<<<2048, 384, 0, stream>>>(qkvd, fcw, fcb, fconv);
  k_depconv<<<768, 256, 0, stream>>>(fconv, depw, depb, outconv);
  k_proj<<<512, 256, 0, stream>>>(qkvd, A, projw, x, outconv, x1);

  // feedforward
  k_lnstats4<<<128, 256, 0, stream>>>(x1, stats);
  k_chmix_gemm<<<3072, 256, 0, stream>>>(x1, ln2w, pinw, SB + 288, SB + 576, stats, ybuf, 288, 6);
  k_ffdw<<<12288, 256, 0, stream>>>(ybuf, dw1, dw2, dw3, zbuf);
  k_pout<<<512, 256, 0, stream>>>(zbuf, poutw, x1, (float*)d_out);
}

// Round 9
// 667.373 us; speedup vs baseline: 3.3486x; 1.0503x over previous
//
#include <hip/hip_runtime.h>

constexpr int NB = 2;
constexpr int NC = 48;
constexpr int NH = 256;
constexpr int NW = 256;
constexpr int NP = NH * NW;           // 65536
constexpr int NHEADS = 8;
constexpr int NCHD = 6;
constexpr int NHID = 96;

__device__ __forceinline__ float gelu_f(float v) {
  return 0.5f * v * (1.0f + erff(v * 0.70710678118654752f));
}

// tap loop over a 12-float window (3x ds_read_b128), compile-time indices.
#define STENCIL_ROW(LROW, D, WVAL0, WVAL1, WVAL2, ACC)                        \
  {                                                                            \
    const float* lp = &lds[(LROW) * 272 + quad * 4];                           \
    float4 va = *(const float4*)lp;                                            \
    float4 vb = *(const float4*)(lp + 4);                                      \
    float4 vc = *(const float4*)(lp + 8);                                      \
    float v[12] = {va.x, va.y, va.z, va.w, vb.x, vb.y, vb.z, vb.w,             \
                   vc.x, vc.y, vc.z, vc.w};                                    \
    _Pragma("unroll") for (int jj = 0; jj < 4; ++jj) {                         \
      ACC[jj] = fmaf(v[jj - (D) + 4], WVAL0, ACC[jj]);                         \
      ACC[jj] = fmaf(v[jj + 4], WVAL1, ACC[jj]);                               \
      ACC[jj] = fmaf(v[jj + (D) + 4], WVAL2, ACC[jj]);                         \
    }                                                                          \
  }

// ---------------- conv-descriptor branch: ic-chunked LDS stride-2 3x3 conv ----------------
// Block: 8x8 output tile, all 48 oc (12 per wave). ic staged in 3 chunks of 16.
// Parity-de-interleaved LDS rows (stride 26): even cols at [0..8], odd at [13..20].
// Taps become lane-stride-1 reads: ds_read2_b32 (kx=0,2) + ds_read_b32 (kx=1).
__global__ __launch_bounds__(256) void k_conv_s2_tile(const float* __restrict__ in,
                                                      const float* __restrict__ w,
                                                      const float* __restrict__ bias,
                                                      float* __restrict__ out,
                                                      int IH, int IW, int OH, int OW) {
  __shared__ float lds[16 * 442];  // 16 ic * 17 rows * 26 = 28288 B
  int tilesX = OW >> 3;
  int tilesY = OH >> 3;
  int blk = blockIdx.x;
  int tx = blk % tilesX;
  int t = blk / tilesX;
  int ty = t % tilesY;
  int b = t / tilesY;
  int oy0 = ty * 8, ox0 = tx * 8;
  int iy0 = oy0 * 2 - 1, ix0 = ox0 * 2 - 1;
  const float* inb = in + (size_t)b * NC * IH * IW;

  int lane = threadIdx.x & 63;
  int oy = lane >> 3, ox = lane & 7;
  int ocb = __builtin_amdgcn_readfirstlane((threadIdx.x >> 6) * 12);
  float acc[12];
  #pragma unroll
  for (int j = 0; j < 12; ++j) acc[j] = bias[ocb + j];
  int rbase = oy * 52;  // row 2*oy, stride 26

  for (int chunk = 0; chunk < 3; ++chunk) {
    int icb = chunk * 16;
    for (int i = threadIdx.x; i < 16 * 17 * 17; i += 256) {
      int cc = i % 17;
      int t2 = i / 17;
      int rr = t2 % 17;
      int ic = t2 / 17;
      float v = 0.f;
      int iy = iy0 + rr, ix = ix0 + cc;
      if ((unsigned)iy < (unsigned)IH && (unsigned)ix < (unsigned)IW)
        v = inb[((size_t)(icb + ic) * IH + iy) * IW + ix];
      lds[ic * 442 + rr * 26 + ((cc & 1) ? 13 + (cc >> 1) : (cc >> 1))] = v;
    }
    __syncthreads();

    for (int ic16 = 0; ic16 < 16; ++ic16) {
      const float* base = lds + ic16 * 442 + rbase;
      float e0[3], e1[3], ov[3];
      #pragma unroll
      for (int ky = 0; ky < 3; ++ky) {
        const float* rowp = base + ky * 26;
        e0[ky] = rowp[ox];        // kx=0 (even col 2ox)
        e1[ky] = rowp[ox + 1];    // kx=2 (even col 2ox+2)
        ov[ky] = rowp[13 + ox];   // kx=1 (odd col 2ox+1)
      }
      const float* wpc = w + (size_t)(ocb * 48 + icb + ic16) * 9;
      #pragma unroll
      for (int j = 0; j < 12; ++j) {
        const float* wp = wpc + (size_t)j * 48 * 9;
        float a = acc[j];
        #pragma unroll
        for (int ky = 0; ky < 3; ++ky) {
          a = fmaf(wp[ky * 3 + 0], e0[ky], a);
          a = fmaf(wp[ky * 3 + 1], ov[ky], a);
          a = fmaf(wp[ky * 3 + 2], e1[ky], a);
        }
        acc[j] = a;
      }
    }
    __syncthreads();
  }

  float* ob = out + (size_t)b * NC * OH * OW;
  #pragma unroll
  for (int j = 0; j < 12; ++j)
    ob[((size_t)(ocb + j) * OH + oy0 + oy) * OW + ox0 + ox] = acc[j];
}

__global__ void k_lnpool(const float* __restrict__ in, const float* __restrict__ lw,
                         const float* __restrict__ lb, float* __restrict__ out,
                         int IH, int IW) {
  int OH = IH >> 1, OW = IW >> 1;
  int idx = blockIdx.x * blockDim.x + threadIdx.x;
  int total = NB * OH * OW;
  if (idx >= total) return;
  int ox = idx % OW;
  int t = idx / OW;
  int oy = t % OH;
  int b = t / OH;
  const float* inb = in + (size_t)b * NC * IH * IW;
  float mu[4], rs[4];
  #pragma unroll
  for (int q = 0; q < 4; ++q) {
    int iy = oy * 2 + (q >> 1), ix = ox * 2 + (q & 1);
    float s = 0.f, ss = 0.f;
    for (int c = 0; c < NC; ++c) {
      float v = inb[((size_t)c * IH + iy) * IW + ix];
      s += v; ss += v * v;
    }
    float m = s * (1.f / NC);
    mu[q] = m;
    rs[q] = rsqrtf(fmaxf(ss * (1.f / NC) - m * m, 0.f) + 1e-5f);
  }
  for (int c = 0; c < NC; ++c) {
    float best = 0.f;  // relu >= 0 so 0 == max of relu'd window
    float wv = lw[c], bv = lb[c];
    #pragma unroll
    for (int q = 0; q < 4; ++q) {
      int iy = oy * 2 + (q >> 1), ix = ox * 2 + (q & 1);
      float v = inb[((size_t)c * IH + iy) * IW + ix];
      v = (v - mu[q]) * rs[q] * wv + bv;
      best = fmaxf(best, fmaxf(v, 0.f));
    }
    out[((size_t)(b * NC + c) * OH + oy) * OW + ox] = best;
  }
}

__global__ void k_head(const float* __restrict__ p3, const float* __restrict__ l2qw,
                       const float* __restrict__ l2qb, float* __restrict__ q0m) {
  __shared__ float xd[NC], q0[NC];
  int b = blockIdx.x, t = threadIdx.x;
  if (t < NC) {
    float s = 0.f;
    for (int i = 0; i < 16; ++i) s += p3[(b * NC + t) * 16 + i];
    xd[t] = gelu_f(s * (1.f / 16.f));
  }
  __syncthreads();
  if (t < NC) {
    float a = l2qb[t];
    for (int c = 0; c < NC; ++c) a += xd[c] * l2qw[t * NC + c];
    q0[t] = a;
  }
  __syncthreads();
  if (t < NHEADS * NCHD * NCHD) {
    int h = t / 36, r = t % 36, c = r / 6, d = r % 6;
    q0m[b * 288 + t] = q0[h * 6 + c] * q0[h * 6 + d];
  }
}

// ---------------- S[o] = sum_c W[o][c]*lnw[c], B[o] = sum_c W[o][c]*lnb[c] ----------------
__global__ void k_prep(const float* __restrict__ qkvw, const float* __restrict__ ln1w,
                       const float* __restrict__ ln1b, const float* __restrict__ pinw,
                       const float* __restrict__ ln2w, const float* __restrict__ ln2b,
                       float* __restrict__ SB) {
  int t = blockIdx.x * blockDim.x + threadIdx.x;
  if (t < 144) {
    float s = 0.f, bb = 0.f;
    for (int c = 0; c < 48; ++c) {
      float w = qkvw[t * 48 + c];
      s = fmaf(w, ln1w[c], s); bb = fmaf(w, ln1b[c], bb);
    }
    SB[t] = s; SB[144 + t] = bb;
  } else if (t < 144 + 288) {
    int o = t - 144;
    float s = 0.f, bb = 0.f;
    for (int c = 0; c < 48; ++c) {
      float w = pinw[o * 48 + c];
      s = fmaf(w, ln2w[c], s); bb = fmaf(w, ln2b[c], bb);
    }
    SB[288 + o] = s; SB[576 + o] = bb;
  }
}

// ---------------- per-pixel LN stats (vectorized x4) ----------------
__global__ __launch_bounds__(256) void k_lnstats4(const float* __restrict__ x,
                                                  float2* __restrict__ stats) {
  int idx = blockIdx.x * blockDim.x + threadIdx.x;   // NB*NP/4
  int b = idx / (NP / 4), p4 = idx % (NP / 4);
  const float* xb = x + (size_t)b * NC * NP + p4 * 4;
  float s[4] = {0.f, 0.f, 0.f, 0.f}, ss[4] = {0.f, 0.f, 0.f, 0.f};
  #pragma unroll
  for (int c = 0; c < NC; ++c) {
    float4 v = *(const float4*)(xb + (size_t)c * NP);
    s[0] += v.x; ss[0] = fmaf(v.x, v.x, ss[0]);
    s[1] += v.y; ss[1] = fmaf(v.y, v.y, ss[1]);
    s[2] += v.z; ss[2] = fmaf(v.z, v.z, ss[2]);
    s[3] += v.w; ss[3] = fmaf(v.w, v.w, ss[3]);
  }
  float4 r0, r1;
  float mu0 = s[0] * (1.f / NC); r0.x = mu0;
  r0.y = rsqrtf(fmaxf(ss[0] * (1.f / NC) - mu0 * mu0, 0.f) + 1e-5f);
  float mu1 = s[1] * (1.f / NC); r0.z = mu1;
  r0.w = rsqrtf(fmaxf(ss[1] * (1.f / NC) - mu1 * mu1, 0.f) + 1e-5f);
  float mu2 = s[2] * (1.f / NC); r1.x = mu2;
  r1.y = rsqrtf(fmaxf(ss[2] * (1.f / NC) - mu2 * mu2, 0.f) + 1e-5f);
  float mu3 = s[3] * (1.f / NC); r1.z = mu3;
  r1.w = rsqrtf(fmaxf(ss[3] * (1.f / NC) - mu3 * mu3, 0.f) + 1e-5f);
  float4* sp = (float4*)(stats + (size_t)b * NP + p4 * 4);
  sp[0] = r0; sp[1] = r1;
}

// ---------------- channel-mix GEMM: LDS x-tile, reg-blocked 12 oc x 4 px ----------------
// out[o][p] = rstd[p]*(sum_c W[o][c]*lnw[c]*x[c][p] - mu[p]*S[o]) + B[o]
__global__ __launch_bounds__(256) void k_chmix_gemm(const float* __restrict__ x,
                                                    const float* __restrict__ lnw,
                                                    const float* __restrict__ w,
                                                    const float* __restrict__ S,
                                                    const float* __restrict__ Bc,
                                                    const float2* __restrict__ stats,
                                                    float* __restrict__ out,
                                                    int nout, int nch) {
  __shared__ float lds[48 * 256];  // 49152 B
  int blk = blockIdx.x;
  int och = blk % nch;
  int pxt = (blk / nch) & 255;
  int b = blk / (nch * 256);
  int pxbase = pxt * 256;
  const float* xb = x + (size_t)b * NC * NP + pxbase;
  for (int i = threadIdx.x; i < 48 * 64; i += 256) {
    int k = i >> 6, c4 = i & 63;
    float4 v = *(const float4*)(xb + (size_t)k * NP + c4 * 4);
    float lw = lnw[k];  // wave-uniform
    v.x *= lw; v.y *= lw; v.z *= lw; v.w *= lw;
    *(float4*)&lds[k * 256 + c4 * 4] = v;
  }
  __syncthreads();
  int lane = threadIdx.x & 63;
  int obase = __builtin_amdgcn_readfirstlane(och * 48 + (threadIdx.x >> 6) * 12);
  float acc[12][4];
  #pragma unroll
  for (int j = 0; j < 12; ++j)
    #pragma unroll
    for (int jj = 0; jj < 4; ++jj) acc[j][jj] = 0.f;
  for (int k = 0; k < 48; ++k) {
    float4 xv = *(const float4*)&lds[k * 256 + lane * 4];
    const float* wr = w + (size_t)obase * 48 + k;
    #pragma unroll
    for (int j = 0; j < 12; ++j) {
      float wv = wr[j * 48];  // scalar load (uniform)
      acc[j][0] = fmaf(wv, xv.x, acc[j][0]);
      acc[j][1] = fmaf(wv, xv.y, acc[j][1]);
      acc[j][2] = fmaf(wv, xv.z, acc[j][2]);
      acc[j][3] = fmaf(wv, xv.w, acc[j][3]);
    }
  }
  const float2* sp = stats + (size_t)b * NP + pxbase + lane * 4;
  float2 st0 = sp[0], st1 = sp[1], st2 = sp[2], st3 = sp[3];
  float* ob = out + (size_t)b * nout * NP + pxbase + lane * 4;
  #pragma unroll
  for (int j = 0; j < 12; ++j) {
    int o = obase + j;
    float Sv = S[o], Bv = Bc[o];
    float4 r;
    r.x = fmaf(st0.y, acc[j][0] - st0.x * Sv, Bv);
    r.y = fmaf(st1.y, acc[j][1] - st1.x * Sv, Bv);
    r.z = fmaf(st2.y, acc[j][2] - st2.x * Sv, Bv);
    r.w = fmaf(st3.y, acc[j][3] - st3.x * Sv, Bv);
    *(float4*)(ob + (size_t)o * NP) = r;
  }
}

// ---------------- depthwise 3x3 on 144 channels (4-row stripe, float4) ----------------
__global__ __launch_bounds__(256) void k_dw144(const float* __restrict__ in,
                                               const float* __restrict__ w9,
                                               float* __restrict__ out) {
  __shared__ float lds[6 * 272];
  int blk = blockIdx.x;
  int rq = blk & 63;
  int ch = (blk >> 6) % 144;
  int b = blk / (144 * 64);
  int yy0 = rq * 4;
  const float* ib = in + (size_t)(b * 144 + ch) * NP;
  for (int i = threadIdx.x; i < 6 * 68; i += 256) {
    int sr = i / 68, c4 = i % 68;
    int iy = yy0 + sr - 1;
    float4 v = make_float4(0.f, 0.f, 0.f, 0.f);
    if ((unsigned)iy < (unsigned)NH && c4 >= 1 && c4 <= 64)
      v = *(const float4*)(ib + iy * NW + (c4 - 1) * 4);
    *(float4*)(&lds[sr * 272 + c4 * 4]) = v;
  }
  __syncthreads();
  int q = threadIdx.x >> 6;
  int quad = threadIdx.x & 63;
  const float* wp = w9 + ch * 9;   // wave-uniform -> scalar loads
  float acc[4] = {0.f, 0.f, 0.f, 0.f};
  #pragma unroll
  for (int rr = 0; rr < 3; ++rr)
    STENCIL_ROW(q + rr, 1, wp[rr * 3 + 0], wp[rr * 3 + 1], wp[rr * 3 + 2], acc);
  float4 o4 = make_float4(acc[0], acc[1], acc[2], acc[3]);
  *(float4*)(out + (size_t)(b * 144 + ch) * NP + (yy0 + q) * NW + quad * 4) = o4;
}

// ---------------- per-head Gram (36) + channel ssq (12) partials, fused ----------------
__global__ void k_gram(const float* __restrict__ qkvd, float* __restrict__ spart) {
  int gid = blockIdx.x;  // b*64 + h*8 + seg
  int seg = gid & 7, h = (gid >> 3) & 7, b = gid >> 6;
  const float* qb = qkvd + (size_t)(b * 144 + h * 6) * NP;
  const float* kb = qkvd + (size_t)(b * 144 + 48 + h * 6) * NP;
  float acc[48];
  #pragma unroll
  for (int j = 0; j < 48; ++j) acc[j] = 0.f;
  for (int i = seg * 8192 + threadIdx.x; i < (seg + 1) * 8192; i += 256) {
    float qv[6], kv[6];
    #pragma unroll
    for (int c = 0; c < 6; ++c) { qv[c] = qb[(size_t)c * NP + i]; kv[c] = kb[(size_t)c * NP + i]; }
    #pragma unroll
    for (int c = 0; c < 6; ++c)
      #pragma unroll
      for (int d = 0; d < 6; ++d) acc[c * 6 + d] = fmaf(qv[c], kv[d], acc[c * 6 + d]);
    #pragma unroll
    for (int c = 0; c < 6; ++c) acc[36 + c] = fmaf(qv[c], qv[c], acc[36 + c]);
    #pragma unroll
    for (int d = 0; d < 6; ++d) acc[42 + d] = fmaf(kv[d], kv[d], acc[42 + d]);
  }
  int lane = threadIdx.x & 63, wid = threadIdx.x >> 6;
  __shared__ float sr[4 * 48];
  #pragma unroll
  for (int j = 0; j < 48; ++j) {
    float v = acc[j];
    #pragma unroll
    for (int off = 32; off; off >>= 1) v += __shfl_down(v, off, 64);
    if (lane == 0) sr[wid * 48 + j] = v;
  }
  __syncthreads();
  if (threadIdx.x < 48)
    spart[gid * 48 + threadIdx.x] =
        sr[threadIdx.x] + sr[48 + threadIdx.x] + sr[96 + threadIdx.x] + sr[144 + threadIdx.x];
}

// ---------------- attention softmax (tiny; norms from ssq partials) ----------------
__global__ void k_attn(const float* __restrict__ spart, const float* __restrict__ temp,
                       const float* __restrict__ q0m, float* __restrict__ A) {
  int b = blockIdx.x, t = threadIdx.x;
  if (t >= 48) return;
  int h = t / 6, c = t % 6;
  float qs = 0.f;
  for (int seg = 0; seg < 8; ++seg)
    qs += spart[(size_t)((b * 64 + h * 8 + seg) * 48) + 36 + c];
  float nq = fmaxf(sqrtf(qs), 1e-12f);
  float tm = temp[h];
  float lg[6];
  #pragma unroll
  for (int d = 0; d < 6; ++d) {
    float s = 0.f, ks = 0.f;
    for (int seg = 0; seg < 8; ++seg) {
      const float* base = spart + (size_t)((b * 64 + h * 8 + seg) * 48);
      s += base[c * 6 + d];
      ks += base[42 + d];
    }
    float nk = fmaxf(sqrtf(ks), 1e-12f);
    lg[d] = (s / (nq * nk)) * tm * q0m[b * 288 + h * 36 + c * 6 + d];
  }
  float m = lg[0];
  #pragma unroll
  for (int d = 1; d < 6; ++d) m = fmaxf(m, lg[d]);
  float sum = 0.f;
  #pragma unroll
  for (int d = 0; d < 6; ++d) { lg[d] = expf(lg[d] - m); sum += lg[d]; }
  float inv = 1.f / sum;
  #pragma unroll
  for (int d = 0; d < 6; ++d) A[b * 288 + h * 36 + c * 6 + d] = lg[d] * inv;
}

// ---------------- fc mix over the raw-reshape scramble ----------------
__global__ __launch_bounds__(384) void k_fc(const float* __restrict__ qkvd,
                                            const float* __restrict__ fcw,
                                            const float* __restrict__ fcb,
                                            float* __restrict__ fconv) {
  __shared__ float sin_[9216];   // 64 pixels * 144
  __shared__ float sout[3456];   // 54 ch * 64 pixels
  int blk = blockIdx.x;
  int b = blk >> 10, p0 = (blk & 1023) << 6;
  const float* src = qkvd + (size_t)b * 144 * NP + (size_t)p0 * 144;
  for (int i = threadIdx.x; i < 9216; i += 384) sin_[i] = src[i];
  __syncthreads();
  int pl = threadIdx.x / 6, c2 = threadIdx.x % 6;
  float xv[24];
  #pragma unroll
  for (int g = 0; g < 24; ++g) xv[g] = sin_[pl * 144 + g * 6 + c2];
  #pragma unroll
  for (int o = 0; o < 9; ++o) {
    float a = fcb[o];
    #pragma unroll
    for (int g = 0; g < 24; ++g) a += fcw[o * 24 + g] * xv[g];
    sout[(c2 * 9 + o) * 64 + pl] = a;
  }
  __syncthreads();
  for (int i = threadIdx.x; i < 3456; i += 384) {
    int ch = i >> 6, pl2 = i & 63;
    fconv[(size_t)(b * 54 + ch) * NP + p0 + pl2] = sout[i];
  }
}

// ---------------- grouped dep conv 54->48 (4-row stripe, 9 planes, 8 oc, float4) ----------------
__global__ __launch_bounds__(256) void k_depconv(const float* __restrict__ fconv,
                                                 const float* __restrict__ dw,
                                                 const float* __restrict__ db,
                                                 float* __restrict__ outconv) {
  __shared__ float lds[9 * 6 * 272];  // 58752 B
  int blk = blockIdx.x;               // b*6*64 + g*64 + rq
  int rq = blk & 63;
  int g = (blk >> 6) % 6;
  int b = blk / (6 * 64);
  int yy0 = rq * 4;
  const float* fb = fconv + (size_t)(b * 54 + g * 9) * NP;
  for (int i = threadIdx.x; i < 9 * 6 * 68; i += 256) {
    int j = i / 408;
    int rem = i % 408;
    int sr = rem / 68, c4 = rem % 68;
    int iy = yy0 + sr - 1;
    float4 v = make_float4(0.f, 0.f, 0.f, 0.f);
    if ((unsigned)iy < (unsigned)NH && c4 >= 1 && c4 <= 64)
      v = *(const float4*)(fb + (size_t)j * NP + iy * NW + (c4 - 1) * 4);
    *(float4*)(&lds[(j * 6 + sr) * 272 + c4 * 4]) = v;
  }
  __syncthreads();
  int q = threadIdx.x >> 6;
  int quad = threadIdx.x & 63;
  float acc[8][4];
  #pragma unroll
  for (int o = 0; o < 8; ++o) {
    float bv = db[g * 8 + o];
    #pragma unroll
    for (int jj = 0; jj < 4; ++jj) acc[o][jj] = bv;
  }
  const float* wg = dw + (size_t)(g * 8) * 81;
  #pragma unroll
  for (int j = 0; j < 9; ++j) {
    #pragma unroll
    for (int rr = 0; rr < 3; ++rr) {
      const float* lp = &lds[((j * 6) + q + rr) * 272 + quad * 4];
      float4 va = *(const float4*)lp;
      float4 vb = *(const float4*)(lp + 4);
      float4 vc = *(const float4*)(lp + 8);
      float v[12] = {va.x, va.y, va.z, va.w, vb.x, vb.y, vb.z, vb.w,
                     vc.x, vc.y, vc.z, vc.w};
      #pragma unroll
      for (int dxi = 0; dxi < 3; ++dxi) {
        int wi = j * 9 + rr * 3 + dxi;
        #pragma unroll
        for (int o = 0; o < 8; ++o) {
          float wv = wg[o * 81 + wi];
          #pragma unroll
          for (int jj = 0; jj < 4; ++jj)
            acc[o][jj] = fmaf(v[jj + dxi + 3], wv, acc[o][jj]);
        }
      }
    }
  }
  float* ob = outconv + ((size_t)(b * NC + g * 8) * NH + yy0 + q) * NW + quad * 4;
  #pragma unroll
  for (int o = 0; o < 8; ++o)
    *(float4*)(ob + (size_t)o * NP) = make_float4(acc[o][0], acc[o][1], acc[o][2], acc[o][3]);
}

// ---------------- fused attn@V + proj + out_conv + residual ----------------
__global__ __launch_bounds__(256, 4) void k_proj(const float* __restrict__ qkvd,
                                                 const float* __restrict__ A,
                                                 const float* __restrict__ projw,
                                                 const float* __restrict__ x,
                                                 const float* __restrict__ outconv,
                                                 float* __restrict__ x1) {
  int idx = blockIdx.x * blockDim.x + threadIdx.x;  // exact NB*NP
  int b = idx / NP, p = idx % NP;
  __shared__ float sA[288];
  for (int i = threadIdx.x; i < 288; i += 256) sA[i] = A[b * 288 + i];
  __syncthreads();
  const float* vb = qkvd + (size_t)(b * 144 + 96) * NP + p;
  float acc[48];
  #pragma unroll
  for (int o = 0; o < 48; ++o) acc[o] = 0.f;
  for (int h = 0; h < 8; ++h) {
    float v6[6];
    #pragma unroll
    for (int d = 0; d < 6; ++d) v6[d] = vb[(size_t)(h * 6 + d) * NP];
    #pragma unroll
    for (int c = 0; c < 6; ++c) {
      float av = 0.f;
      #pragma unroll
      for (int d = 0; d < 6; ++d) av = fmaf(sA[h * 36 + c * 6 + d], v6[d], av);
      const float* wc = projw + h * 6 + c;  // projw[o*48 + (h*6+c)]
      #pragma unroll
      for (int o = 0; o < 48; ++o) acc[o] = fmaf(wc[o * 48], av, acc[o]);
    }
  }
  const float* xb = x + (size_t)b * NC * NP + p;
  const float* ob = outconv + (size_t)b * NC * NP + p;
  float* x1b = x1 + (size_t)b * NC * NP + p;
  #pragma unroll
  for (int o = 0; o < 48; ++o)
    x1b[(size_t)o * NP] = xb[(size_t)o * NP] + acc[o] + ob[(size_t)o * NP];
}

// ---------------- FF: 3-dilation depthwise + gelu gate (4-row stripe, float4) ----------------
__global__ __launch_bounds__(256) void k_ffdw(const float* __restrict__ y,
                                              const float* __restrict__ w1,
                                              const float* __restrict__ w2,
                                              const float* __restrict__ w3,
                                              float* __restrict__ z) {
  __shared__ float lds[24 * 272];  // 26112 B
  int blk = blockIdx.x;
  int rq = blk & 63;
  int ch = (blk >> 6) % NHID;
  int b = blk / (NHID * 64);
  int yy0 = rq * 4;
  const float* yb = y + (size_t)(b * 288 + ch) * NP;
  for (int i = threadIdx.x; i < 24 * 68; i += 256) {
    int sr = i / 68, c4 = i % 68;
    int br, iy;
    if (sr < 6)       { br = 0; iy = yy0 + sr - 1; }
    else if (sr < 14) { br = 1; iy = yy0 + sr - 8; }
    else              { br = 2; iy = yy0 + sr - 17; }
    float4 v = make_float4(0.f, 0.f, 0.f, 0.f);
    if ((unsigned)iy < (unsigned)NH && c4 >= 1 && c4 <= 64)
      v = *(const float4*)(yb + (size_t)(br * NHID) * NP + iy * NW + (c4 - 1) * 4);
    *(float4*)(&lds[sr * 272 + c4 * 4]) = v;
  }
  __syncthreads();
  int q = threadIdx.x >> 6;
  int quad = threadIdx.x & 63;
  const float* wp1 = w1 + ch * 9;   // wave-uniform -> scalar loads
  const float* wp2 = w2 + ch * 9;
  const float* wp3 = w3 + ch * 9;
  float c1[4] = {0.f, 0.f, 0.f, 0.f};
  float c2[4] = {0.f, 0.f, 0.f, 0.f};
  float c3[4] = {0.f, 0.f, 0.f, 0.f};
  #pragma unroll
  for (int rr = 0; rr < 3; ++rr)
    STENCIL_ROW(0 + q + rr * 1, 1, wp1[rr * 3 + 0], wp1[rr * 3 + 1], wp1[rr * 3 + 2], c1);
  #pragma unroll
  for (int rr = 0; rr < 3; ++rr)
    STENCIL_ROW(6 + q + rr * 2, 2, wp2[rr * 3 + 0], wp2[rr * 3 + 1], wp2[rr * 3 + 2], c2);
  #pragma unroll
  for (int rr = 0; rr < 3; ++rr)
    STENCIL_ROW(14 + q + rr * 3, 3, wp3[rr * 3 + 0], wp3[rr * 3 + 1], wp3[rr * 3 + 2], c3);
  float4 o4;
  o4.x = gelu_f(c1[0]) * c2[0] * c3[0];
  o4.y = gelu_f(c1[1]) * c2[1] * c3[1];
  o4.z = gelu_f(c1[2]) * c2[2] * c3[2];
  o4.w = gelu_f(c1[3]) * c2[3] * c3[3];
  *(float4*)(z + (size_t)(b * NHID + ch) * NP + (yy0 + q) * NW + quad * 4) = o4;
}

// ---------------- pout + residual -> d_out (streamed, acc[48]) ----------------
__global__ __launch_bounds__(256, 4) void k_pout(const float* __restrict__ z,
                                                 const float* __restrict__ poutw,
                                                 const float* __restrict__ x1,
                                                 float* __restrict__ outp) {
  int idx = blockIdx.x * blockDim.x + threadIdx.x;  // exact NB*NP
  int b = idx / NP, p = idx % NP;
  const float* zb = z + (size_t)b * NHID * NP + p;
  float acc[48];
  #pragma unroll
  for (int o = 0; o < 48; ++o) acc[o] = 0.f;
  for (int j = 0; j < 96; ++j) {
    float zv = zb[(size_t)j * NP];
    const float* wc = poutw + j;  // poutw[o*96 + j]
    #pragma unroll
    for (int o = 0; o < 48; ++o) acc[o] = fmaf(wc[o * 96], zv, acc[o]);
  }
  const float* x1b = x1 + (size_t)b * NC * NP + p;
  float* ob = outp + (size_t)b * NC * NP + p;
  #pragma unroll
  for (int o = 0; o < 48; ++o)
    ob[(size_t)o * NP] = x1b[(size_t)o * NP] + acc[o];
}

// ---------------- workspace layout (floats) ----------------
constexpr size_t SZ_QKV = (size_t)NB * 144 * NP;       // 18,874,368
constexpr size_t SZ_CHW = (size_t)NB * NC * NP;        // 6,291,456
constexpr size_t OFF_QKV0 = 0;
constexpr size_t OFF_QKVD = OFF_QKV0 + SZ_QKV;
constexpr size_t OFF_FCONV = OFF_QKVD + SZ_QKV;        // y reuses [0, OFF_FCONV)
constexpr size_t SZ_FCONV = (size_t)NB * 54 * NP;
constexpr size_t OFF_OUTCONV = OFF_FCONV + SZ_FCONV;   // z reuses [OFF_FCONV, +NB*96*NP)
constexpr size_t OFF_X1 = OFF_OUTCONV + SZ_CHW;
constexpr size_t OFF_STATS = OFF_X1 + SZ_CHW;          // float2 stats [NB*NP]
constexpr size_t OFF_T1 = OFF_STATS + (size_t)NB * NP * 2;
constexpr size_t OFF_P1 = OFF_T1 + (size_t)NB * NC * 128 * 128;
constexpr size_t OFF_T2 = OFF_P1 + (size_t)NB * NC * 64 * 64;
constexpr size_t OFF_P2 = OFF_T2 + (size_t)NB * NC * 32 * 32;
constexpr size_t OFF_T3 = OFF_P2 + (size_t)NB * NC * 16 * 16;   // reused for SB after conv branch
constexpr size_t OFF_P3 = OFF_T3 + (size_t)NB * NC * 8 * 8;
constexpr size_t OFF_Q0M = OFF_P3 + (size_t)NB * NC * 4 * 4;
constexpr size_t OFF_NORMS = OFF_Q0M + 576;            // unused
constexpr size_t OFF_SPART = OFF_NORMS + 192;
constexpr size_t OFF_A = OFF_SPART + (size_t)NB * 64 * 48;

extern "C" void kernel_launch(void* const* d_in, const int* in_sizes, int n_in,
                              void* d_out, int out_size, void* d_ws, size_t ws_size,
                              hipStream_t stream) {
  const float* x     = (const float*)d_in[0];
  const float* ln1w  = (const float*)d_in[1];
  const float* ln1b  = (const float*)d_in[2];
  const float* qkvw  = (const float*)d_in[3];
  const float* qkvdw = (const float*)d_in[4];
  const float* projw = (const float*)d_in[5];
  const float* fcw   = (const float*)d_in[6];
  const float* fcb   = (const float*)d_in[7];
  const float* depw  = (const float*)d_in[8];
  const float* depb  = (const float*)d_in[9];
  const float* l2qw  = (const float*)d_in[10];
  const float* l2qb  = (const float*)d_in[11];
  const float* temp  = (const float*)d_in[12];
  const float* ln2w  = (const float*)d_in[13];
  const float* ln2b  = (const float*)d_in[14];
  const float* pinw  = (const float*)d_in[15];
  const float* dw1   = (const float*)d_in[16];
  const float* dw2   = (const float*)d_in[17];
  const float* dw3   = (const float*)d_in[18];
  const float* poutw = (const float*)d_in[19];
  const float* cvw0  = (const float*)d_in[20];
  const float* cvb0  = (const float*)d_in[21];
  const float* clw0  = (const float*)d_in[22];
  const float* clb0  = (const float*)d_in[23];
  const float* cvw1  = (const float*)d_in[24];
  const float* cvb1  = (const float*)d_in[25];
  const float* clw1  = (const float*)d_in[26];
  const float* clb1  = (const float*)d_in[27];
  const float* cvw2  = (const float*)d_in[28];
  const float* cvb2  = (const float*)d_in[29];
  const float* clw2  = (const float*)d_in[30];
  const float* clb2  = (const float*)d_in[31];

  float* ws = (float*)d_ws;
  float* qkv0 = ws + OFF_QKV0;
  float* qkvd = ws + OFF_QKVD;
  float* fconv = ws + OFF_FCONV;
  float* outconv = ws + OFF_OUTCONV;
  float* x1 = ws + OFF_X1;
  float2* stats = (float2*)(ws + OFF_STATS);
  float* t1 = ws + OFF_T1;
  float* p1 = ws + OFF_P1;
  float* t2 = ws + OFF_T2;
  float* p2 = ws + OFF_P2;
  float* t3 = ws + OFF_T3;
  float* p3 = ws + OFF_P3;
  float* q0m = ws + OFF_Q0M;
  float* spart = ws + OFF_SPART;
  float* A = ws + OFF_A;
  float* SB = ws + OFF_T3;       // reuse t3 region after conv branch (864 floats)
  float* ybuf = ws + OFF_QKV0;   // reuse qkv0+qkvd (exactly NB*288*NP)
  float* zbuf = ws + OFF_FCONV;  // reuse fconv+outconv (NB*96*NP fits)

  // conv-descriptor branch (ic-chunked LDS convs)
  k_conv_s2_tile<<<512, 256, 0, stream>>>(x, cvw0, cvb0, t1, 256, 256, 128, 128);
  k_lnpool<<<32, 256, 0, stream>>>(t1, clw0, clb0, p1, 128, 128);
  k_conv_s2_tile<<<32, 256, 0, stream>>>(p1, cvw1, cvb1, t2, 64, 64, 32, 32);
  k_lnpool<<<2, 256, 0, stream>>>(t2, clw1, clb1, p2, 32, 32);
  k_conv_s2_tile<<<2, 256, 0, stream>>>(p2, cvw2, cvb2, t3, 16, 16, 8, 8);
  k_lnpool<<<1, 256, 0, stream>>>(t3, clw2, clb2, p3, 8, 8);
  k_head<<<2, 320, 0, stream>>>(p3, l2qw, l2qb, q0m);

  // LN folding setup (after conv branch frees t3 region)
  k_prep<<<2, 256, 0, stream>>>(qkvw, ln1w, ln1b, pinw, ln2w, ln2b, SB);

  // attention
  k_lnstats4<<<128, 256, 0, stream>>>(x, stats);
  k_chmix_gemm<<<1536, 256, 0, stream>>>(x, ln1w, qkvw, SB, SB + 144, stats, qkv0, 144, 3);
  k_dw144<<<18432, 256, 0, stream>>>(qkv0, qkvdw, qkvd);
  k_gram<<<128, 256, 0, stream>>>(qkvd, spart);
  k_attn<<<2, 64, 0, stream>>>(spart, temp, q0m, A);
  k_fc<<<2048, 384, 0, stream>>>(qkvd, fcw, fcb, fconv);
  k_depconv<<<768, 256, 0, stream>>>(fconv, depw, depb, outconv);
  k_proj<<<512, 256, 0, stream>>>(qkvd, A, projw, x, outconv, x1);

  // feedforward
  k_lnstats4<<<128, 256, 0, stream>>>(x1, stats);
  k_chmix_gemm<<<3072, 256, 0, stream>>>(x1, ln2w, pinw, SB + 288, SB + 576, stats, ybuf, 288, 6);
  k_ffdw<<<12288, 256, 0, stream>>>(ybuf, dw1, dw2, dw3, zbuf);
  k_pout<<<512, 256, 0, stream>>>(zbuf, poutw, x1, (float*)d_out);
}

// Round 10
// 620.133 us; speedup vs baseline: 3.6037x; 1.0762x over previous
//
#include <hip/hip_runtime.h>

constexpr int NB = 2;
constexpr int NC = 48;
constexpr int NH = 256;
constexpr int NW = 256;
constexpr int NP = NH * NW;           // 65536
constexpr int NHEADS = 8;
constexpr int NCHD = 6;
constexpr int NHID = 96;

typedef unsigned short bf16_t;

__device__ __forceinline__ float bf2f(bf16_t u) {
  union { unsigned int i; float f; } c; c.i = ((unsigned int)u) << 16; return c.f;
}
__device__ __forceinline__ bf16_t f2bf(float f) {
  union { float f; unsigned int i; } c; c.f = f;
  unsigned int r = (c.i + 0x7FFFu + ((c.i >> 16) & 1u)) >> 16;
  return (bf16_t)r;
}
__device__ __forceinline__ void unpack2(unsigned int u, float& a, float& b) {
  union { unsigned int i; float f; } c0, c1;
  c0.i = u << 16; c1.i = u & 0xffff0000u;
  a = c0.f; b = c1.f;
}

__device__ __forceinline__ float gelu_f(float v) {
  return 0.5f * v * (1.0f + erff(v * 0.70710678118654752f));
}

// tap loop over a 12-float window (3x ds_read_b128), compile-time indices.
#define STENCIL_ROW(LROW, D, WVAL0, WVAL1, WVAL2, ACC)                        \
  {                                                                            \
    const float* lp = &lds[(LROW) * 272 + quad * 4];                           \
    float4 va = *(const float4*)lp;                                            \
    float4 vb = *(const float4*)(lp + 4);                                      \
    float4 vc = *(const float4*)(lp + 8);                                      \
    float v[12] = {va.x, va.y, va.z, va.w, vb.x, vb.y, vb.z, vb.w,             \
                   vc.x, vc.y, vc.z, vc.w};                                    \
    _Pragma("unroll") for (int jj = 0; jj < 4; ++jj) {                         \
      ACC[jj] = fmaf(v[jj - (D) + 4], WVAL0, ACC[jj]);                         \
      ACC[jj] = fmaf(v[jj + 4], WVAL1, ACC[jj]);                               \
      ACC[jj] = fmaf(v[jj + (D) + 4], WVAL2, ACC[jj]);                         \
    }                                                                          \
  }

// ---------------- conv-descriptor branch: ic-chunked LDS stride-2 3x3 conv ----------------
__global__ __launch_bounds__(256) void k_conv_s2_tile(const float* __restrict__ in,
                                                      const float* __restrict__ w,
                                                      const float* __restrict__ bias,
                                                      float* __restrict__ out,
                                                      int IH, int IW, int OH, int OW) {
  __shared__ float lds[16 * 442];  // 16 ic * 17 rows * 26 = 28288 B
  int tilesX = OW >> 3;
  int tilesY = OH >> 3;
  int blk = blockIdx.x;
  int tx = blk % tilesX;
  int t = blk / tilesX;
  int ty = t % tilesY;
  int b = t / tilesY;
  int oy0 = ty * 8, ox0 = tx * 8;
  int iy0 = oy0 * 2 - 1, ix0 = ox0 * 2 - 1;
  const float* inb = in + (size_t)b * NC * IH * IW;

  int lane = threadIdx.x & 63;
  int oy = lane >> 3, ox = lane & 7;
  int ocb = __builtin_amdgcn_readfirstlane((threadIdx.x >> 6) * 12);
  float acc[12];
  #pragma unroll
  for (int j = 0; j < 12; ++j) acc[j] = bias[ocb + j];
  int rbase = oy * 52;  // row 2*oy, stride 26

  for (int chunk = 0; chunk < 3; ++chunk) {
    int icb = chunk * 16;
    for (int i = threadIdx.x; i < 16 * 17 * 17; i += 256) {
      int cc = i % 17;
      int t2 = i / 17;
      int rr = t2 % 17;
      int ic = t2 / 17;
      float v = 0.f;
      int iy = iy0 + rr, ix = ix0 + cc;
      if ((unsigned)iy < (unsigned)IH && (unsigned)ix < (unsigned)IW)
        v = inb[((size_t)(icb + ic) * IH + iy) * IW + ix];
      lds[ic * 442 + rr * 26 + ((cc & 1) ? 13 + (cc >> 1) : (cc >> 1))] = v;
    }
    __syncthreads();

    for (int ic16 = 0; ic16 < 16; ++ic16) {
      const float* base = lds + ic16 * 442 + rbase;
      float e0[3], e1[3], ov[3];
      #pragma unroll
      for (int ky = 0; ky < 3; ++ky) {
        const float* rowp = base + ky * 26;
        e0[ky] = rowp[ox];
        e1[ky] = rowp[ox + 1];
        ov[ky] = rowp[13 + ox];
      }
      const float* wpc = w + (size_t)(ocb * 48 + icb + ic16) * 9;
      #pragma unroll
      for (int j = 0; j < 12; ++j) {
        const float* wp = wpc + (size_t)j * 48 * 9;
        float a = acc[j];
        #pragma unroll
        for (int ky = 0; ky < 3; ++ky) {
          a = fmaf(wp[ky * 3 + 0], e0[ky], a);
          a = fmaf(wp[ky * 3 + 1], ov[ky], a);
          a = fmaf(wp[ky * 3 + 2], e1[ky], a);
        }
        acc[j] = a;
      }
    }
    __syncthreads();
  }

  float* ob = out + (size_t)b * NC * OH * OW;
  #pragma unroll
  for (int j = 0; j < 12; ++j)
    ob[((size_t)(ocb + j) * OH + oy0 + oy) * OW + ox0 + ox] = acc[j];
}

__global__ void k_lnpool(const float* __restrict__ in, const float* __restrict__ lw,
                         const float* __restrict__ lb, float* __restrict__ out,
                         int IH, int IW) {
  int OH = IH >> 1, OW = IW >> 1;
  int idx = blockIdx.x * blockDim.x + threadIdx.x;
  int total = NB * OH * OW;
  if (idx >= total) return;
  int ox = idx % OW;
  int t = idx / OW;
  int oy = t % OH;
  int b = t / OH;
  const float* inb = in + (size_t)b * NC * IH * IW;
  float mu[4], rs[4];
  #pragma unroll
  for (int q = 0; q < 4; ++q) {
    int iy = oy * 2 + (q >> 1), ix = ox * 2 + (q & 1);
    float s = 0.f, ss = 0.f;
    for (int c = 0; c < NC; ++c) {
      float v = inb[((size_t)c * IH + iy) * IW + ix];
      s += v; ss += v * v;
    }
    float m = s * (1.f / NC);
    mu[q] = m;
    rs[q] = rsqrtf(fmaxf(ss * (1.f / NC) - m * m, 0.f) + 1e-5f);
  }
  for (int c = 0; c < NC; ++c) {
    float best = 0.f;  // relu >= 0 so 0 == max of relu'd window
    float wv = lw[c], bv = lb[c];
    #pragma unroll
    for (int q = 0; q < 4; ++q) {
      int iy = oy * 2 + (q >> 1), ix = ox * 2 + (q & 1);
      float v = inb[((size_t)c * IH + iy) * IW + ix];
      v = (v - mu[q]) * rs[q] * wv + bv;
      best = fmaxf(best, fmaxf(v, 0.f));
    }
    out[((size_t)(b * NC + c) * OH + oy) * OW + ox] = best;
  }
}

__global__ void k_head(const float* __restrict__ p3, const float* __restrict__ l2qw,
                       const float* __restrict__ l2qb, float* __restrict__ q0m) {
  __shared__ float xd[NC], q0[NC];
  int b = blockIdx.x, t = threadIdx.x;
  if (t < NC) {
    float s = 0.f;
    for (int i = 0; i < 16; ++i) s += p3[(b * NC + t) * 16 + i];
    xd[t] = gelu_f(s * (1.f / 16.f));
  }
  __syncthreads();
  if (t < NC) {
    float a = l2qb[t];
    for (int c = 0; c < NC; ++c) a += xd[c] * l2qw[t * NC + c];
    q0[t] = a;
  }
  __syncthreads();
  if (t < NHEADS * NCHD * NCHD) {
    int h = t / 36, r = t % 36, c = r / 6, d = r % 6;
    q0m[b * 288 + t] = q0[h * 6 + c] * q0[h * 6 + d];
  }
}

// ---------------- S[o] = sum_c W[o][c]*lnw[c], B[o] = sum_c W[o][c]*lnb[c] ----------------
__global__ void k_prep(const float* __restrict__ qkvw, const float* __restrict__ ln1w,
                       const float* __restrict__ ln1b, const float* __restrict__ pinw,
                       const float* __restrict__ ln2w, const float* __restrict__ ln2b,
                       float* __restrict__ SB) {
  int t = blockIdx.x * blockDim.x + threadIdx.x;
  if (t < 144) {
    float s = 0.f, bb = 0.f;
    for (int c = 0; c < 48; ++c) {
      float w = qkvw[t * 48 + c];
      s = fmaf(w, ln1w[c], s); bb = fmaf(w, ln1b[c], bb);
    }
    SB[t] = s; SB[144 + t] = bb;
  } else if (t < 144 + 288) {
    int o = t - 144;
    float s = 0.f, bb = 0.f;
    for (int c = 0; c < 48; ++c) {
      float w = pinw[o * 48 + c];
      s = fmaf(w, ln2w[c], s); bb = fmaf(w, ln2b[c], bb);
    }
    SB[288 + o] = s; SB[576 + o] = bb;
  }
}

// ---------------- per-pixel LN stats (vectorized x4) ----------------
__global__ __launch_bounds__(256) void k_lnstats4(const float* __restrict__ x,
                                                  float2* __restrict__ stats) {
  int idx = blockIdx.x * blockDim.x + threadIdx.x;   // NB*NP/4
  int b = idx / (NP / 4), p4 = idx % (NP / 4);
  const float* xb = x + (size_t)b * NC * NP + p4 * 4;
  float s[4] = {0.f, 0.f, 0.f, 0.f}, ss[4] = {0.f, 0.f, 0.f, 0.f};
  #pragma unroll
  for (int c = 0; c < NC; ++c) {
    float4 v = *(const float4*)(xb + (size_t)c * NP);
    s[0] += v.x; ss[0] = fmaf(v.x, v.x, ss[0]);
    s[1] += v.y; ss[1] = fmaf(v.y, v.y, ss[1]);
    s[2] += v.z; ss[2] = fmaf(v.z, v.z, ss[2]);
    s[3] += v.w; ss[3] = fmaf(v.w, v.w, ss[3]);
  }
  float4 r0, r1;
  float mu0 = s[0] * (1.f / NC); r0.x = mu0;
  r0.y = rsqrtf(fmaxf(ss[0] * (1.f / NC) - mu0 * mu0, 0.f) + 1e-5f);
  float mu1 = s[1] * (1.f / NC); r0.z = mu1;
  r0.w = rsqrtf(fmaxf(ss[1] * (1.f / NC) - mu1 * mu1, 0.f) + 1e-5f);
  float mu2 = s[2] * (1.f / NC); r1.x = mu2;
  r1.y = rsqrtf(fmaxf(ss[2] * (1.f / NC) - mu2 * mu2, 0.f) + 1e-5f);
  float mu3 = s[3] * (1.f / NC); r1.z = mu3;
  r1.w = rsqrtf(fmaxf(ss[3] * (1.f / NC) - mu3 * mu3, 0.f) + 1e-5f);
  float4* sp = (float4*)(stats + (size_t)b * NP + p4 * 4);
  sp[0] = r0; sp[1] = r1;
}

// ---------------- channel-mix GEMM: LDS x-tile, reg-blocked 12 oc x 4 px, bf16 out ----------------
__global__ __launch_bounds__(256) void k_chmix_gemm(const float* __restrict__ x,
                                                    const float* __restrict__ lnw,
                                                    const float* __restrict__ w,
                                                    const float* __restrict__ S,
                                                    const float* __restrict__ Bc,
                                                    const float2* __restrict__ stats,
                                                    bf16_t* __restrict__ out,
                                                    int nout, int nch) {
  __shared__ float lds[48 * 256];  // 49152 B
  int blk = blockIdx.x;
  int och = blk % nch;
  int pxt = (blk / nch) & 255;
  int b = blk / (nch * 256);
  int pxbase = pxt * 256;
  const float* xb = x + (size_t)b * NC * NP + pxbase;
  for (int i = threadIdx.x; i < 48 * 64; i += 256) {
    int k = i >> 6, c4 = i & 63;
    float4 v = *(const float4*)(xb + (size_t)k * NP + c4 * 4);
    float lw = lnw[k];  // wave-uniform
    v.x *= lw; v.y *= lw; v.z *= lw; v.w *= lw;
    *(float4*)&lds[k * 256 + c4 * 4] = v;
  }
  __syncthreads();
  int lane = threadIdx.x & 63;
  int obase = __builtin_amdgcn_readfirstlane(och * 48 + (threadIdx.x >> 6) * 12);
  float acc[12][4];
  #pragma unroll
  for (int j = 0; j < 12; ++j)
    #pragma unroll
    for (int jj = 0; jj < 4; ++jj) acc[j][jj] = 0.f;
  for (int k = 0; k < 48; ++k) {
    float4 xv = *(const float4*)&lds[k * 256 + lane * 4];
    const float* wr = w + (size_t)obase * 48 + k;
    #pragma unroll
    for (int j = 0; j < 12; ++j) {
      float wv = wr[j * 48];  // scalar load (uniform)
      acc[j][0] = fmaf(wv, xv.x, acc[j][0]);
      acc[j][1] = fmaf(wv, xv.y, acc[j][1]);
      acc[j][2] = fmaf(wv, xv.z, acc[j][2]);
      acc[j][3] = fmaf(wv, xv.w, acc[j][3]);
    }
  }
  const float2* sp = stats + (size_t)b * NP + pxbase + lane * 4;
  float2 st0 = sp[0], st1 = sp[1], st2 = sp[2], st3 = sp[3];
  bf16_t* ob = out + (size_t)b * nout * NP + pxbase + lane * 4;
  #pragma unroll
  for (int j = 0; j < 12; ++j) {
    int o = obase + j;
    float Sv = S[o], Bv = Bc[o];
    float r0 = fmaf(st0.y, acc[j][0] - st0.x * Sv, Bv);
    float r1 = fmaf(st1.y, acc[j][1] - st1.x * Sv, Bv);
    float r2 = fmaf(st2.y, acc[j][2] - st2.x * Sv, Bv);
    float r3 = fmaf(st3.y, acc[j][3] - st3.x * Sv, Bv);
    *(ushort4*)(ob + (size_t)o * NP) = make_ushort4(f2bf(r0), f2bf(r1), f2bf(r2), f2bf(r3));
  }
}

// ---------------- depthwise 3x3 on 144 channels (4-row stripe, bf16 in/out) ----------------
__global__ __launch_bounds__(256) void k_dw144(const bf16_t* __restrict__ in,
                                               const float* __restrict__ w9,
                                               bf16_t* __restrict__ out) {
  __shared__ float lds[6 * 272];
  int blk = blockIdx.x;
  int rq = blk & 63;
  int ch = (blk >> 6) % 144;
  int b = blk / (144 * 64);
  int yy0 = rq * 4;
  const bf16_t* ib = in + (size_t)(b * 144 + ch) * NP;
  for (int i = threadIdx.x; i < 6 * 68; i += 256) {
    int sr = i / 68, c4 = i % 68;
    int iy = yy0 + sr - 1;
    float4 v = make_float4(0.f, 0.f, 0.f, 0.f);
    if ((unsigned)iy < (unsigned)NH && c4 >= 1 && c4 <= 64) {
      ushort4 u = *(const ushort4*)(ib + iy * NW + (c4 - 1) * 4);
      v = make_float4(bf2f(u.x), bf2f(u.y), bf2f(u.z), bf2f(u.w));
    }
    *(float4*)(&lds[sr * 272 + c4 * 4]) = v;
  }
  __syncthreads();
  int q = threadIdx.x >> 6;
  int quad = threadIdx.x & 63;
  const float* wp = w9 + ch * 9;   // wave-uniform -> scalar loads
  float acc[4] = {0.f, 0.f, 0.f, 0.f};
  #pragma unroll
  for (int rr = 0; rr < 3; ++rr)
    STENCIL_ROW(q + rr, 1, wp[rr * 3 + 0], wp[rr * 3 + 1], wp[rr * 3 + 2], acc);
  *(ushort4*)(out + (size_t)(b * 144 + ch) * NP + (yy0 + q) * NW + quad * 4) =
      make_ushort4(f2bf(acc[0]), f2bf(acc[1]), f2bf(acc[2]), f2bf(acc[3]));
}

// ---------------- per-head Gram (36) + channel ssq (12) partials, fused (bf16 in) ----------------
__global__ void k_gram(const bf16_t* __restrict__ qkvd, float* __restrict__ spart) {
  int gid = blockIdx.x;  // b*64 + h*8 + seg
  int seg = gid & 7, h = (gid >> 3) & 7, b = gid >> 6;
  const bf16_t* qb = qkvd + (size_t)(b * 144 + h * 6) * NP;
  const bf16_t* kb = qkvd + (size_t)(b * 144 + 48 + h * 6) * NP;
  float acc[48];
  #pragma unroll
  for (int j = 0; j < 48; ++j) acc[j] = 0.f;
  for (int i = seg * 8192 + threadIdx.x; i < (seg + 1) * 8192; i += 256) {
    float qv[6], kv[6];
    #pragma unroll
    for (int c = 0; c < 6; ++c) {
      qv[c] = bf2f(qb[(size_t)c * NP + i]);
      kv[c] = bf2f(kb[(size_t)c * NP + i]);
    }
    #pragma unroll
    for (int c = 0; c < 6; ++c)
      #pragma unroll
      for (int d = 0; d < 6; ++d) acc[c * 6 + d] = fmaf(qv[c], kv[d], acc[c * 6 + d]);
    #pragma unroll
    for (int c = 0; c < 6; ++c) acc[36 + c] = fmaf(qv[c], qv[c], acc[36 + c]);
    #pragma unroll
    for (int d = 0; d < 6; ++d) acc[42 + d] = fmaf(kv[d], kv[d], acc[42 + d]);
  }
  int lane = threadIdx.x & 63, wid = threadIdx.x >> 6;
  __shared__ float sr[4 * 48];
  #pragma unroll
  for (int j = 0; j < 48; ++j) {
    float v = acc[j];
    #pragma unroll
    for (int off = 32; off; off >>= 1) v += __shfl_down(v, off, 64);
    if (lane == 0) sr[wid * 48 + j] = v;
  }
  __syncthreads();
  if (threadIdx.x < 48)
    spart[gid * 48 + threadIdx.x] =
        sr[threadIdx.x] + sr[48 + threadIdx.x] + sr[96 + threadIdx.x] + sr[144 + threadIdx.x];
}

// ---------------- attention softmax (tiny; norms from ssq partials) ----------------
__global__ void k_attn(const float* __restrict__ spart, const float* __restrict__ temp,
                       const float* __restrict__ q0m, float* __restrict__ A) {
  int b = blockIdx.x, t = threadIdx.x;
  if (t >= 48) return;
  int h = t / 6, c = t % 6;
  float qs = 0.f;
  for (int seg = 0; seg < 8; ++seg)
    qs += spart[(size_t)((b * 64 + h * 8 + seg) * 48) + 36 + c];
  float nq = fmaxf(sqrtf(qs), 1e-12f);
  float tm = temp[h];
  float lg[6];
  #pragma unroll
  for (int d = 0; d < 6; ++d) {
    float s = 0.f, ks = 0.f;
    for (int seg = 0; seg < 8; ++seg) {
      const float* base = spart + (size_t)((b * 64 + h * 8 + seg) * 48);
      s += base[c * 6 + d];
      ks += base[42 + d];
    }
    float nk = fmaxf(sqrtf(ks), 1e-12f);
    lg[d] = (s / (nq * nk)) * tm * q0m[b * 288 + h * 36 + c * 6 + d];
  }
  float m = lg[0];
  #pragma unroll
  for (int d = 1; d < 6; ++d) m = fmaxf(m, lg[d]);
  float sum = 0.f;
  #pragma unroll
  for (int d = 0; d < 6; ++d) { lg[d] = expf(lg[d] - m); sum += lg[d]; }
  float inv = 1.f / sum;
  #pragma unroll
  for (int d = 0; d < 6; ++d) A[b * 288 + h * 36 + c * 6 + d] = lg[d] * inv;
}

// ---------------- fc mix over the raw-reshape scramble (bf16 in/out) ----------------
__global__ __launch_bounds__(384) void k_fc(const bf16_t* __restrict__ qkvd,
                                            const float* __restrict__ fcw,
                                            const float* __restrict__ fcb,
                                            bf16_t* __restrict__ fconv) {
  __shared__ float sin_[9216];   // 64 pixels * 144
  __shared__ float sout[3456];   // 54 ch * 64 pixels
  int blk = blockIdx.x;
  int b = blk >> 10, p0 = (blk & 1023) << 6;
  const bf16_t* src = qkvd + (size_t)b * 144 * NP + (size_t)p0 * 144;
  const uint4* src4 = (const uint4*)src;
  for (int i = threadIdx.x; i < 1152; i += 384) {
    uint4 u = src4[i];
    float* d = &sin_[i * 8];
    unpack2(u.x, d[0], d[1]);
    unpack2(u.y, d[2], d[3]);
    unpack2(u.z, d[4], d[5]);
    unpack2(u.w, d[6], d[7]);
  }
  __syncthreads();
  int pl = threadIdx.x / 6, c2 = threadIdx.x % 6;
  float xv[24];
  #pragma unroll
  for (int g = 0; g < 24; ++g) xv[g] = sin_[pl * 144 + g * 6 + c2];
  #pragma unroll
  for (int o = 0; o < 9; ++o) {
    float a = fcb[o];
    #pragma unroll
    for (int g = 0; g < 24; ++g) a += fcw[o * 24 + g] * xv[g];
    sout[(c2 * 9 + o) * 64 + pl] = a;
  }
  __syncthreads();
  for (int i = threadIdx.x; i < 1728; i += 384) {
    int ch = i >> 5, pr = (i & 31) * 2;
    *(ushort2*)(fconv + (size_t)(b * 54 + ch) * NP + p0 + pr) =
        make_ushort2(f2bf(sout[ch * 64 + pr]), f2bf(sout[ch * 64 + pr + 1]));
  }
}

// ---------------- grouped dep conv 54->48 (4-row stripe, bf16 in/out) ----------------
__global__ __launch_bounds__(256) void k_depconv(const bf16_t* __restrict__ fconv,
                                                 const float* __restrict__ dw,
                                                 const float* __restrict__ db,
                                                 bf16_t* __restrict__ outconv) {
  __shared__ float lds[9 * 6 * 272];  // 58752 B
  int blk = blockIdx.x;               // b*6*64 + g*64 + rq
  int rq = blk & 63;
  int g = (blk >> 6) % 6;
  int b = blk / (6 * 64);
  int yy0 = rq * 4;
  const bf16_t* fb = fconv + (size_t)(b * 54 + g * 9) * NP;
  for (int i = threadIdx.x; i < 9 * 6 * 68; i += 256) {
    int j = i / 408;
    int rem = i % 408;
    int sr = rem / 68, c4 = rem % 68;
    int iy = yy0 + sr - 1;
    float4 v = make_float4(0.f, 0.f, 0.f, 0.f);
    if ((unsigned)iy < (unsigned)NH && c4 >= 1 && c4 <= 64) {
      ushort4 u = *(const ushort4*)(fb + (size_t)j * NP + iy * NW + (c4 - 1) * 4);
      v = make_float4(bf2f(u.x), bf2f(u.y), bf2f(u.z), bf2f(u.w));
    }
    *(float4*)(&lds[(j * 6 + sr) * 272 + c4 * 4]) = v;
  }
  __syncthreads();
  int q = threadIdx.x >> 6;
  int quad = threadIdx.x & 63;
  float acc[8][4];
  #pragma unroll
  for (int o = 0; o < 8; ++o) {
    float bv = db[g * 8 + o];
    #pragma unroll
    for (int jj = 0; jj < 4; ++jj) acc[o][jj] = bv;
  }
  const float* wg = dw + (size_t)(g * 8) * 81;
  #pragma unroll
  for (int j = 0; j < 9; ++j) {
    #pragma unroll
    for (int rr = 0; rr < 3; ++rr) {
      const float* lp = &lds[((j * 6) + q + rr) * 272 + quad * 4];
      float4 va = *(const float4*)lp;
      float4 vb = *(const float4*)(lp + 4);
      float4 vc = *(const float4*)(lp + 8);
      float v[12] = {va.x, va.y, va.z, va.w, vb.x, vb.y, vb.z, vb.w,
                     vc.x, vc.y, vc.z, vc.w};
      #pragma unroll
      for (int dxi = 0; dxi < 3; ++dxi) {
        int wi = j * 9 + rr * 3 + dxi;
        #pragma unroll
        for (int o = 0; o < 8; ++o) {
          float wv = wg[o * 81 + wi];
          #pragma unroll
          for (int jj = 0; jj < 4; ++jj)
            acc[o][jj] = fmaf(v[jj + dxi + 3], wv, acc[o][jj]);
        }
      }
    }
  }
  bf16_t* ob = outconv + ((size_t)(b * NC + g * 8) * NH + yy0 + q) * NW + quad * 4;
  #pragma unroll
  for (int o = 0; o < 8; ++o)
    *(ushort4*)(ob + (size_t)o * NP) =
        make_ushort4(f2bf(acc[o][0]), f2bf(acc[o][1]), f2bf(acc[o][2]), f2bf(acc[o][3]));
}

// ---------------- fused attn@V + proj + out_conv + residual ----------------
__global__ __launch_bounds__(256, 4) void k_proj(const bf16_t* __restrict__ qkvd,
                                                 const float* __restrict__ A,
                                                 const float* __restrict__ projw,
                                                 const float* __restrict__ x,
                                                 const bf16_t* __restrict__ outconv,
                                                 float* __restrict__ x1) {
  int idx = blockIdx.x * blockDim.x + threadIdx.x;  // exact NB*NP
  int b = idx / NP, p = idx % NP;
  __shared__ float sA[288];
  for (int i = threadIdx.x; i < 288; i += 256) sA[i] = A[b * 288 + i];
  __syncthreads();
  const bf16_t* vb = qkvd + (size_t)(b * 144 + 96) * NP + p;
  float acc[48];
  #pragma unroll
  for (int o = 0; o < 48; ++o) acc[o] = 0.f;
  for (int h = 0; h < 8; ++h) {
    float v6[6];
    #pragma unroll
    for (int d = 0; d < 6; ++d) v6[d] = bf2f(vb[(size_t)(h * 6 + d) * NP]);
    #pragma unroll
    for (int c = 0; c < 6; ++c) {
      float av = 0.f;
      #pragma unroll
      for (int d = 0; d < 6; ++d) av = fmaf(sA[h * 36 + c * 6 + d], v6[d], av);
      const float* wc = projw + h * 6 + c;  // projw[o*48 + (h*6+c)]
      #pragma unroll
      for (int o = 0; o < 48; ++o) acc[o] = fmaf(wc[o * 48], av, acc[o]);
    }
  }
  const float* xb = x + (size_t)b * NC * NP + p;
  const bf16_t* ob = outconv + (size_t)b * NC * NP + p;
  float* x1b = x1 + (size_t)b * NC * NP + p;
  #pragma unroll
  for (int o = 0; o < 48; ++o)
    x1b[(size_t)o * NP] = xb[(size_t)o * NP] + acc[o] + bf2f(ob[(size_t)o * NP]);
}

// ---------------- FF: 3-dilation depthwise + gelu gate (bf16 in/out) ----------------
__global__ __launch_bounds__(256) void k_ffdw(const bf16_t* __restrict__ y,
                                              const float* __restrict__ w1,
                                              const float* __restrict__ w2,
                                              const float* __restrict__ w3,
                                              bf16_t* __restrict__ z) {
  __shared__ float lds[24 * 272];  // 26112 B
  int blk = blockIdx.x;
  int rq = blk & 63;
  int ch = (blk >> 6) % NHID;
  int b = blk / (NHID * 64);
  int yy0 = rq * 4;
  const bf16_t* yb = y + (size_t)(b * 288 + ch) * NP;
  for (int i = threadIdx.x; i < 24 * 68; i += 256) {
    int sr = i / 68, c4 = i % 68;
    int br, iy;
    if (sr < 6)       { br = 0; iy = yy0 + sr - 1; }
    else if (sr < 14) { br = 1; iy = yy0 + sr - 8; }
    else              { br = 2; iy = yy0 + sr - 17; }
    float4 v = make_float4(0.f, 0.f, 0.f, 0.f);
    if ((unsigned)iy < (unsigned)NH && c4 >= 1 && c4 <= 64) {
      ushort4 u = *(const ushort4*)(yb + (size_t)(br * NHID) * NP + iy * NW + (c4 - 1) * 4);
      v = make_float4(bf2f(u.x), bf2f(u.y), bf2f(u.z), bf2f(u.w));
    }
    *(float4*)(&lds[sr * 272 + c4 * 4]) = v;
  }
  __syncthreads();
  int q = threadIdx.x >> 6;
  int quad = threadIdx.x & 63;
  const float* wp1 = w1 + ch * 9;   // wave-uniform -> scalar loads
  const float* wp2 = w2 + ch * 9;
  const float* wp3 = w3 + ch * 9;
  float c1[4] = {0.f, 0.f, 0.f, 0.f};
  float c2[4] = {0.f, 0.f, 0.f, 0.f};
  float c3[4] = {0.f, 0.f, 0.f, 0.f};
  #pragma unroll
  for (int rr = 0; rr < 3; ++rr)
    STENCIL_ROW(0 + q + rr * 1, 1, wp1[rr * 3 + 0], wp1[rr * 3 + 1], wp1[rr * 3 + 2], c1);
  #pragma unroll
  for (int rr = 0; rr < 3; ++rr)
    STENCIL_ROW(6 + q + rr * 2, 2, wp2[rr * 3 + 0], wp2[rr * 3 + 1], wp2[rr * 3 + 2], c2);
  #pragma unroll
  for (int rr = 0; rr < 3; ++rr)
    STENCIL_ROW(14 + q + rr * 3, 3, wp3[rr * 3 + 0], wp3[rr * 3 + 1], wp3[rr * 3 + 2], c3);
  *(ushort4*)(z + (size_t)(b * NHID + ch) * NP + (yy0 + q) * NW + quad * 4) =
      make_ushort4(f2bf(gelu_f(c1[0]) * c2[0] * c3[0]),
                   f2bf(gelu_f(c1[1]) * c2[1] * c3[1]),
                   f2bf(gelu_f(c1[2]) * c2[2] * c3[2]),
                   f2bf(gelu_f(c1[3]) * c2[3] * c3[3]));
}

// ---------------- pout + residual -> d_out (streamed, acc[48], bf16 z) ----------------
__global__ __launch_bounds__(256, 4) void k_pout(const bf16_t* __restrict__ z,
                                                 const float* __restrict__ poutw,
                                                 const float* __restrict__ x1,
                                                 float* __restrict__ outp) {
  int idx = blockIdx.x * blockDim.x + threadIdx.x;  // exact NB*NP
  int b = idx / NP, p = idx % NP;
  const bf16_t* zb = z + (size_t)b * NHID * NP + p;
  float acc[48];
  #pragma unroll
  for (int o = 0; o < 48; ++o) acc[o] = 0.f;
  for (int j = 0; j < 96; ++j) {
    float zv = bf2f(zb[(size_t)j * NP]);
    const float* wc = poutw + j;  // poutw[o*96 + j]
    #pragma unroll
    for (int o = 0; o < 48; ++o) acc[o] = fmaf(wc[o * 96], zv, acc[o]);
  }
  const float* x1b = x1 + (size_t)b * NC * NP + p;
  float* ob = outp + (size_t)b * NC * NP + p;
  #pragma unroll
  for (int o = 0; o < 48; ++o)
    ob[(size_t)o * NP] = x1b[(size_t)o * NP] + acc[o];
}

// ---------------- workspace layout (float offsets; bf16 buffers use half) ----------------
constexpr size_t SZ_QKV = (size_t)NB * 144 * NP;
constexpr size_t SZ_CHW = (size_t)NB * NC * NP;
constexpr size_t OFF_QKV0 = 0;
constexpr size_t OFF_QKVD = OFF_QKV0 + SZ_QKV;         // bf16 buffers: region oversized, fine
constexpr size_t OFF_FCONV = OFF_QKVD + SZ_QKV;
constexpr size_t SZ_FCONV = (size_t)NB * 54 * NP;
constexpr size_t OFF_OUTCONV = OFF_FCONV + SZ_FCONV;
constexpr size_t OFF_X1 = OFF_OUTCONV + SZ_CHW;
constexpr size_t OFF_STATS = OFF_X1 + SZ_CHW;          // float2 stats [NB*NP]
constexpr size_t OFF_T1 = OFF_STATS + (size_t)NB * NP * 2;
constexpr size_t OFF_P1 = OFF_T1 + (size_t)NB * NC * 128 * 128;
constexpr size_t OFF_T2 = OFF_P1 + (size_t)NB * NC * 64 * 64;
constexpr size_t OFF_P2 = OFF_T2 + (size_t)NB * NC * 32 * 32;
constexpr size_t OFF_T3 = OFF_P2 + (size_t)NB * NC * 16 * 16;   // reused for SB after conv branch
constexpr size_t OFF_P3 = OFF_T3 + (size_t)NB * NC * 8 * 8;
constexpr size_t OFF_Q0M = OFF_P3 + (size_t)NB * NC * 4 * 4;
constexpr size_t OFF_NORMS = OFF_Q0M + 576;
constexpr size_t OFF_SPART = OFF_NORMS + 192;
constexpr size_t OFF_A = OFF_SPART + (size_t)NB * 64 * 48;

extern "C" void kernel_launch(void* const* d_in, const int* in_sizes, int n_in,
                              void* d_out, int out_size, void* d_ws, size_t ws_size,
                              hipStream_t stream) {
  const float* x     = (const float*)d_in[0];
  const float* ln1w  = (const float*)d_in[1];
  const float* ln1b  = (const float*)d_in[2];
  const float* qkvw  = (const float*)d_in[3];
  const float* qkvdw = (const float*)d_in[4];
  const float* projw = (const float*)d_in[5];
  const float* fcw   = (const float*)d_in[6];
  const float* fcb   = (const float*)d_in[7];
  const float* depw  = (const float*)d_in[8];
  const float* depb  = (const float*)d_in[9];
  const float* l2qw  = (const float*)d_in[10];
  const float* l2qb  = (const float*)d_in[11];
  const float* temp  = (const float*)d_in[12];
  const float* ln2w  = (const float*)d_in[13];
  const float* ln2b  = (const float*)d_in[14];
  const float* pinw  = (const float*)d_in[15];
  const float* dw1   = (const float*)d_in[16];
  const float* dw2   = (const float*)d_in[17];
  const float* dw3   = (const float*)d_in[18];
  const float* poutw = (const float*)d_in[19];
  const float* cvw0  = (const float*)d_in[20];
  const float* cvb0  = (const float*)d_in[21];
  const float* clw0  = (const float*)d_in[22];
  const float* clb0  = (const float*)d_in[23];
  const float* cvw1  = (const float*)d_in[24];
  const float* cvb1  = (const float*)d_in[25];
  const float* clw1  = (const float*)d_in[26];
  const float* clb1  = (const float*)d_in[27];
  const float* cvw2  = (const float*)d_in[28];
  const float* cvb2  = (const float*)d_in[29];
  const float* clw2  = (const float*)d_in[30];
  const float* clb2  = (const float*)d_in[31];

  float* ws = (float*)d_ws;
  bf16_t* qkv0 = (bf16_t*)(ws + OFF_QKV0);
  bf16_t* qkvd = (bf16_t*)(ws + OFF_QKVD);
  bf16_t* fconv = (bf16_t*)(ws + OFF_FCONV);
  bf16_t* outconv = (bf16_t*)(ws + OFF_OUTCONV);
  float* x1 = ws + OFF_X1;
  float2* stats = (float2*)(ws + OFF_STATS);
  float* t1 = ws + OFF_T1;
  float* p1 = ws + OFF_P1;
  float* t2 = ws + OFF_T2;
  float* p2 = ws + OFF_P2;
  float* t3 = ws + OFF_T3;
  float* p3 = ws + OFF_P3;
  float* q0m = ws + OFF_Q0M;
  float* spart = ws + OFF_SPART;
  float* A = ws + OFF_A;
  float* SB = ws + OFF_T3;          // reuse t3 region after conv branch
  bf16_t* ybuf = (bf16_t*)(ws + OFF_QKV0);   // reuse qkv0 region (bf16, 75 MB < region)
  bf16_t* zbuf = (bf16_t*)(ws + OFF_FCONV);  // reuse fconv region (bf16, fits)

  // conv-descriptor branch (ic-chunked LDS convs)
  k_conv_s2_tile<<<512, 256, 0, stream>>>(x, cvw0, cvb0, t1, 256, 256, 128, 128);
  k_lnpool<<<32, 256, 0, stream>>>(t1, clw0, clb0, p1, 128, 128);
  k_conv_s2_tile<<<32, 256, 0, stream>>>(p1, cvw1, cvb1, t2, 64, 64, 32, 32);
  k_lnpool<<<2, 256, 0, stream>>>(t2, clw1, clb1, p2, 32, 32);
  k_conv_s2_tile<<<2, 256, 0, stream>>>(p2, cvw2, cvb2, t3, 16, 16, 8, 8);
  k_lnpool<<<1, 256, 0, stream>>>(t3, clw2, clb2, p3, 8, 8);
  k_head<<<2, 320, 0, stream>>>(p3, l2qw, l2qb, q0m);

  // LN folding setup (after conv branch frees t3 region)
  k_prep<<<2, 256, 0, stream>>>(qkvw, ln1w, ln1b, pinw, ln2w, ln2b, SB);

  // attention
  k_lnstats4<<<128, 256, 0, stream>>>(x, stats);
  k_chmix_gemm<<<1536, 256, 0, stream>>>(x, ln1w, qkvw, SB, SB + 144, stats, qkv0, 144, 3);
  k_dw144<<<18432, 256, 0, stream>>>(qkv0, qkvdw, qkvd);
  k_gram<<<128, 256, 0, stream>>>(qkvd, spart);
  k_attn<<<2, 64, 0, stream>>>(spart, temp, q0m, A);
  k_fc<<<2048, 384, 0, stream>>>(qkvd, fcw, fcb, fconv);
  k_depconv<<<768, 256, 0, stream>>>(fconv, depw, depb, outconv);
  k_proj<<<512, 256, 0, stream>>>(qkvd, A, projw, x, outconv, x1);

  // feedforward
  k_lnstats4<<<128, 256, 0, stream>>>(x1, stats);
  k_chmix_gemm<<<3072, 256, 0, stream>>>(x1, ln2w, pinw, SB + 288, SB + 576, stats, ybuf, 288, 6);
  k_ffdw<<<12288, 256, 0, stream>>>(ybuf, dw1, dw2, dw3, zbuf);
  k_pout<<<512, 256, 0, stream>>>(zbuf, poutw, x1, (float*)d_out);
}

// Round 11
// 547.463 us; speedup vs baseline: 4.0820x; 1.1327x over previous
//
#include <hip/hip_runtime.h>

constexpr int NB = 2;
constexpr int NC = 48;
constexpr int NH = 256;
constexpr int NW = 256;
constexpr int NP = NH * NW;           // 65536
constexpr int NHEADS = 8;
constexpr int NCHD = 6;
constexpr int NHID = 96;

typedef unsigned short bf16_t;

__device__ __forceinline__ float bf2f(bf16_t u) {
  union { unsigned int i; float f; } c; c.i = ((unsigned int)u) << 16; return c.f;
}
__device__ __forceinline__ bf16_t f2bf(float f) {
  union { float f; unsigned int i; } c; c.f = f;
  unsigned int r = (c.i + 0x7FFFu + ((c.i >> 16) & 1u)) >> 16;
  return (bf16_t)r;
}
__device__ __forceinline__ void unpack2(unsigned int u, float& a, float& b) {
  union { unsigned int i; float f; } c0, c1;
  c0.i = u << 16; c1.i = u & 0xffff0000u;
  a = c0.f; b = c1.f;
}

__device__ __forceinline__ float gelu_f(float v) {
  return 0.5f * v * (1.0f + erff(v * 0.70710678118654752f));
}

// tap loop over a 12-float window (3x ds_read_b128), compile-time indices.
#define STENCIL_ROW(LROW, D, WVAL0, WVAL1, WVAL2, ACC)                        \
  {                                                                            \
    const float* lp = &lds[(LROW) * 272 + quad * 4];                           \
    float4 va = *(const float4*)lp;                                            \
    float4 vb = *(const float4*)(lp + 4);                                      \
    float4 vc = *(const float4*)(lp + 8);                                      \
    float v[12] = {va.x, va.y, va.z, va.w, vb.x, vb.y, vb.z, vb.w,             \
                   vc.x, vc.y, vc.z, vc.w};                                    \
    _Pragma("unroll") for (int jj = 0; jj < 4; ++jj) {                         \
      ACC[jj] = fmaf(v[jj - (D) + 4], WVAL0, ACC[jj]);                         \
      ACC[jj] = fmaf(v[jj + 4], WVAL1, ACC[jj]);                               \
      ACC[jj] = fmaf(v[jj + (D) + 4], WVAL2, ACC[jj]);                         \
    }                                                                          \
  }

// ---------------- conv-descriptor branch: ic-chunked, 8-wave blocks (6 oc/wave) ----------------
__global__ __launch_bounds__(512) void k_conv_s2_tile(const float* __restrict__ in,
                                                      const float* __restrict__ w,
                                                      const float* __restrict__ bias,
                                                      float* __restrict__ out,
                                                      int IH, int IW, int OH, int OW) {
  __shared__ float lds[16 * 442];  // 16 ic * 17 rows * 26 = 28288 B
  int tilesX = OW >> 3;
  int tilesY = OH >> 3;
  int blk = blockIdx.x;
  int tx = blk % tilesX;
  int t = blk / tilesX;
  int ty = t % tilesY;
  int b = t / tilesY;
  int oy0 = ty * 8, ox0 = tx * 8;
  int iy0 = oy0 * 2 - 1, ix0 = ox0 * 2 - 1;
  const float* inb = in + (size_t)b * NC * IH * IW;

  int lane = threadIdx.x & 63;
  int oy = lane >> 3, ox = lane & 7;
  int ocb = __builtin_amdgcn_readfirstlane((threadIdx.x >> 6) * 6);
  float acc[6];
  #pragma unroll
  for (int j = 0; j < 6; ++j) acc[j] = bias[ocb + j];
  int rbase = oy * 52;  // row 2*oy, stride 26

  for (int chunk = 0; chunk < 3; ++chunk) {
    int icb = chunk * 16;
    for (int i = threadIdx.x; i < 16 * 17 * 17; i += 512) {
      int cc = i % 17;
      int t2 = i / 17;
      int rr = t2 % 17;
      int ic = t2 / 17;
      float v = 0.f;
      int iy = iy0 + rr, ix = ix0 + cc;
      if ((unsigned)iy < (unsigned)IH && (unsigned)ix < (unsigned)IW)
        v = inb[((size_t)(icb + ic) * IH + iy) * IW + ix];
      lds[ic * 442 + rr * 26 + ((cc & 1) ? 13 + (cc >> 1) : (cc >> 1))] = v;
    }
    __syncthreads();

    for (int ic16 = 0; ic16 < 16; ++ic16) {
      const float* base = lds + ic16 * 442 + rbase;
      float e0[3], e1[3], ov[3];
      #pragma unroll
      for (int ky = 0; ky < 3; ++ky) {
        const float* rowp = base + ky * 26;
        e0[ky] = rowp[ox];
        e1[ky] = rowp[ox + 1];
        ov[ky] = rowp[13 + ox];
      }
      const float* wpc = w + (size_t)(ocb * 48 + icb + ic16) * 9;
      #pragma unroll
      for (int j = 0; j < 6; ++j) {
        const float* wp = wpc + (size_t)j * 48 * 9;
        float a = acc[j];
        #pragma unroll
        for (int ky = 0; ky < 3; ++ky) {
          a = fmaf(wp[ky * 3 + 0], e0[ky], a);
          a = fmaf(wp[ky * 3 + 1], ov[ky], a);
          a = fmaf(wp[ky * 3 + 2], e1[ky], a);
        }
        acc[j] = a;
      }
    }
    __syncthreads();
  }

  float* ob = out + (size_t)b * NC * OH * OW;
  #pragma unroll
  for (int j = 0; j < 6; ++j)
    ob[((size_t)(ocb + j) * OH + oy0 + oy) * OW + ox0 + ox] = acc[j];
}

__global__ void k_lnpool(const float* __restrict__ in, const float* __restrict__ lw,
                         const float* __restrict__ lb, float* __restrict__ out,
                         int IH, int IW) {
  int OH = IH >> 1, OW = IW >> 1;
  int idx = blockIdx.x * blockDim.x + threadIdx.x;
  int total = NB * OH * OW;
  if (idx >= total) return;
  int ox = idx % OW;
  int t = idx / OW;
  int oy = t % OH;
  int b = t / OH;
  const float* inb = in + (size_t)b * NC * IH * IW;
  float mu[4], rs[4];
  #pragma unroll
  for (int q = 0; q < 4; ++q) {
    int iy = oy * 2 + (q >> 1), ix = ox * 2 + (q & 1);
    float s = 0.f, ss = 0.f;
    for (int c = 0; c < NC; ++c) {
      float v = inb[((size_t)c * IH + iy) * IW + ix];
      s += v; ss += v * v;
    }
    float m = s * (1.f / NC);
    mu[q] = m;
    rs[q] = rsqrtf(fmaxf(ss * (1.f / NC) - m * m, 0.f) + 1e-5f);
  }
  for (int c = 0; c < NC; ++c) {
    float best = 0.f;  // relu >= 0 so 0 == max of relu'd window
    float wv = lw[c], bv = lb[c];
    #pragma unroll
    for (int q = 0; q < 4; ++q) {
      int iy = oy * 2 + (q >> 1), ix = ox * 2 + (q & 1);
      float v = inb[((size_t)c * IH + iy) * IW + ix];
      v = (v - mu[q]) * rs[q] * wv + bv;
      best = fmaxf(best, fmaxf(v, 0.f));
    }
    out[((size_t)(b * NC + c) * OH + oy) * OW + ox] = best;
  }
}

__global__ void k_head(const float* __restrict__ p3, const float* __restrict__ l2qw,
                       const float* __restrict__ l2qb, float* __restrict__ q0m) {
  __shared__ float xd[NC], q0[NC];
  int b = blockIdx.x, t = threadIdx.x;
  if (t < NC) {
    float s = 0.f;
    for (int i = 0; i < 16; ++i) s += p3[(b * NC + t) * 16 + i];
    xd[t] = gelu_f(s * (1.f / 16.f));
  }
  __syncthreads();
  if (t < NC) {
    float a = l2qb[t];
    for (int c = 0; c < NC; ++c) a += xd[c] * l2qw[t * NC + c];
    q0[t] = a;
  }
  __syncthreads();
  if (t < NHEADS * NCHD * NCHD) {
    int h = t / 36, r = t % 36, c = r / 6, d = r % 6;
    q0m[b * 288 + t] = q0[h * 6 + c] * q0[h * 6 + d];
  }
}

// ---------------- prep: S/B vectors + lnw-prescaled weight copies ----------------
__global__ void k_prep(const float* __restrict__ qkvw, const float* __restrict__ ln1w,
                       const float* __restrict__ ln1b, const float* __restrict__ pinw,
                       const float* __restrict__ ln2w, const float* __restrict__ ln2b,
                       float* __restrict__ SB, float* __restrict__ W1s,
                       float* __restrict__ W2s) {
  int t = blockIdx.x * blockDim.x + threadIdx.x;
  int stride = gridDim.x * blockDim.x;
  if (t < 144) {
    float s = 0.f, bb = 0.f;
    for (int c = 0; c < 48; ++c) {
      float w = qkvw[t * 48 + c];
      s = fmaf(w, ln1w[c], s); bb = fmaf(w, ln1b[c], bb);
    }
    SB[t] = s; SB[144 + t] = bb;
  } else if (t < 144 + 288) {
    int o = t - 144;
    float s = 0.f, bb = 0.f;
    for (int c = 0; c < 48; ++c) {
      float w = pinw[o * 48 + c];
      s = fmaf(w, ln2w[c], s); bb = fmaf(w, ln2b[c], bb);
    }
    SB[288 + o] = s; SB[576 + o] = bb;
  }
  for (int i = t; i < 144 * 48; i += stride) W1s[i] = qkvw[i] * ln1w[i % 48];
  for (int i = t; i < 288 * 48; i += stride) W2s[i] = pinw[i] * ln2w[i % 48];
}

// ---------------- channel-mix GEMM: raw x tile + in-block LN stats, bf16 out ----------------
// out[o][p] = rstd[p]*(sum_c W'[o][c]*x[c][p] - mu[p]*S[o]) + B[o], W' prescaled by lnw
__global__ __launch_bounds__(256) void k_chmix_gemm(const float* __restrict__ x,
                                                    const float* __restrict__ w,
                                                    const float* __restrict__ S,
                                                    const float* __restrict__ Bc,
                                                    bf16_t* __restrict__ out,
                                                    int nout, int nch) {
  __shared__ float lds[48 * 256];  // 49152 B
  __shared__ float smu[256], srstd[256];
  int blk = blockIdx.x;
  int och = blk % nch;
  int pxt = (blk / nch) & 255;
  int b = blk / (nch * 256);
  int pxbase = pxt * 256;
  const float* xb = x + (size_t)b * NC * NP + pxbase;
  for (int i = threadIdx.x; i < 48 * 64; i += 256) {
    int k = i >> 6, c4 = i & 63;
    float4 v = *(const float4*)(xb + (size_t)k * NP + c4 * 4);
    *(float4*)&lds[k * 256 + c4 * 4] = v;
  }
  __syncthreads();
  {
    int px = threadIdx.x;
    float s = 0.f, ss = 0.f;
    #pragma unroll
    for (int k = 0; k < 48; ++k) {
      float v = lds[k * 256 + px];
      s += v; ss = fmaf(v, v, ss);
    }
    float mu = s * (1.f / NC);
    smu[px] = mu;
    srstd[px] = rsqrtf(fmaxf(ss * (1.f / NC) - mu * mu, 0.f) + 1e-5f);
  }
  __syncthreads();
  int lane = threadIdx.x & 63;
  int obase = __builtin_amdgcn_readfirstlane(och * 48 + (threadIdx.x >> 6) * 12);
  float acc[12][4];
  #pragma unroll
  for (int j = 0; j < 12; ++j)
    #pragma unroll
    for (int jj = 0; jj < 4; ++jj) acc[j][jj] = 0.f;
  for (int k = 0; k < 48; ++k) {
    float4 xv = *(const float4*)&lds[k * 256 + lane * 4];
    const float* wr = w + (size_t)obase * 48 + k;
    #pragma unroll
    for (int j = 0; j < 12; ++j) {
      float wv = wr[j * 48];  // scalar load (uniform)
      acc[j][0] = fmaf(wv, xv.x, acc[j][0]);
      acc[j][1] = fmaf(wv, xv.y, acc[j][1]);
      acc[j][2] = fmaf(wv, xv.z, acc[j][2]);
      acc[j][3] = fmaf(wv, xv.w, acc[j][3]);
    }
  }
  float mu0 = smu[lane * 4 + 0], rs0 = srstd[lane * 4 + 0];
  float mu1 = smu[lane * 4 + 1], rs1 = srstd[lane * 4 + 1];
  float mu2 = smu[lane * 4 + 2], rs2 = srstd[lane * 4 + 2];
  float mu3 = smu[lane * 4 + 3], rs3 = srstd[lane * 4 + 3];
  bf16_t* ob = out + (size_t)b * nout * NP + pxbase + lane * 4;
  #pragma unroll
  for (int j = 0; j < 12; ++j) {
    int o = obase + j;
    float Sv = S[o], Bv = Bc[o];
    float r0 = fmaf(rs0, acc[j][0] - mu0 * Sv, Bv);
    float r1 = fmaf(rs1, acc[j][1] - mu1 * Sv, Bv);
    float r2 = fmaf(rs2, acc[j][2] - mu2 * Sv, Bv);
    float r3 = fmaf(rs3, acc[j][3] - mu3 * Sv, Bv);
    *(ushort4*)(ob + (size_t)o * NP) = make_ushort4(f2bf(r0), f2bf(r1), f2bf(r2), f2bf(r3));
  }
}

// ---------------- depthwise 3x3 on 144 channels (4-row stripe, bf16 in/out) ----------------
__global__ __launch_bounds__(256) void k_dw144(const bf16_t* __restrict__ in,
                                               const float* __restrict__ w9,
                                               bf16_t* __restrict__ out) {
  __shared__ float lds[6 * 272];
  int blk = blockIdx.x;
  int rq = blk & 63;
  int ch = (blk >> 6) % 144;
  int b = blk / (144 * 64);
  int yy0 = rq * 4;
  const bf16_t* ib = in + (size_t)(b * 144 + ch) * NP;
  for (int i = threadIdx.x; i < 6 * 68; i += 256) {
    int sr = i / 68, c4 = i % 68;
    int iy = yy0 + sr - 1;
    float4 v = make_float4(0.f, 0.f, 0.f, 0.f);
    if ((unsigned)iy < (unsigned)NH && c4 >= 1 && c4 <= 64) {
      ushort4 u = *(const ushort4*)(ib + iy * NW + (c4 - 1) * 4);
      v = make_float4(bf2f(u.x), bf2f(u.y), bf2f(u.z), bf2f(u.w));
    }
    *(float4*)(&lds[sr * 272 + c4 * 4]) = v;
  }
  __syncthreads();
  int q = threadIdx.x >> 6;
  int quad = threadIdx.x & 63;
  const float* wp = w9 + ch * 9;   // wave-uniform -> scalar loads
  float acc[4] = {0.f, 0.f, 0.f, 0.f};
  #pragma unroll
  for (int rr = 0; rr < 3; ++rr)
    STENCIL_ROW(q + rr, 1, wp[rr * 3 + 0], wp[rr * 3 + 1], wp[rr * 3 + 2], acc);
  *(ushort4*)(out + (size_t)(b * 144 + ch) * NP + (yy0 + q) * NW + quad * 4) =
      make_ushort4(f2bf(acc[0]), f2bf(acc[1]), f2bf(acc[2]), f2bf(acc[3]));
}

// ---------------- per-head Gram (36) + channel ssq (12) partials, fused (bf16 in) ----------------
__global__ void k_gram(const bf16_t* __restrict__ qkvd, float* __restrict__ spart) {
  int gid = blockIdx.x;  // b*64 + h*8 + seg
  int seg = gid & 7, h = (gid >> 3) & 7, b = gid >> 6;
  const bf16_t* qb = qkvd + (size_t)(b * 144 + h * 6) * NP;
  const bf16_t* kb = qkvd + (size_t)(b * 144 + 48 + h * 6) * NP;
  float acc[48];
  #pragma unroll
  for (int j = 0; j < 48; ++j) acc[j] = 0.f;
  for (int i = seg * 8192 + threadIdx.x; i < (seg + 1) * 8192; i += 256) {
    float qv[6], kv[6];
    #pragma unroll
    for (int c = 0; c < 6; ++c) {
      qv[c] = bf2f(qb[(size_t)c * NP + i]);
      kv[c] = bf2f(kb[(size_t)c * NP + i]);
    }
    #pragma unroll
    for (int c = 0; c < 6; ++c)
      #pragma unroll
      for (int d = 0; d < 6; ++d) acc[c * 6 + d] = fmaf(qv[c], kv[d], acc[c * 6 + d]);
    #pragma unroll
    for (int c = 0; c < 6; ++c) acc[36 + c] = fmaf(qv[c], qv[c], acc[36 + c]);
    #pragma unroll
    for (int d = 0; d < 6; ++d) acc[42 + d] = fmaf(kv[d], kv[d], acc[42 + d]);
  }
  int lane = threadIdx.x & 63, wid = threadIdx.x >> 6;
  __shared__ float sr[4 * 48];
  #pragma unroll
  for (int j = 0; j < 48; ++j) {
    float v = acc[j];
    #pragma unroll
    for (int off = 32; off; off >>= 1) v += __shfl_down(v, off, 64);
    if (lane == 0) sr[wid * 48 + j] = v;
  }
  __syncthreads();
  if (threadIdx.x < 48)
    spart[gid * 48 + threadIdx.x] =
        sr[threadIdx.x] + sr[48 + threadIdx.x] + sr[96 + threadIdx.x] + sr[144 + threadIdx.x];
}

// ---------------- attention softmax (tiny; norms from ssq partials) ----------------
__global__ void k_attn(const float* __restrict__ spart, const float* __restrict__ temp,
                       const float* __restrict__ q0m, float* __restrict__ A) {
  int b = blockIdx.x, t = threadIdx.x;
  if (t >= 48) return;
  int h = t / 6, c = t % 6;
  float qs = 0.f;
  for (int seg = 0; seg < 8; ++seg)
    qs += spart[(size_t)((b * 64 + h * 8 + seg) * 48) + 36 + c];
  float nq = fmaxf(sqrtf(qs), 1e-12f);
  float tm = temp[h];
  float lg[6];
  #pragma unroll
  for (int d = 0; d < 6; ++d) {
    float s = 0.f, ks = 0.f;
    for (int seg = 0; seg < 8; ++seg) {
      const float* base = spart + (size_t)((b * 64 + h * 8 + seg) * 48);
      s += base[c * 6 + d];
      ks += base[42 + d];
    }
    float nk = fmaxf(sqrtf(ks), 1e-12f);
    lg[d] = (s / (nq * nk)) * tm * q0m[b * 288 + h * 36 + c * 6 + d];
  }
  float m = lg[0];
  #pragma unroll
  for (int d = 1; d < 6; ++d) m = fmaxf(m, lg[d]);
  float sum = 0.f;
  #pragma unroll
  for (int d = 0; d < 6; ++d) { lg[d] = expf(lg[d] - m); sum += lg[d]; }
  float inv = 1.f / sum;
  #pragma unroll
  for (int d = 0; d < 6; ++d) A[b * 288 + h * 36 + c * 6 + d] = lg[d] * inv;
}

// ---------------- fc mix over the raw-reshape scramble (bf16 in/out) ----------------
__global__ __launch_bounds__(384) void k_fc(const bf16_t* __restrict__ qkvd,
                                            const float* __restrict__ fcw,
                                            const float* __restrict__ fcb,
                                            bf16_t* __restrict__ fconv) {
  __shared__ float sin_[9216];   // 64 pixels * 144
  __shared__ float sout[3456];   // 54 ch * 64 pixels
  int blk = blockIdx.x;
  int b = blk >> 10, p0 = (blk & 1023) << 6;
  const bf16_t* src = qkvd + (size_t)b * 144 * NP + (size_t)p0 * 144;
  const uint4* src4 = (const uint4*)src;
  for (int i = threadIdx.x; i < 1152; i += 384) {
    uint4 u = src4[i];
    float* d = &sin_[i * 8];
    unpack2(u.x, d[0], d[1]);
    unpack2(u.y, d[2], d[3]);
    unpack2(u.z, d[4], d[5]);
    unpack2(u.w, d[6], d[7]);
  }
  __syncthreads();
  int pl = threadIdx.x / 6, c2 = threadIdx.x % 6;
  float xv[24];
  #pragma unroll
  for (int g = 0; g < 24; ++g) xv[g] = sin_[pl * 144 + g * 6 + c2];
  #pragma unroll
  for (int o = 0; o < 9; ++o) {
    float a = fcb[o];
    #pragma unroll
    for (int g = 0; g < 24; ++g) a += fcw[o * 24 + g] * xv[g];
    sout[(c2 * 9 + o) * 64 + pl] = a;
  }
  __syncthreads();
  for (int i = threadIdx.x; i < 1728; i += 384) {
    int ch = i >> 5, pr = (i & 31) * 2;
    *(ushort2*)(fconv + (size_t)(b * 54 + ch) * NP + p0 + pr) =
        make_ushort2(f2bf(sout[ch * 64 + pr]), f2bf(sout[ch * 64 + pr + 1]));
  }
}

// ---------------- grouped dep conv 54->48 (4-row stripe, bf16 in/out) ----------------
__global__ __launch_bounds__(256) void k_depconv(const bf16_t* __restrict__ fconv,
                                                 const float* __restrict__ dw,
                                                 const float* __restrict__ db,
                                                 bf16_t* __restrict__ outconv) {
  __shared__ float lds[9 * 6 * 272];  // 58752 B
  int blk = blockIdx.x;               // b*6*64 + g*64 + rq
  int rq = blk & 63;
  int g = (blk >> 6) % 6;
  int b = blk / (6 * 64);
  int yy0 = rq * 4;
  const bf16_t* fb = fconv + (size_t)(b * 54 + g * 9) * NP;
  for (int i = threadIdx.x; i < 9 * 6 * 68; i += 256) {
    int j = i / 408;
    int rem = i % 408;
    int sr = rem / 68, c4 = rem % 68;
    int iy = yy0 + sr - 1;
    float4 v = make_float4(0.f, 0.f, 0.f, 0.f);
    if ((unsigned)iy < (unsigned)NH && c4 >= 1 && c4 <= 64) {
      ushort4 u = *(const ushort4*)(fb + (size_t)j * NP + iy * NW + (c4 - 1) * 4);
      v = make_float4(bf2f(u.x), bf2f(u.y), bf2f(u.z), bf2f(u.w));
    }
    *(float4*)(&lds[(j * 6 + sr) * 272 + c4 * 4]) = v;
  }
  __syncthreads();
  int q = threadIdx.x >> 6;
  int quad = threadIdx.x & 63;
  float acc[8][4];
  #pragma unroll
  for (int o = 0; o < 8; ++o) {
    float bv = db[g * 8 + o];
    #pragma unroll
    for (int jj = 0; jj < 4; ++jj) acc[o][jj] = bv;
  }
  const float* wg = dw + (size_t)(g * 8) * 81;
  #pragma unroll
  for (int j = 0; j < 9; ++j) {
    #pragma unroll
    for (int rr = 0; rr < 3; ++rr) {
      const float* lp = &lds[((j * 6) + q + rr) * 272 + quad * 4];
      float4 va = *(const float4*)lp;
      float4 vb = *(const float4*)(lp + 4);
      float4 vc = *(const float4*)(lp + 8);
      float v[12] = {va.x, va.y, va.z, va.w, vb.x, vb.y, vb.z, vb.w,
                     vc.x, vc.y, vc.z, vc.w};
      #pragma unroll
      for (int dxi = 0; dxi < 3; ++dxi) {
        int wi = j * 9 + rr * 3 + dxi;
        #pragma unroll
        for (int o = 0; o < 8; ++o) {
          float wv = wg[o * 81 + wi];
          #pragma unroll
          for (int jj = 0; jj < 4; ++jj)
            acc[o][jj] = fmaf(v[jj + dxi + 3], wv, acc[o][jj]);
        }
      }
    }
  }
  bf16_t* ob = outconv + ((size_t)(b * NC + g * 8) * NH + yy0 + q) * NW + quad * 4;
  #pragma unroll
  for (int o = 0; o < 8; ++o)
    *(ushort4*)(ob + (size_t)o * NP) =
        make_ushort4(f2bf(acc[o][0]), f2bf(acc[o][1]), f2bf(acc[o][2]), f2bf(acc[o][3]));
}

// ---------------- fused attn@V + proj + out_conv + residual ----------------
__global__ __launch_bounds__(256, 4) void k_proj(const bf16_t* __restrict__ qkvd,
                                                 const float* __restrict__ A,
                                                 const float* __restrict__ projw,
                                                 const float* __restrict__ x,
                                                 const bf16_t* __restrict__ outconv,
                                                 float* __restrict__ x1) {
  int idx = blockIdx.x * blockDim.x + threadIdx.x;  // exact NB*NP
  int b = idx / NP, p = idx % NP;
  __shared__ float sA[288];
  for (int i = threadIdx.x; i < 288; i += 256) sA[i] = A[b * 288 + i];
  __syncthreads();
  const bf16_t* vb = qkvd + (size_t)(b * 144 + 96) * NP + p;
  float acc[48];
  #pragma unroll
  for (int o = 0; o < 48; ++o) acc[o] = 0.f;
  for (int h = 0; h < 8; ++h) {
    float v6[6];
    #pragma unroll
    for (int d = 0; d < 6; ++d) v6[d] = bf2f(vb[(size_t)(h * 6 + d) * NP]);
    #pragma unroll
    for (int c = 0; c < 6; ++c) {
      float av = 0.f;
      #pragma unroll
      for (int d = 0; d < 6; ++d) av = fmaf(sA[h * 36 + c * 6 + d], v6[d], av);
      const float* wc = projw + h * 6 + c;  // projw[o*48 + (h*6+c)]
      #pragma unroll
      for (int o = 0; o < 48; ++o) acc[o] = fmaf(wc[o * 48], av, acc[o]);
    }
  }
  const float* xb = x + (size_t)b * NC * NP + p;
  const bf16_t* ob = outconv + (size_t)b * NC * NP + p;
  float* x1b = x1 + (size_t)b * NC * NP + p;
  #pragma unroll
  for (int o = 0; o < 48; ++o)
    x1b[(size_t)o * NP] = xb[(size_t)o * NP] + acc[o] + bf2f(ob[(size_t)o * NP]);
}

// ---------------- FF: 3-dilation depthwise + gelu gate (bf16 in/out) ----------------
__global__ __launch_bounds__(256) void k_ffdw(const bf16_t* __restrict__ y,
                                              const float* __restrict__ w1,
                                              const float* __restrict__ w2,
                                              const float* __restrict__ w3,
                                              bf16_t* __restrict__ z) {
  __shared__ float lds[24 * 272];  // 26112 B
  int blk = blockIdx.x;
  int rq = blk & 63;
  int ch = (blk >> 6) % NHID;
  int b = blk / (NHID * 64);
  int yy0 = rq * 4;
  const bf16_t* yb = y + (size_t)(b * 288 + ch) * NP;
  for (int i = threadIdx.x; i < 24 * 68; i += 256) {
    int sr = i / 68, c4 = i % 68;
    int br, iy;
    if (sr < 6)       { br = 0; iy = yy0 + sr - 1; }
    else if (sr < 14) { br = 1; iy = yy0 + sr - 8; }
    else              { br = 2; iy = yy0 + sr - 17; }
    float4 v = make_float4(0.f, 0.f, 0.f, 0.f);
    if ((unsigned)iy < (unsigned)NH && c4 >= 1 && c4 <= 64) {
      ushort4 u = *(const ushort4*)(yb + (size_t)(br * NHID) * NP + iy * NW + (c4 - 1) * 4);
      v = make_float4(bf2f(u.x), bf2f(u.y), bf2f(u.z), bf2f(u.w));
    }
    *(float4*)(&lds[sr * 272 + c4 * 4]) = v;
  }
  __syncthreads();
  int q = threadIdx.x >> 6;
  int quad = threadIdx.x & 63;
  const float* wp1 = w1 + ch * 9;   // wave-uniform -> scalar loads
  const float* wp2 = w2 + ch * 9;
  const float* wp3 = w3 + ch * 9;
  float c1[4] = {0.f, 0.f, 0.f, 0.f};
  float c2[4] = {0.f, 0.f, 0.f, 0.f};
  float c3[4] = {0.f, 0.f, 0.f, 0.f};
  #pragma unroll
  for (int rr = 0; rr < 3; ++rr)
    STENCIL_ROW(0 + q + rr * 1, 1, wp1[rr * 3 + 0], wp1[rr * 3 + 1], wp1[rr * 3 + 2], c1);
  #pragma unroll
  for (int rr = 0; rr < 3; ++rr)
    STENCIL_ROW(6 + q + rr * 2, 2, wp2[rr * 3 + 0], wp2[rr * 3 + 1], wp2[rr * 3 + 2], c2);
  #pragma unroll
  for (int rr = 0; rr < 3; ++rr)
    STENCIL_ROW(14 + q + rr * 3, 3, wp3[rr * 3 + 0], wp3[rr * 3 + 1], wp3[rr * 3 + 2], c3);
  *(ushort4*)(z + (size_t)(b * NHID + ch) * NP + (yy0 + q) * NW + quad * 4) =
      make_ushort4(f2bf(gelu_f(c1[0]) * c2[0] * c3[0]),
                   f2bf(gelu_f(c1[1]) * c2[1] * c3[1]),
                   f2bf(gelu_f(c1[2]) * c2[2] * c3[2]),
                   f2bf(gelu_f(c1[3]) * c2[3] * c3[3]));
}

// ---------------- pout + residual -> d_out (streamed, acc[48], bf16 z) ----------------
__global__ __launch_bounds__(256, 4) void k_pout(const bf16_t* __restrict__ z,
                                                 const float* __restrict__ poutw,
                                                 const float* __restrict__ x1,
                                                 float* __restrict__ outp) {
  int idx = blockIdx.x * blockDim.x + threadIdx.x;  // exact NB*NP
  int b = idx / NP, p = idx % NP;
  const bf16_t* zb = z + (size_t)b * NHID * NP + p;
  float acc[48];
  #pragma unroll
  for (int o = 0; o < 48; ++o) acc[o] = 0.f;
  for (int j = 0; j < 96; ++j) {
    float zv = bf2f(zb[(size_t)j * NP]);
    const float* wc = poutw + j;  // poutw[o*96 + j]
    #pragma unroll
    for (int o = 0; o < 48; ++o) acc[o] = fmaf(wc[o * 96], zv, acc[o]);
  }
  const float* x1b = x1 + (size_t)b * NC * NP + p;
  float* ob = outp + (size_t)b * NC * NP + p;
  #pragma unroll
  for (int o = 0; o < 48; ++o)
    ob[(size_t)o * NP] = x1b[(size_t)o * NP] + acc[o];
}

// ---------------- workspace layout (float offsets; bf16 buffers use half) ----------------
constexpr size_t SZ_QKV = (size_t)NB * 144 * NP;
constexpr size_t SZ_CHW = (size_t)NB * NC * NP;
constexpr size_t OFF_QKV0 = 0;
constexpr size_t OFF_QKVD = OFF_QKV0 + SZ_QKV;         // bf16 buffers: region oversized, fine
constexpr size_t OFF_FCONV = OFF_QKVD + SZ_QKV;
constexpr size_t SZ_FCONV = (size_t)NB * 54 * NP;
constexpr size_t OFF_OUTCONV = OFF_FCONV + SZ_FCONV;
constexpr size_t OFF_X1 = OFF_OUTCONV + SZ_CHW;
constexpr size_t OFF_STATS = OFF_X1 + SZ_CHW;          // (slot retained, unused)
constexpr size_t OFF_T1 = OFF_STATS + (size_t)NB * NP * 2;
constexpr size_t OFF_P1 = OFF_T1 + (size_t)NB * NC * 128 * 128;
constexpr size_t OFF_T2 = OFF_P1 + (size_t)NB * NC * 64 * 64;
constexpr size_t OFF_P2 = OFF_T2 + (size_t)NB * NC * 32 * 32;
constexpr size_t OFF_T3 = OFF_P2 + (size_t)NB * NC * 16 * 16;   // reused: SB + scaled weights
constexpr size_t OFF_P3 = OFF_T3 + (size_t)NB * NC * 8 * 8;
constexpr size_t OFF_Q0M = OFF_P3 + (size_t)NB * NC * 4 * 4;
constexpr size_t OFF_NORMS = OFF_Q0M + 576;
constexpr size_t OFF_SPART = OFF_NORMS + 192;
constexpr size_t OFF_A = OFF_SPART + (size_t)NB * 64 * 48;

extern "C" void kernel_launch(void* const* d_in, const int* in_sizes, int n_in,
                              void* d_out, int out_size, void* d_ws, size_t ws_size,
                              hipStream_t stream) {
  const float* x     = (const float*)d_in[0];
  const float* ln1w  = (const float*)d_in[1];
  const float* ln1b  = (const float*)d_in[2];
  const float* qkvw  = (const float*)d_in[3];
  const float* qkvdw = (const float*)d_in[4];
  const float* projw = (const float*)d_in[5];
  const float* fcw   = (const float*)d_in[6];
  const float* fcb   = (const float*)d_in[7];
  const float* depw  = (const float*)d_in[8];
  const float* depb  = (const float*)d_in[9];
  const float* l2qw  = (const float*)d_in[10];
  const float* l2qb  = (const float*)d_in[11];
  const float* temp  = (const float*)d_in[12];
  const float* ln2w  = (const float*)d_in[13];
  const float* ln2b  = (const float*)d_in[14];
  const float* pinw  = (const float*)d_in[15];
  const float* dw1   = (const float*)d_in[16];
  const float* dw2   = (const float*)d_in[17];
  const float* dw3   = (const float*)d_in[18];
  const float* poutw = (const float*)d_in[19];
  const float* cvw0  = (const float*)d_in[20];
  const float* cvb0  = (const float*)d_in[21];
  const float* clw0  = (const float*)d_in[22];
  const float* clb0  = (const float*)d_in[23];
  const float* cvw1  = (const float*)d_in[24];
  const float* cvb1  = (const float*)d_in[25];
  const float* clw1  = (const float*)d_in[26];
  const float* clb1  = (const float*)d_in[27];
  const float* cvw2  = (const float*)d_in[28];
  const float* cvb2  = (const float*)d_in[29];
  const float* clw2  = (const float*)d_in[30];
  const float* clb2  = (const float*)d_in[31];

  float* ws = (float*)d_ws;
  bf16_t* qkv0 = (bf16_t*)(ws + OFF_QKV0);
  bf16_t* qkvd = (bf16_t*)(ws + OFF_QKVD);
  bf16_t* fconv = (bf16_t*)(ws + OFF_FCONV);
  bf16_t* outconv = (bf16_t*)(ws + OFF_OUTCONV);
  float* x1 = ws + OFF_X1;
  float* t1 = ws + OFF_T1;
  float* p1 = ws + OFF_P1;
  float* t2 = ws + OFF_T2;
  float* p2 = ws + OFF_P2;
  float* t3 = ws + OFF_T3;
  float* p3 = ws + OFF_P3;
  float* q0m = ws + OFF_Q0M;
  float* spart = ws + OFF_SPART;
  float* A = ws + OFF_A;
  float* SB = ws + OFF_T3;            // 864 floats
  float* W1s = ws + OFF_T3 + 864;     // 144*48 = 6912
  float* W2s = ws + OFF_T3 + 864 + 6912;  // 288*48 = 13824 (total 21600 <= 24576 region)
  bf16_t* ybuf = (bf16_t*)(ws + OFF_QKV0);   // reuse qkv0 region (bf16, fits)
  bf16_t* zbuf = (bf16_t*)(ws + OFF_FCONV);  // reuse fconv region (bf16, fits)

  // conv-descriptor branch (ic-chunked LDS convs, 8-wave blocks)
  k_conv_s2_tile<<<512, 512, 0, stream>>>(x, cvw0, cvb0, t1, 256, 256, 128, 128);
  k_lnpool<<<32, 256, 0, stream>>>(t1, clw0, clb0, p1, 128, 128);
  k_conv_s2_tile<<<32, 512, 0, stream>>>(p1, cvw1, cvb1, t2, 64, 64, 32, 32);
  k_lnpool<<<2, 256, 0, stream>>>(t2, clw1, clb1, p2, 32, 32);
  k_conv_s2_tile<<<2, 512, 0, stream>>>(p2, cvw2, cvb2, t3, 16, 16, 8, 8);
  k_lnpool<<<1, 256, 0, stream>>>(t3, clw2, clb2, p3, 8, 8);
  k_head<<<2, 320, 0, stream>>>(p3, l2qw, l2qb, q0m);

  // LN folding setup (after conv branch frees t3 region)
  k_prep<<<4, 256, 0, stream>>>(qkvw, ln1w, ln1b, pinw, ln2w, ln2b, SB, W1s, W2s);

  // attention
  k_chmix_gemm<<<1536, 256, 0, stream>>>(x, W1s, SB, SB + 144, qkv0, 144, 3);
  k_dw144<<<18432, 256, 0, stream>>>(qkv0, qkvdw, qkvd);
  k_gram<<<128, 256, 0, stream>>>(qkvd, spart);
  k_attn<<<2, 64, 0, stream>>>(spart, temp, q0m, A);
  k_fc<<<2048, 384, 0, stream>>>(qkvd, fcw, fcb, fconv);
  k_depconv<<<768, 256, 0, stream>>>(fconv, depw, depb, outconv);
  k_proj<<<512, 256, 0, stream>>>(qkvd, A, projw, x, outconv, x1);

  // feedforward
  k_chmix_gemm<<<3072, 256, 0, stream>>>(x1, W2s, SB + 288, SB + 576, ybuf, 288, 6);
  k_ffdw<<<12288, 256, 0, stream>>>(ybuf, dw1, dw2, dw3, zbuf);
  k_pout<<<512, 256, 0, stream>>>(zbuf, poutw, x1, (float*)d_out);
}

// Round 12
// 502.844 us; speedup vs baseline: 4.4442x; 1.0887x over previous
//
#include <hip/hip_runtime.h>

constexpr int NB = 2;
constexpr int NC = 48;
constexpr int NH = 256;
constexpr int NW = 256;
constexpr int NP = NH * NW;           // 65536
constexpr int NHEADS = 8;
constexpr int NCHD = 6;
constexpr int NHID = 96;
constexpr int GSEG = 64;              // gram segments per (b,h)

typedef unsigned short bf16_t;

__device__ __forceinline__ float bf2f(bf16_t u) {
  union { unsigned int i; float f; } c; c.i = ((unsigned int)u) << 16; return c.f;
}
__device__ __forceinline__ bf16_t f2bf(float f) {
  union { float f; unsigned int i; } c; c.f = f;
  unsigned int r = (c.i + 0x7FFFu + ((c.i >> 16) & 1u)) >> 16;
  return (bf16_t)r;
}
__device__ __forceinline__ void unpack2(unsigned int u, float& a, float& b) {
  union { unsigned int i; float f; } c0, c1;
  c0.i = u << 16; c1.i = u & 0xffff0000u;
  a = c0.f; b = c1.f;
}

__device__ __forceinline__ float gelu_f(float v) {
  return 0.5f * v * (1.0f + erff(v * 0.70710678118654752f));
}

// tap loop over a 12-float window (3x ds_read_b128), compile-time indices.
#define STENCIL_ROW(LROW, D, WVAL0, WVAL1, WVAL2, ACC)                        \
  {                                                                            \
    const float* lp = &lds[(LROW) * 272 + quad * 4];                           \
    float4 va = *(const float4*)lp;                                            \
    float4 vb = *(const float4*)(lp + 4);                                      \
    float4 vc = *(const float4*)(lp + 8);                                      \
    float v[12] = {va.x, va.y, va.z, va.w, vb.x, vb.y, vb.z, vb.w,             \
                   vc.x, vc.y, vc.z, vc.w};                                    \
    _Pragma("unroll") for (int jj = 0; jj < 4; ++jj) {                         \
      ACC[jj] = fmaf(v[jj - (D) + 4], WVAL0, ACC[jj]);                         \
      ACC[jj] = fmaf(v[jj + 4], WVAL1, ACC[jj]);                               \
      ACC[jj] = fmaf(v[jj + (D) + 4], WVAL2, ACC[jj]);                         \
    }                                                                          \
  }

// ---------------- conv-descriptor branch: ic-chunked, 8-wave blocks (6 oc/wave) ----------------
__global__ __launch_bounds__(512) void k_conv_s2_tile(const float* __restrict__ in,
                                                      const float* __restrict__ w,
                                                      const float* __restrict__ bias,
                                                      float* __restrict__ out,
                                                      int IH, int IW, int OH, int OW) {
  __shared__ float lds[16 * 442];  // 16 ic * 17 rows * 26 = 28288 B
  int tilesX = OW >> 3;
  int tilesY = OH >> 3;
  int blk = blockIdx.x;
  int tx = blk % tilesX;
  int t = blk / tilesX;
  int ty = t % tilesY;
  int b = t / tilesY;
  int oy0 = ty * 8, ox0 = tx * 8;
  int iy0 = oy0 * 2 - 1, ix0 = ox0 * 2 - 1;
  const float* inb = in + (size_t)b * NC * IH * IW;

  int lane = threadIdx.x & 63;
  int oy = lane >> 3, ox = lane & 7;
  int ocb = __builtin_amdgcn_readfirstlane((threadIdx.x >> 6) * 6);
  float acc[6];
  #pragma unroll
  for (int j = 0; j < 6; ++j) acc[j] = bias[ocb + j];
  int rbase = oy * 52;  // row 2*oy, stride 26

  for (int chunk = 0; chunk < 3; ++chunk) {
    int icb = chunk * 16;
    for (int i = threadIdx.x; i < 16 * 17 * 17; i += 512) {
      int cc = i % 17;
      int t2 = i / 17;
      int rr = t2 % 17;
      int ic = t2 / 17;
      float v = 0.f;
      int iy = iy0 + rr, ix = ix0 + cc;
      if ((unsigned)iy < (unsigned)IH && (unsigned)ix < (unsigned)IW)
        v = inb[((size_t)(icb + ic) * IH + iy) * IW + ix];
      lds[ic * 442 + rr * 26 + ((cc & 1) ? 13 + (cc >> 1) : (cc >> 1))] = v;
    }
    __syncthreads();

    for (int ic16 = 0; ic16 < 16; ++ic16) {
      const float* base = lds + ic16 * 442 + rbase;
      float e0[3], e1[3], ov[3];
      #pragma unroll
      for (int ky = 0; ky < 3; ++ky) {
        const float* rowp = base + ky * 26;
        e0[ky] = rowp[ox];
        e1[ky] = rowp[ox + 1];
        ov[ky] = rowp[13 + ox];
      }
      const float* wpc = w + (size_t)(ocb * 48 + icb + ic16) * 9;
      #pragma unroll
      for (int j = 0; j < 6; ++j) {
        const float* wp = wpc + (size_t)j * 48 * 9;
        float a = acc[j];
        #pragma unroll
        for (int ky = 0; ky < 3; ++ky) {
          a = fmaf(wp[ky * 3 + 0], e0[ky], a);
          a = fmaf(wp[ky * 3 + 1], ov[ky], a);
          a = fmaf(wp[ky * 3 + 2], e1[ky], a);
        }
        acc[j] = a;
      }
    }
    __syncthreads();
  }

  float* ob = out + (size_t)b * NC * OH * OW;
  #pragma unroll
  for (int j = 0; j < 6; ++j)
    ob[((size_t)(ocb + j) * OH + oy0 + oy) * OW + ox0 + ox] = acc[j];
}

__global__ void k_lnpool(const float* __restrict__ in, const float* __restrict__ lw,
                         const float* __restrict__ lb, float* __restrict__ out,
                         int IH, int IW) {
  int OH = IH >> 1, OW = IW >> 1;
  int idx = blockIdx.x * blockDim.x + threadIdx.x;
  int total = NB * OH * OW;
  if (idx >= total) return;
  int ox = idx % OW;
  int t = idx / OW;
  int oy = t % OH;
  int b = t / OH;
  const float* inb = in + (size_t)b * NC * IH * IW;
  float mu[4], rs[4];
  #pragma unroll
  for (int q = 0; q < 4; ++q) {
    int iy = oy * 2 + (q >> 1), ix = ox * 2 + (q & 1);
    float s = 0.f, ss = 0.f;
    for (int c = 0; c < NC; ++c) {
      float v = inb[((size_t)c * IH + iy) * IW + ix];
      s += v; ss += v * v;
    }
    float m = s * (1.f / NC);
    mu[q] = m;
    rs[q] = rsqrtf(fmaxf(ss * (1.f / NC) - m * m, 0.f) + 1e-5f);
  }
  for (int c = 0; c < NC; ++c) {
    float best = 0.f;  // relu >= 0 so 0 == max of relu'd window
    float wv = lw[c], bv = lb[c];
    #pragma unroll
    for (int q = 0; q < 4; ++q) {
      int iy = oy * 2 + (q >> 1), ix = ox * 2 + (q & 1);
      float v = inb[((size_t)c * IH + iy) * IW + ix];
      v = (v - mu[q]) * rs[q] * wv + bv;
      best = fmaxf(best, fmaxf(v, 0.f));
    }
    out[((size_t)(b * NC + c) * OH + oy) * OW + ox] = best;
  }
}

__global__ void k_head(const float* __restrict__ p3, const float* __restrict__ l2qw,
                       const float* __restrict__ l2qb, float* __restrict__ q0m) {
  __shared__ float xd[NC], q0[NC];
  int b = blockIdx.x, t = threadIdx.x;
  if (t < NC) {
    float s = 0.f;
    for (int i = 0; i < 16; ++i) s += p3[(b * NC + t) * 16 + i];
    xd[t] = gelu_f(s * (1.f / 16.f));
  }
  __syncthreads();
  if (t < NC) {
    float a = l2qb[t];
    for (int c = 0; c < NC; ++c) a += xd[c] * l2qw[t * NC + c];
    q0[t] = a;
  }
  __syncthreads();
  if (t < NHEADS * NCHD * NCHD) {
    int h = t / 36, r = t % 36, c = r / 6, d = r % 6;
    q0m[b * 288 + t] = q0[h * 6 + c] * q0[h * 6 + d];
  }
}

// ---------------- prep: S/B vectors + lnw-prescaled weight copies ----------------
__global__ void k_prep(const float* __restrict__ qkvw, const float* __restrict__ ln1w,
                       const float* __restrict__ ln1b, const float* __restrict__ pinw,
                       const float* __restrict__ ln2w, const float* __restrict__ ln2b,
                       float* __restrict__ SB, float* __restrict__ W1s,
                       float* __restrict__ W2s) {
  int t = blockIdx.x * blockDim.x + threadIdx.x;
  int stride = gridDim.x * blockDim.x;
  if (t < 144) {
    float s = 0.f, bb = 0.f;
    for (int c = 0; c < 48; ++c) {
      float w = qkvw[t * 48 + c];
      s = fmaf(w, ln1w[c], s); bb = fmaf(w, ln1b[c], bb);
    }
    SB[t] = s; SB[144 + t] = bb;
  } else if (t < 144 + 288) {
    int o = t - 144;
    float s = 0.f, bb = 0.f;
    for (int c = 0; c < 48; ++c) {
      float w = pinw[o * 48 + c];
      s = fmaf(w, ln2w[c], s); bb = fmaf(w, ln2b[c], bb);
    }
    SB[288 + o] = s; SB[576 + o] = bb;
  }
  for (int i = t; i < 144 * 48; i += stride) W1s[i] = qkvw[i] * ln1w[i % 48];
  for (int i = t; i < 288 * 48; i += stride) W2s[i] = pinw[i] * ln2w[i % 48];
}

// ---------------- channel-mix GEMM: raw x tile + in-block LN stats, bf16 out ----------------
__global__ __launch_bounds__(256) void k_chmix_gemm(const float* __restrict__ x,
                                                    const float* __restrict__ w,
                                                    const float* __restrict__ S,
                                                    const float* __restrict__ Bc,
                                                    bf16_t* __restrict__ out,
                                                    int nout, int nch) {
  __shared__ float lds[48 * 256];  // 49152 B
  __shared__ float smu[256], srstd[256];
  int blk = blockIdx.x;
  int och = blk % nch;
  int pxt = (blk / nch) & 255;
  int b = blk / (nch * 256);
  int pxbase = pxt * 256;
  const float* xb = x + (size_t)b * NC * NP + pxbase;
  for (int i = threadIdx.x; i < 48 * 64; i += 256) {
    int k = i >> 6, c4 = i & 63;
    float4 v = *(const float4*)(xb + (size_t)k * NP + c4 * 4);
    *(float4*)&lds[k * 256 + c4 * 4] = v;
  }
  __syncthreads();
  {
    int px = threadIdx.x;
    float s = 0.f, ss = 0.f;
    #pragma unroll
    for (int k = 0; k < 48; ++k) {
      float v = lds[k * 256 + px];
      s += v; ss = fmaf(v, v, ss);
    }
    float mu = s * (1.f / NC);
    smu[px] = mu;
    srstd[px] = rsqrtf(fmaxf(ss * (1.f / NC) - mu * mu, 0.f) + 1e-5f);
  }
  __syncthreads();
  int lane = threadIdx.x & 63;
  int obase = __builtin_amdgcn_readfirstlane(och * 48 + (threadIdx.x >> 6) * 12);
  float acc[12][4];
  #pragma unroll
  for (int j = 0; j < 12; ++j)
    #pragma unroll
    for (int jj = 0; jj < 4; ++jj) acc[j][jj] = 0.f;
  for (int k = 0; k < 48; ++k) {
    float4 xv = *(const float4*)&lds[k * 256 + lane * 4];
    const float* wr = w + (size_t)obase * 48 + k;
    #pragma unroll
    for (int j = 0; j < 12; ++j) {
      float wv = wr[j * 48];  // scalar load (uniform)
      acc[j][0] = fmaf(wv, xv.x, acc[j][0]);
      acc[j][1] = fmaf(wv, xv.y, acc[j][1]);
      acc[j][2] = fmaf(wv, xv.z, acc[j][2]);
      acc[j][3] = fmaf(wv, xv.w, acc[j][3]);
    }
  }
  float mu0 = smu[lane * 4 + 0], rs0 = srstd[lane * 4 + 0];
  float mu1 = smu[lane * 4 + 1], rs1 = srstd[lane * 4 + 1];
  float mu2 = smu[lane * 4 + 2], rs2 = srstd[lane * 4 + 2];
  float mu3 = smu[lane * 4 + 3], rs3 = srstd[lane * 4 + 3];
  bf16_t* ob = out + (size_t)b * nout * NP + pxbase + lane * 4;
  #pragma unroll
  for (int j = 0; j < 12; ++j) {
    int o = obase + j;
    float Sv = S[o], Bv = Bc[o];
    float r0 = fmaf(rs0, acc[j][0] - mu0 * Sv, Bv);
    float r1 = fmaf(rs1, acc[j][1] - mu1 * Sv, Bv);
    float r2 = fmaf(rs2, acc[j][2] - mu2 * Sv, Bv);
    float r3 = fmaf(rs3, acc[j][3] - mu3 * Sv, Bv);
    *(ushort4*)(ob + (size_t)o * NP) = make_ushort4(f2bf(r0), f2bf(r1), f2bf(r2), f2bf(r3));
  }
}

// ---------------- depthwise 3x3 on 144 channels (4-row stripe, bf16 in/out) ----------------
__global__ __launch_bounds__(256) void k_dw144(const bf16_t* __restrict__ in,
                                               const float* __restrict__ w9,
                                               bf16_t* __restrict__ out) {
  __shared__ float lds[6 * 272];
  int blk = blockIdx.x;
  int rq = blk & 63;
  int ch = (blk >> 6) % 144;
  int b = blk / (144 * 64);
  int yy0 = rq * 4;
  const bf16_t* ib = in + (size_t)(b * 144 + ch) * NP;
  for (int i = threadIdx.x; i < 6 * 68; i += 256) {
    int sr = i / 68, c4 = i % 68;
    int iy = yy0 + sr - 1;
    float4 v = make_float4(0.f, 0.f, 0.f, 0.f);
    if ((unsigned)iy < (unsigned)NH && c4 >= 1 && c4 <= 64) {
      ushort4 u = *(const ushort4*)(ib + iy * NW + (c4 - 1) * 4);
      v = make_float4(bf2f(u.x), bf2f(u.y), bf2f(u.z), bf2f(u.w));
    }
    *(float4*)(&lds[sr * 272 + c4 * 4]) = v;
  }
  __syncthreads();
  int q = threadIdx.x >> 6;
  int quad = threadIdx.x & 63;
  const float* wp = w9 + ch * 9;   // wave-uniform -> scalar loads
  float acc[4] = {0.f, 0.f, 0.f, 0.f};
  #pragma unroll
  for (int rr = 0; rr < 3; ++rr)
    STENCIL_ROW(q + rr, 1, wp[rr * 3 + 0], wp[rr * 3 + 1], wp[rr * 3 + 2], acc);
  *(ushort4*)(out + (size_t)(b * 144 + ch) * NP + (yy0 + q) * NW + quad * 4) =
      make_ushort4(f2bf(acc[0]), f2bf(acc[1]), f2bf(acc[2]), f2bf(acc[3]));
}

// ---------------- per-head Gram (36) + channel ssq (12) partials, 64-seg, packed loads ----------------
__global__ __launch_bounds__(256) void k_gram(const bf16_t* __restrict__ qkvd,
                                              float* __restrict__ spart) {
  int gid = blockIdx.x;  // b*512 + h*64 + seg
  int seg = gid & (GSEG - 1), h = (gid >> 6) & 7, b = gid >> 9;
  const bf16_t* qb = qkvd + (size_t)(b * 144 + h * 6) * NP;
  const bf16_t* kb = qkvd + (size_t)(b * 144 + 48 + h * 6) * NP;
  float acc[48];
  #pragma unroll
  for (int j = 0; j < 48; ++j) acc[j] = 0.f;
  int p0 = seg * (NP / GSEG) + threadIdx.x * 4;
  float qv[6][4], kv[6][4];
  #pragma unroll
  for (int c = 0; c < 6; ++c) {
    ushort4 uq = *(const ushort4*)(qb + (size_t)c * NP + p0);
    qv[c][0] = bf2f(uq.x); qv[c][1] = bf2f(uq.y); qv[c][2] = bf2f(uq.z); qv[c][3] = bf2f(uq.w);
    ushort4 uk = *(const ushort4*)(kb + (size_t)c * NP + p0);
    kv[c][0] = bf2f(uk.x); kv[c][1] = bf2f(uk.y); kv[c][2] = bf2f(uk.z); kv[c][3] = bf2f(uk.w);
  }
  #pragma unroll
  for (int px = 0; px < 4; ++px) {
    #pragma unroll
    for (int c = 0; c < 6; ++c)
      #pragma unroll
      for (int d = 0; d < 6; ++d)
        acc[c * 6 + d] = fmaf(qv[c][px], kv[d][px], acc[c * 6 + d]);
    #pragma unroll
    for (int c = 0; c < 6; ++c) acc[36 + c] = fmaf(qv[c][px], qv[c][px], acc[36 + c]);
    #pragma unroll
    for (int d = 0; d < 6; ++d) acc[42 + d] = fmaf(kv[d][px], kv[d][px], acc[42 + d]);
  }
  int lane = threadIdx.x & 63, wid = threadIdx.x >> 6;
  __shared__ float sr[4 * 48];
  #pragma unroll
  for (int j = 0; j < 48; ++j) {
    float v = acc[j];
    #pragma unroll
    for (int off = 32; off; off >>= 1) v += __shfl_down(v, off, 64);
    if (lane == 0) sr[wid * 48 + j] = v;
  }
  __syncthreads();
  if (threadIdx.x < 48)
    spart[(size_t)gid * 48 + threadIdx.x] =
        sr[threadIdx.x] + sr[48 + threadIdx.x] + sr[96 + threadIdx.x] + sr[144 + threadIdx.x];
}

// ---------------- attention softmax (cooperative 64-seg reduce + softmax) ----------------
__global__ __launch_bounds__(256) void k_attn(const float* __restrict__ spart,
                                              const float* __restrict__ temp,
                                              const float* __restrict__ q0m,
                                              float* __restrict__ A) {
  int b = blockIdx.x;
  __shared__ float tot[8 * 48];
  for (int j = threadIdx.x; j < 384; j += 256) {
    int h = j / 48, v = j % 48;
    const float* base = spart + ((size_t)(b * 8 + h) * GSEG) * 48 + v;
    float s = 0.f;
    for (int seg = 0; seg < GSEG; ++seg) s += base[(size_t)seg * 48];
    tot[j] = s;
  }
  __syncthreads();
  int t = threadIdx.x;
  if (t >= 48) return;
  int h = t / 6, c = t % 6;
  const float* T = &tot[h * 48];
  float nq = fmaxf(sqrtf(T[36 + c]), 1e-12f);
  float tm = temp[h];
  float lg[6];
  #pragma unroll
  for (int d = 0; d < 6; ++d) {
    float nk = fmaxf(sqrtf(T[42 + d]), 1e-12f);
    lg[d] = (T[c * 6 + d] / (nq * nk)) * tm * q0m[b * 288 + h * 36 + c * 6 + d];
  }
  float m = lg[0];
  #pragma unroll
  for (int d = 1; d < 6; ++d) m = fmaxf(m, lg[d]);
  float sum = 0.f;
  #pragma unroll
  for (int d = 0; d < 6; ++d) { lg[d] = expf(lg[d] - m); sum += lg[d]; }
  float inv = 1.f / sum;
  #pragma unroll
  for (int d = 0; d < 6; ++d) A[b * 288 + h * 36 + c * 6 + d] = lg[d] * inv;
}

// ---------------- fc mix over the raw-reshape scramble (bf16 in/out) ----------------
__global__ __launch_bounds__(384) void k_fc(const bf16_t* __restrict__ qkvd,
                                            const float* __restrict__ fcw,
                                            const float* __restrict__ fcb,
                                            bf16_t* __restrict__ fconv) {
  __shared__ float sin_[9216];   // 64 pixels * 144
  __shared__ float sout[3456];   // 54 ch * 64 pixels
  int blk = blockIdx.x;
  int b = blk >> 10, p0 = (blk & 1023) << 6;
  const bf16_t* src = qkvd + (size_t)b * 144 * NP + (size_t)p0 * 144;
  const uint4* src4 = (const uint4*)src;
  for (int i = threadIdx.x; i < 1152; i += 384) {
    uint4 u = src4[i];
    float* d = &sin_[i * 8];
    unpack2(u.x, d[0], d[1]);
    unpack2(u.y, d[2], d[3]);
    unpack2(u.z, d[4], d[5]);
    unpack2(u.w, d[6], d[7]);
  }
  __syncthreads();
  int pl = threadIdx.x / 6, c2 = threadIdx.x % 6;
  float xv[24];
  #pragma unroll
  for (int g = 0; g < 24; ++g) xv[g] = sin_[pl * 144 + g * 6 + c2];
  #pragma unroll
  for (int o = 0; o < 9; ++o) {
    float a = fcb[o];
    #pragma unroll
    for (int g = 0; g < 24; ++g) a += fcw[o * 24 + g] * xv[g];
    sout[(c2 * 9 + o) * 64 + pl] = a;
  }
  __syncthreads();
  for (int i = threadIdx.x; i < 1728; i += 384) {
    int ch = i >> 5, pr = (i & 31) * 2;
    *(ushort2*)(fconv + (size_t)(b * 54 + ch) * NP + p0 + pr) =
        make_ushort2(f2bf(sout[ch * 64 + pr]), f2bf(sout[ch * 64 + pr + 1]));
  }
}

// ---------------- grouped dep conv 54->48 (4-row stripe, bf16 in/out) ----------------
__global__ __launch_bounds__(256) void k_depconv(const bf16_t* __restrict__ fconv,
                                                 const float* __restrict__ dw,
                                                 const float* __restrict__ db,
                                                 bf16_t* __restrict__ outconv) {
  __shared__ float lds[9 * 6 * 272];  // 58752 B
  int blk = blockIdx.x;               // b*6*64 + g*64 + rq
  int rq = blk & 63;
  int g = (blk >> 6) % 6;
  int b = blk / (6 * 64);
  int yy0 = rq * 4;
  const bf16_t* fb = fconv + (size_t)(b * 54 + g * 9) * NP;
  for (int i = threadIdx.x; i < 9 * 6 * 68; i += 256) {
    int j = i / 408;
    int rem = i % 408;
    int sr = rem / 68, c4 = rem % 68;
    int iy = yy0 + sr - 1;
    float4 v = make_float4(0.f, 0.f, 0.f, 0.f);
    if ((unsigned)iy < (unsigned)NH && c4 >= 1 && c4 <= 64) {
      ushort4 u = *(const ushort4*)(fb + (size_t)j * NP + iy * NW + (c4 - 1) * 4);
      v = make_float4(bf2f(u.x), bf2f(u.y), bf2f(u.z), bf2f(u.w));
    }
    *(float4*)(&lds[(j * 6 + sr) * 272 + c4 * 4]) = v;
  }
  __syncthreads();
  int q = threadIdx.x >> 6;
  int quad = threadIdx.x & 63;
  float acc[8][4];
  #pragma unroll
  for (int o = 0; o < 8; ++o) {
    float bv = db[g * 8 + o];
    #pragma unroll
    for (int jj = 0; jj < 4; ++jj) acc[o][jj] = bv;
  }
  const float* wg = dw + (size_t)(g * 8) * 81;
  #pragma unroll
  for (int j = 0; j < 9; ++j) {
    #pragma unroll
    for (int rr = 0; rr < 3; ++rr) {
      const float* lp = &lds[((j * 6) + q + rr) * 272 + quad * 4];
      float4 va = *(const float4*)lp;
      float4 vb = *(const float4*)(lp + 4);
      float4 vc = *(const float4*)(lp + 8);
      float v[12] = {va.x, va.y, va.z, va.w, vb.x, vb.y, vb.z, vb.w,
                     vc.x, vc.y, vc.z, vc.w};
      #pragma unroll
      for (int dxi = 0; dxi < 3; ++dxi) {
        int wi = j * 9 + rr * 3 + dxi;
        #pragma unroll
        for (int o = 0; o < 8; ++o) {
          float wv = wg[o * 81 + wi];
          #pragma unroll
          for (int jj = 0; jj < 4; ++jj)
            acc[o][jj] = fmaf(v[jj + dxi + 3], wv, acc[o][jj]);
        }
      }
    }
  }
  bf16_t* ob = outconv + ((size_t)(b * NC + g * 8) * NH + yy0 + q) * NW + quad * 4;
  #pragma unroll
  for (int o = 0; o < 8; ++o)
    *(ushort4*)(ob + (size_t)o * NP) =
        make_ushort4(f2bf(acc[o][0]), f2bf(acc[o][1]), f2bf(acc[o][2]), f2bf(acc[o][3]));
}

// ---------------- fused attn@V + proj + out_conv + residual ----------------
__global__ __launch_bounds__(256, 4) void k_proj(const bf16_t* __restrict__ qkvd,
                                                 const float* __restrict__ A,
                                                 const float* __restrict__ projw,
                                                 const float* __restrict__ x,
                                                 const bf16_t* __restrict__ outconv,
                                                 float* __restrict__ x1) {
  int idx = blockIdx.x * blockDim.x + threadIdx.x;  // exact NB*NP
  int b = idx / NP, p = idx % NP;
  __shared__ float sA[288];
  for (int i = threadIdx.x; i < 288; i += 256) sA[i] = A[b * 288 + i];
  __syncthreads();
  const bf16_t* vb = qkvd + (size_t)(b * 144 + 96) * NP + p;
  float acc[48];
  #pragma unroll
  for (int o = 0; o < 48; ++o) acc[o] = 0.f;
  for (int h = 0; h < 8; ++h) {
    float v6[6];
    #pragma unroll
    for (int d = 0; d < 6; ++d) v6[d] = bf2f(vb[(size_t)(h * 6 + d) * NP]);
    #pragma unroll
    for (int c = 0; c < 6; ++c) {
      float av = 0.f;
      #pragma unroll
      for (int d = 0; d < 6; ++d) av = fmaf(sA[h * 36 + c * 6 + d], v6[d], av);
      const float* wc = projw + h * 6 + c;  // projw[o*48 + (h*6+c)]
      #pragma unroll
      for (int o = 0; o < 48; ++o) acc[o] = fmaf(wc[o * 48], av, acc[o]);
    }
  }
  const float* xb = x + (size_t)b * NC * NP + p;
  const bf16_t* ob = outconv + (size_t)b * NC * NP + p;
  float* x1b = x1 + (size_t)b * NC * NP + p;
  #pragma unroll
  for (int o = 0; o < 48; ++o)
    x1b[(size_t)o * NP] = xb[(size_t)o * NP] + acc[o] + bf2f(ob[(size_t)o * NP]);
}

// ---------------- FF: 3-dilation depthwise + gelu gate (bf16 in/out) ----------------
__global__ __launch_bounds__(256) void k_ffdw(const bf16_t* __restrict__ y,
                                              const float* __restrict__ w1,
                                              const float* __restrict__ w2,
                                              const float* __restrict__ w3,
                                              bf16_t* __restrict__ z) {
  __shared__ float lds[24 * 272];  // 26112 B
  int blk = blockIdx.x;
  int rq = blk & 63;
  int ch = (blk >> 6) % NHID;
  int b = blk / (NHID * 64);
  int yy0 = rq * 4;
  const bf16_t* yb = y + (size_t)(b * 288 + ch) * NP;
  for (int i = threadIdx.x; i < 24 * 68; i += 256) {
    int sr = i / 68, c4 = i % 68;
    int br, iy;
    if (sr < 6)       { br = 0; iy = yy0 + sr - 1; }
    else if (sr < 14) { br = 1; iy = yy0 + sr - 8; }
    else              { br = 2; iy = yy0 + sr - 17; }
    float4 v = make_float4(0.f, 0.f, 0.f, 0.f);
    if ((unsigned)iy < (unsigned)NH && c4 >= 1 && c4 <= 64) {
      ushort4 u = *(const ushort4*)(yb + (size_t)(br * NHID) * NP + iy * NW + (c4 - 1) * 4);
      v = make_float4(bf2f(u.x), bf2f(u.y), bf2f(u.z), bf2f(u.w));
    }
    *(float4*)(&lds[sr * 272 + c4 * 4]) = v;
  }
  __syncthreads();
  int q = threadIdx.x >> 6;
  int quad = threadIdx.x & 63;
  const float* wp1 = w1 + ch * 9;   // wave-uniform -> scalar loads
  const float* wp2 = w2 + ch * 9;
  const float* wp3 = w3 + ch * 9;
  float c1[4] = {0.f, 0.f, 0.f, 0.f};
  float c2[4] = {0.f, 0.f, 0.f, 0.f};
  float c3[4] = {0.f, 0.f, 0.f, 0.f};
  #pragma unroll
  for (int rr = 0; rr < 3; ++rr)
    STENCIL_ROW(0 + q + rr * 1, 1, wp1[rr * 3 + 0], wp1[rr * 3 + 1], wp1[rr * 3 + 2], c1);
  #pragma unroll
  for (int rr = 0; rr < 3; ++rr)
    STENCIL_ROW(6 + q + rr * 2, 2, wp2[rr * 3 + 0], wp2[rr * 3 + 1], wp2[rr * 3 + 2], c2);
  #pragma unroll
  for (int rr = 0; rr < 3; ++rr)
    STENCIL_ROW(14 + q + rr * 3, 3, wp3[rr * 3 + 0], wp3[rr * 3 + 1], wp3[rr * 3 + 2], c3);
  *(ushort4*)(z + (size_t)(b * NHID + ch) * NP + (yy0 + q) * NW + quad * 4) =
      make_ushort4(f2bf(gelu_f(c1[0]) * c2[0] * c3[0]),
                   f2bf(gelu_f(c1[1]) * c2[1] * c3[1]),
                   f2bf(gelu_f(c1[2]) * c2[2] * c3[2]),
                   f2bf(gelu_f(c1[3]) * c2[3] * c3[3]));
}

// ---------------- pout + residual -> d_out (streamed, acc[48], bf16 z) ----------------
__global__ __launch_bounds__(256, 4) void k_pout(const bf16_t* __restrict__ z,
                                                 const float* __restrict__ poutw,
                                                 const float* __restrict__ x1,
                                                 float* __restrict__ outp) {
  int idx = blockIdx.x * blockDim.x + threadIdx.x;  // exact NB*NP
  int b = idx / NP, p = idx % NP;
  const bf16_t* zb = z + (size_t)b * NHID * NP + p;
  float acc[48];
  #pragma unroll
  for (int o = 0; o < 48; ++o) acc[o] = 0.f;
  for (int j = 0; j < 96; ++j) {
    float zv = bf2f(zb[(size_t)j * NP]);
    const float* wc = poutw + j;  // poutw[o*96 + j]
    #pragma unroll
    for (int o = 0; o < 48; ++o) acc[o] = fmaf(wc[o * 96], zv, acc[o]);
  }
  const float* x1b = x1 + (size_t)b * NC * NP + p;
  float* ob = outp + (size_t)b * NC * NP + p;
  #pragma unroll
  for (int o = 0; o < 48; ++o)
    ob[(size_t)o * NP] = x1b[(size_t)o * NP] + acc[o];
}

// ---------------- workspace layout (float offsets; bf16 buffers use half) ----------------
constexpr size_t SZ_QKV = (size_t)NB * 144 * NP;
constexpr size_t SZ_CHW = (size_t)NB * NC * NP;
constexpr size_t OFF_QKV0 = 0;
constexpr size_t OFF_QKVD = OFF_QKV0 + SZ_QKV;         // bf16 buffers: region oversized, fine
constexpr size_t OFF_FCONV = OFF_QKVD + SZ_QKV;
constexpr size_t SZ_FCONV = (size_t)NB * 54 * NP;
constexpr size_t OFF_OUTCONV = OFF_FCONV + SZ_FCONV;
constexpr size_t OFF_X1 = OFF_OUTCONV + SZ_CHW;
constexpr size_t OFF_STATS = OFF_X1 + SZ_CHW;          // repurposed: spart (1024*48 <= NB*NP*2)
constexpr size_t OFF_T1 = OFF_STATS + (size_t)NB * NP * 2;
constexpr size_t OFF_P1 = OFF_T1 + (size_t)NB * NC * 128 * 128;
constexpr size_t OFF_T2 = OFF_P1 + (size_t)NB * NC * 64 * 64;
constexpr size_t OFF_P2 = OFF_T2 + (size_t)NB * NC * 32 * 32;
constexpr size_t OFF_T3 = OFF_P2 + (size_t)NB * NC * 16 * 16;   // reused: SB + scaled weights
constexpr size_t OFF_P3 = OFF_T3 + (size_t)NB * NC * 8 * 8;
constexpr size_t OFF_Q0M = OFF_P3 + (size_t)NB * NC * 4 * 4;
constexpr size_t OFF_NORMS = OFF_Q0M + 576;
constexpr size_t OFF_SPART = OFF_NORMS + 192;          // repurposed: A (576 floats)
constexpr size_t OFF_A = OFF_SPART + (size_t)NB * 64 * 48;

extern "C" void kernel_launch(void* const* d_in, const int* in_sizes, int n_in,
                              void* d_out, int out_size, void* d_ws, size_t ws_size,
                              hipStream_t stream) {
  const float* x     = (const float*)d_in[0];
  const float* ln1w  = (const float*)d_in[1];
  const float* ln1b  = (const float*)d_in[2];
  const float* qkvw  = (const float*)d_in[3];
  const float* qkvdw = (const float*)d_in[4];
  const float* projw = (const float*)d_in[5];
  const float* fcw   = (const float*)d_in[6];
  const float* fcb   = (const float*)d_in[7];
  const float* depw  = (const float*)d_in[8];
  const float* depb  = (const float*)d_in[9];
  const float* l2qw  = (const float*)d_in[10];
  const float* l2qb  = (const float*)d_in[11];
  const float* temp  = (const float*)d_in[12];
  const float* ln2w  = (const float*)d_in[13];
  const float* ln2b  = (const float*)d_in[14];
  const float* pinw  = (const float*)d_in[15];
  const float* dw1   = (const float*)d_in[16];
  const float* dw2   = (const float*)d_in[17];
  const float* dw3   = (const float*)d_in[18];
  const float* poutw = (const float*)d_in[19];
  const float* cvw0  = (const float*)d_in[20];
  const float* cvb0  = (const float*)d_in[21];
  const float* clw0  = (const float*)d_in[22];
  const float* clb0  = (const float*)d_in[23];
  const float* cvw1  = (const float*)d_in[24];
  const float* cvb1  = (const float*)d_in[25];
  const float* clw1  = (const float*)d_in[26];
  const float* clb1  = (const float*)d_in[27];
  const float* cvw2  = (const float*)d_in[28];
  const float* cvb2  = (const float*)d_in[29];
  const float* clw2  = (const float*)d_in[30];
  const float* clb2  = (const float*)d_in[31];

  float* ws = (float*)d_ws;
  bf16_t* qkv0 = (bf16_t*)(ws + OFF_QKV0);
  bf16_t* qkvd = (bf16_t*)(ws + OFF_QKVD);
  bf16_t* fconv = (bf16_t*)(ws + OFF_FCONV);
  bf16_t* outconv = (bf16_t*)(ws + OFF_OUTCONV);
  float* x1 = ws + OFF_X1;
  float* t1 = ws + OFF_T1;
  float* p1 = ws + OFF_P1;
  float* t2 = ws + OFF_T2;
  float* p2 = ws + OFF_P2;
  float* t3 = ws + OFF_T3;
  float* p3 = ws + OFF_P3;
  float* q0m = ws + OFF_Q0M;
  float* spart = ws + OFF_STATS;      // 1024*48 = 49152 floats (fits 262144 region)
  float* A = ws + OFF_SPART;          // 576 floats (fits old spart region)
  float* SB = ws + OFF_T3;            // 864 floats
  float* W1s = ws + OFF_T3 + 864;     // 144*48 = 6912
  float* W2s = ws + OFF_T3 + 864 + 6912;  // 288*48 = 13824 (total 21600 <= 24576 region)
  bf16_t* ybuf = (bf16_t*)(ws + OFF_QKV0);   // reuse qkv0 region (bf16, fits)
  bf16_t* zbuf = (bf16_t*)(ws + OFF_FCONV);  // reuse fconv region (bf16, fits)

  // conv-descriptor branch (ic-chunked LDS convs, 8-wave blocks)
  k_conv_s2_tile<<<512, 512, 0, stream>>>(x, cvw0, cvb0, t1, 256, 256, 128, 128);
  k_lnpool<<<32, 256, 0, stream>>>(t1, clw0, clb0, p1, 128, 128);
  k_conv_s2_tile<<<32, 512, 0, stream>>>(p1, cvw1, cvb1, t2, 64, 64, 32, 32);
  k_lnpool<<<2, 256, 0, stream>>>(t2, clw1, clb1, p2, 32, 32);
  k_conv_s2_tile<<<2, 512, 0, stream>>>(p2, cvw2, cvb2, t3, 16, 16, 8, 8);
  k_lnpool<<<1, 256, 0, stream>>>(t3, clw2, clb2, p3, 8, 8);
  k_head<<<2, 320, 0, stream>>>(p3, l2qw, l2qb, q0m);

  // LN folding setup (after conv branch frees t3 region)
  k_prep<<<4, 256, 0, stream>>>(qkvw, ln1w, ln1b, pinw, ln2w, ln2b, SB, W1s, W2s);

  // attention
  k_chmix_gemm<<<1536, 256, 0, stream>>>(x, W1s, SB, SB + 144, qkv0, 144, 3);
  k_dw144<<<18432, 256, 0, stream>>>(qkv0, qkvdw, qkvd);
  k_gram<<<NB * NHEADS * GSEG, 256, 0, stream>>>(qkvd, spart);
  k_attn<<<2, 256, 0, stream>>>(spart, temp, q0m, A);
  k_fc<<<2048, 384, 0, stream>>>(qkvd, fcw, fcb, fconv);
  k_depconv<<<768, 256, 0, stream>>>(fconv, depw, depb, outconv);
  k_proj<<<512, 256, 0, stream>>>(qkvd, A, projw, x, outconv, x1);

  // feedforward
  k_chmix_gemm<<<3072, 256, 0, stream>>>(x1, W2s, SB + 288, SB + 576, ybuf, 288, 6);
  k_ffdw<<<12288, 256, 0, stream>>>(ybuf, dw1, dw2, dw3, zbuf);
  k_pout<<<512, 256, 0, stream>>>(zbuf, poutw, x1, (float*)d_out);
}

// Round 13
// 488.629 us; speedup vs baseline: 4.5735x; 1.0291x over previous
//
#include <hip/hip_runtime.h>

constexpr int NB = 2;
constexpr int NC = 48;
constexpr int NH = 256;
constexpr int NW = 256;
constexpr int NP = NH * NW;           // 65536
constexpr int NHEADS = 8;
constexpr int NCHD = 6;
constexpr int NHID = 96;
constexpr int GSEG = 64;              // gram segments per (b,h)

typedef unsigned short bf16_t;

__device__ __forceinline__ float bf2f(bf16_t u) {
  union { unsigned int i; float f; } c; c.i = ((unsigned int)u) << 16; return c.f;
}
__device__ __forceinline__ bf16_t f2bf(float f) {
  union { float f; unsigned int i; } c; c.f = f;
  unsigned int r = (c.i + 0x7FFFu + ((c.i >> 16) & 1u)) >> 16;
  return (bf16_t)r;
}
__device__ __forceinline__ void unpack2(unsigned int u, float& a, float& b) {
  union { unsigned int i; float f; } c0, c1;
  c0.i = u << 16; c1.i = u & 0xffff0000u;
  a = c0.f; b = c1.f;
}

__device__ __forceinline__ float gelu_f(float v) {
  return 0.5f * v * (1.0f + erff(v * 0.70710678118654752f));
}

// tap loop over a 12-float window (3x ds_read_b128), compile-time indices.
#define STENCIL_ROW(LROW, D, WVAL0, WVAL1, WVAL2, ACC)                        \
  {                                                                            \
    const float* lp = &lds[(LROW) * 272 + quad * 4];                           \
    float4 va = *(const float4*)lp;                                            \
    float4 vb = *(const float4*)(lp + 4);                                      \
    float4 vc = *(const float4*)(lp + 8);                                      \
    float v[12] = {va.x, va.y, va.z, va.w, vb.x, vb.y, vb.z, vb.w,             \
                   vc.x, vc.y, vc.z, vc.w};                                    \
    _Pragma("unroll") for (int jj = 0; jj < 4; ++jj) {                         \
      ACC[jj] = fmaf(v[jj - (D) + 4], WVAL0, ACC[jj]);                         \
      ACC[jj] = fmaf(v[jj + 4], WVAL1, ACC[jj]);                               \
      ACC[jj] = fmaf(v[jj + (D) + 4], WVAL2, ACC[jj]);                         \
    }                                                                          \
  }

// ---------------- conv-descriptor branch: ic-chunked, 8-wave blocks (6 oc/wave) ----------------
__global__ __launch_bounds__(512) void k_conv_s2_tile(const float* __restrict__ in,
                                                      const float* __restrict__ w,
                                                      const float* __restrict__ bias,
                                                      float* __restrict__ out,
                                                      int IH, int IW, int OH, int OW) {
  __shared__ float lds[16 * 442];  // 16 ic * 17 rows * 26 = 28288 B
  int tilesX = OW >> 3;
  int tilesY = OH >> 3;
  int blk = blockIdx.x;
  int tx = blk % tilesX;
  int t = blk / tilesX;
  int ty = t % tilesY;
  int b = t / tilesY;
  int oy0 = ty * 8, ox0 = tx * 8;
  int iy0 = oy0 * 2 - 1, ix0 = ox0 * 2 - 1;
  const float* inb = in + (size_t)b * NC * IH * IW;

  int lane = threadIdx.x & 63;
  int oy = lane >> 3, ox = lane & 7;
  int ocb = __builtin_amdgcn_readfirstlane((threadIdx.x >> 6) * 6);
  float acc[6];
  #pragma unroll
  for (int j = 0; j < 6; ++j) acc[j] = bias[ocb + j];
  int rbase = oy * 52;  // row 2*oy, stride 26

  for (int chunk = 0; chunk < 3; ++chunk) {
    int icb = chunk * 16;
    for (int i = threadIdx.x; i < 16 * 17 * 17; i += 512) {
      int cc = i % 17;
      int t2 = i / 17;
      int rr = t2 % 17;
      int ic = t2 / 17;
      float v = 0.f;
      int iy = iy0 + rr, ix = ix0 + cc;
      if ((unsigned)iy < (unsigned)IH && (unsigned)ix < (unsigned)IW)
        v = inb[((size_t)(icb + ic) * IH + iy) * IW + ix];
      lds[ic * 442 + rr * 26 + ((cc & 1) ? 13 + (cc >> 1) : (cc >> 1))] = v;
    }
    __syncthreads();

    for (int ic16 = 0; ic16 < 16; ++ic16) {
      const float* base = lds + ic16 * 442 + rbase;
      float e0[3], e1[3], ov[3];
      #pragma unroll
      for (int ky = 0; ky < 3; ++ky) {
        const float* rowp = base + ky * 26;
        e0[ky] = rowp[ox];
        e1[ky] = rowp[ox + 1];
        ov[ky] = rowp[13 + ox];
      }
      const float* wpc = w + (size_t)(ocb * 48 + icb + ic16) * 9;
      #pragma unroll
      for (int j = 0; j < 6; ++j) {
        const float* wp = wpc + (size_t)j * 48 * 9;
        float a = acc[j];
        #pragma unroll
        for (int ky = 0; ky < 3; ++ky) {
          a = fmaf(wp[ky * 3 + 0], e0[ky], a);
          a = fmaf(wp[ky * 3 + 1], ov[ky], a);
          a = fmaf(wp[ky * 3 + 2], e1[ky], a);
        }
        acc[j] = a;
      }
    }
    __syncthreads();
  }

  float* ob = out + (size_t)b * NC * OH * OW;
  #pragma unroll
  for (int j = 0; j < 6; ++j)
    ob[((size_t)(ocb + j) * OH + oy0 + oy) * OW + ox0 + ox] = acc[j];
}

__global__ void k_lnpool(const float* __restrict__ in, const float* __restrict__ lw,
                         const float* __restrict__ lb, float* __restrict__ out,
                         int IH, int IW) {
  int OH = IH >> 1, OW = IW >> 1;
  int idx = blockIdx.x * blockDim.x + threadIdx.x;
  int total = NB * OH * OW;
  if (idx >= total) return;
  int ox = idx % OW;
  int t = idx / OW;
  int oy = t % OH;
  int b = t / OH;
  const float* inb = in + (size_t)b * NC * IH * IW;
  float mu[4], rs[4];
  #pragma unroll
  for (int q = 0; q < 4; ++q) {
    int iy = oy * 2 + (q >> 1), ix = ox * 2 + (q & 1);
    float s = 0.f, ss = 0.f;
    for (int c = 0; c < NC; ++c) {
      float v = inb[((size_t)c * IH + iy) * IW + ix];
      s += v; ss += v * v;
    }
    float m = s * (1.f / NC);
    mu[q] = m;
    rs[q] = rsqrtf(fmaxf(ss * (1.f / NC) - m * m, 0.f) + 1e-5f);
  }
  for (int c = 0; c < NC; ++c) {
    float best = 0.f;  // relu >= 0 so 0 == max of relu'd window
    float wv = lw[c], bv = lb[c];
    #pragma unroll
    for (int q = 0; q < 4; ++q) {
      int iy = oy * 2 + (q >> 1), ix = ox * 2 + (q & 1);
      float v = inb[((size_t)c * IH + iy) * IW + ix];
      v = (v - mu[q]) * rs[q] * wv + bv;
      best = fmaxf(best, fmaxf(v, 0.f));
    }
    out[((size_t)(b * NC + c) * OH + oy) * OW + ox] = best;
  }
}

__global__ void k_head(const float* __restrict__ p3, const float* __restrict__ l2qw,
                       const float* __restrict__ l2qb, float* __restrict__ q0m) {
  __shared__ float xd[NC], q0[NC];
  int b = blockIdx.x, t = threadIdx.x;
  if (t < NC) {
    float s = 0.f;
    for (int i = 0; i < 16; ++i) s += p3[(b * NC + t) * 16 + i];
    xd[t] = gelu_f(s * (1.f / 16.f));
  }
  __syncthreads();
  if (t < NC) {
    float a = l2qb[t];
    for (int c = 0; c < NC; ++c) a += xd[c] * l2qw[t * NC + c];
    q0[t] = a;
  }
  __syncthreads();
  if (t < NHEADS * NCHD * NCHD) {
    int h = t / 36, r = t % 36, c = r / 6, d = r % 6;
    q0m[b * 288 + t] = q0[h * 6 + c] * q0[h * 6 + d];
  }
}

// ---------------- prep: S/B vectors + lnw-prescaled weight copies ----------------
__global__ void k_prep(const float* __restrict__ qkvw, const float* __restrict__ ln1w,
                       const float* __restrict__ ln1b, const float* __restrict__ pinw,
                       const float* __restrict__ ln2w, const float* __restrict__ ln2b,
                       float* __restrict__ SB, float* __restrict__ W1s,
                       float* __restrict__ W2s) {
  int t = blockIdx.x * blockDim.x + threadIdx.x;
  int stride = gridDim.x * blockDim.x;
  if (t < 144) {
    float s = 0.f, bb = 0.f;
    for (int c = 0; c < 48; ++c) {
      float w = qkvw[t * 48 + c];
      s = fmaf(w, ln1w[c], s); bb = fmaf(w, ln1b[c], bb);
    }
    SB[t] = s; SB[144 + t] = bb;
  } else if (t < 144 + 288) {
    int o = t - 144;
    float s = 0.f, bb = 0.f;
    for (int c = 0; c < 48; ++c) {
      float w = pinw[o * 48 + c];
      s = fmaf(w, ln2w[c], s); bb = fmaf(w, ln2b[c], bb);
    }
    SB[288 + o] = s; SB[576 + o] = bb;
  }
  for (int i = t; i < 144 * 48; i += stride) W1s[i] = qkvw[i] * ln1w[i % 48];
  for (int i = t; i < 288 * 48; i += stride) W2s[i] = pinw[i] * ln2w[i % 48];
}

// ---------------- channel-mix GEMM: 128-px tile, ALL output chunks in-block ----------------
// out[o][p] = rstd[p]*(sum_c W'[o][c]*x[c][p] - mu[p]*S[o]) + B[o], W' prescaled by lnw
__global__ __launch_bounds__(256) void k_chmix_gemm(const float* __restrict__ x,
                                                    const float* __restrict__ w,
                                                    const float* __restrict__ S,
                                                    const float* __restrict__ Bc,
                                                    bf16_t* __restrict__ out,
                                                    int nout) {
  __shared__ float lds[48 * 128];  // 24576 B
  __shared__ float smu[128], srstd[128];
  int blk = blockIdx.x;
  int pxt = blk & 511;
  int b = blk >> 9;
  int pxbase = pxt * 128;
  const float* xb = x + (size_t)b * NC * NP + pxbase;
  for (int i = threadIdx.x; i < 48 * 32; i += 256) {
    int k = i >> 5, c4 = i & 31;
    float4 v = *(const float4*)(xb + (size_t)k * NP + c4 * 4);
    *(float4*)&lds[k * 128 + c4 * 4] = v;
  }
  __syncthreads();
  if (threadIdx.x < 128) {
    int px = threadIdx.x;
    float s = 0.f, ss = 0.f;
    #pragma unroll
    for (int k = 0; k < 48; ++k) {
      float v = lds[k * 128 + px];
      s += v; ss = fmaf(v, v, ss);
    }
    float mu = s * (1.f / NC);
    smu[px] = mu;
    srstd[px] = rsqrtf(fmaxf(ss * (1.f / NC) - mu * mu, 0.f) + 1e-5f);
  }
  __syncthreads();
  int lane = threadIdx.x & 63;
  int wid12 = (threadIdx.x >> 6) * 12;
  float mu0 = smu[lane * 2 + 0], rs0 = srstd[lane * 2 + 0];
  float mu1 = smu[lane * 2 + 1], rs1 = srstd[lane * 2 + 1];
  int chunks = nout / 48;
  for (int chunk = 0; chunk < chunks; ++chunk) {
    int obase = __builtin_amdgcn_readfirstlane(chunk * 48 + wid12);
    float acc[12][2];
    #pragma unroll
    for (int j = 0; j < 12; ++j) { acc[j][0] = 0.f; acc[j][1] = 0.f; }
    for (int k = 0; k < 48; ++k) {
      float2 xv = *(const float2*)&lds[k * 128 + lane * 2];
      const float* wr = w + (size_t)obase * 48 + k;
      #pragma unroll
      for (int j = 0; j < 12; ++j) {
        float wv = wr[j * 48];  // scalar load (uniform)
        acc[j][0] = fmaf(wv, xv.x, acc[j][0]);
        acc[j][1] = fmaf(wv, xv.y, acc[j][1]);
      }
    }
    bf16_t* ob = out + (size_t)b * nout * NP + pxbase + lane * 2;
    #pragma unroll
    for (int j = 0; j < 12; ++j) {
      int o = obase + j;
      float Sv = S[o], Bv = Bc[o];
      float r0 = fmaf(rs0, acc[j][0] - mu0 * Sv, Bv);
      float r1 = fmaf(rs1, acc[j][1] - mu1 * Sv, Bv);
      *(ushort2*)(ob + (size_t)o * NP) = make_ushort2(f2bf(r0), f2bf(r1));
    }
  }
}

// ---------------- depthwise 3x3 on 144 channels (4-row stripe, bf16 in/out) ----------------
__global__ __launch_bounds__(256) void k_dw144(const bf16_t* __restrict__ in,
                                               const float* __restrict__ w9,
                                               bf16_t* __restrict__ out) {
  __shared__ float lds[6 * 272];
  int blk = blockIdx.x;
  int rq = blk & 63;
  int ch = (blk >> 6) % 144;
  int b = blk / (144 * 64);
  int yy0 = rq * 4;
  const bf16_t* ib = in + (size_t)(b * 144 + ch) * NP;
  for (int i = threadIdx.x; i < 6 * 68; i += 256) {
    int sr = i / 68, c4 = i % 68;
    int iy = yy0 + sr - 1;
    float4 v = make_float4(0.f, 0.f, 0.f, 0.f);
    if ((unsigned)iy < (unsigned)NH && c4 >= 1 && c4 <= 64) {
      ushort4 u = *(const ushort4*)(ib + iy * NW + (c4 - 1) * 4);
      v = make_float4(bf2f(u.x), bf2f(u.y), bf2f(u.z), bf2f(u.w));
    }
    *(float4*)(&lds[sr * 272 + c4 * 4]) = v;
  }
  __syncthreads();
  int q = threadIdx.x >> 6;
  int quad = threadIdx.x & 63;
  const float* wp = w9 + ch * 9;   // wave-uniform -> scalar loads
  float acc[4] = {0.f, 0.f, 0.f, 0.f};
  #pragma unroll
  for (int rr = 0; rr < 3; ++rr)
    STENCIL_ROW(q + rr, 1, wp[rr * 3 + 0], wp[rr * 3 + 1], wp[rr * 3 + 2], acc);
  *(ushort4*)(out + (size_t)(b * 144 + ch) * NP + (yy0 + q) * NW + quad * 4) =
      make_ushort4(f2bf(acc[0]), f2bf(acc[1]), f2bf(acc[2]), f2bf(acc[3]));
}

// ---------------- per-head Gram (36) + channel ssq (12) partials, 64-seg, packed loads ----------------
__global__ __launch_bounds__(256) void k_gram(const bf16_t* __restrict__ qkvd,
                                              float* __restrict__ spart) {
  int gid = blockIdx.x;  // b*512 + h*64 + seg
  int seg = gid & (GSEG - 1), h = (gid >> 6) & 7, b = gid >> 9;
  const bf16_t* qb = qkvd + (size_t)(b * 144 + h * 6) * NP;
  const bf16_t* kb = qkvd + (size_t)(b * 144 + 48 + h * 6) * NP;
  float acc[48];
  #pragma unroll
  for (int j = 0; j < 48; ++j) acc[j] = 0.f;
  int p0 = seg * (NP / GSEG) + threadIdx.x * 4;
  float qv[6][4], kv[6][4];
  #pragma unroll
  for (int c = 0; c < 6; ++c) {
    ushort4 uq = *(const ushort4*)(qb + (size_t)c * NP + p0);
    qv[c][0] = bf2f(uq.x); qv[c][1] = bf2f(uq.y); qv[c][2] = bf2f(uq.z); qv[c][3] = bf2f(uq.w);
    ushort4 uk = *(const ushort4*)(kb + (size_t)c * NP + p0);
    kv[c][0] = bf2f(uk.x); kv[c][1] = bf2f(uk.y); kv[c][2] = bf2f(uk.z); kv[c][3] = bf2f(uk.w);
  }
  #pragma unroll
  for (int px = 0; px < 4; ++px) {
    #pragma unroll
    for (int c = 0; c < 6; ++c)
      #pragma unroll
      for (int d = 0; d < 6; ++d)
        acc[c * 6 + d] = fmaf(qv[c][px], kv[d][px], acc[c * 6 + d]);
    #pragma unroll
    for (int c = 0; c < 6; ++c) acc[36 + c] = fmaf(qv[c][px], qv[c][px], acc[36 + c]);
    #pragma unroll
    for (int d = 0; d < 6; ++d) acc[42 + d] = fmaf(kv[d][px], kv[d][px], acc[42 + d]);
  }
  int lane = threadIdx.x & 63, wid = threadIdx.x >> 6;
  __shared__ float sr[4 * 48];
  #pragma unroll
  for (int j = 0; j < 48; ++j) {
    float v = acc[j];
    #pragma unroll
    for (int off = 32; off; off >>= 1) v += __shfl_down(v, off, 64);
    if (lane == 0) sr[wid * 48 + j] = v;
  }
  __syncthreads();
  if (threadIdx.x < 48)
    spart[(size_t)gid * 48 + threadIdx.x] =
        sr[threadIdx.x] + sr[48 + threadIdx.x] + sr[96 + threadIdx.x] + sr[144 + threadIdx.x];
}

// ---------------- attention softmax (cooperative 64-seg reduce + softmax) ----------------
__global__ __launch_bounds__(256) void k_attn(const float* __restrict__ spart,
                                              const float* __restrict__ temp,
                                              const float* __restrict__ q0m,
                                              float* __restrict__ A) {
  int b = blockIdx.x;
  __shared__ float tot[8 * 48];
  for (int j = threadIdx.x; j < 384; j += 256) {
    int h = j / 48, v = j % 48;
    const float* base = spart + ((size_t)(b * 8 + h) * GSEG) * 48 + v;
    float s = 0.f;
    for (int seg = 0; seg < GSEG; ++seg) s += base[(size_t)seg * 48];
    tot[j] = s;
  }
  __syncthreads();
  int t = threadIdx.x;
  if (t >= 48) return;
  int h = t / 6, c = t % 6;
  const float* T = &tot[h * 48];
  float nq = fmaxf(sqrtf(T[36 + c]), 1e-12f);
  float tm = temp[h];
  float lg[6];
  #pragma unroll
  for (int d = 0; d < 6; ++d) {
    float nk = fmaxf(sqrtf(T[42 + d]), 1e-12f);
    lg[d] = (T[c * 6 + d] / (nq * nk)) * tm * q0m[b * 288 + h * 36 + c * 6 + d];
  }
  float m = lg[0];
  #pragma unroll
  for (int d = 1; d < 6; ++d) m = fmaxf(m, lg[d]);
  float sum = 0.f;
  #pragma unroll
  for (int d = 0; d < 6; ++d) { lg[d] = expf(lg[d] - m); sum += lg[d]; }
  float inv = 1.f / sum;
  #pragma unroll
  for (int d = 0; d < 6; ++d) A[b * 288 + h * 36 + c * 6 + d] = lg[d] * inv;
}

// ---------------- fc mix over the raw-reshape scramble (bf16 in/out) ----------------
__global__ __launch_bounds__(384) void k_fc(const bf16_t* __restrict__ qkvd,
                                            const float* __restrict__ fcw,
                                            const float* __restrict__ fcb,
                                            bf16_t* __restrict__ fconv) {
  __shared__ float sin_[9216];   // 64 pixels * 144
  __shared__ float sout[3456];   // 54 ch * 64 pixels
  int blk = blockIdx.x;
  int b = blk >> 10, p0 = (blk & 1023) << 6;
  const bf16_t* src = qkvd + (size_t)b * 144 * NP + (size_t)p0 * 144;
  const uint4* src4 = (const uint4*)src;
  for (int i = threadIdx.x; i < 1152; i += 384) {
    uint4 u = src4[i];
    float* d = &sin_[i * 8];
    unpack2(u.x, d[0], d[1]);
    unpack2(u.y, d[2], d[3]);
    unpack2(u.z, d[4], d[5]);
    unpack2(u.w, d[6], d[7]);
  }
  __syncthreads();
  int pl = threadIdx.x / 6, c2 = threadIdx.x % 6;
  float xv[24];
  #pragma unroll
  for (int g = 0; g < 24; ++g) xv[g] = sin_[pl * 144 + g * 6 + c2];
  #pragma unroll
  for (int o = 0; o < 9; ++o) {
    float a = fcb[o];
    #pragma unroll
    for (int g = 0; g < 24; ++g) a += fcw[o * 24 + g] * xv[g];
    sout[(c2 * 9 + o) * 64 + pl] = a;
  }
  __syncthreads();
  for (int i = threadIdx.x; i < 1728; i += 384) {
    int ch = i >> 5, pr = (i & 31) * 2;
    *(ushort2*)(fconv + (size_t)(b * 54 + ch) * NP + p0 + pr) =
        make_ushort2(f2bf(sout[ch * 64 + pr]), f2bf(sout[ch * 64 + pr + 1]));
  }
}

// ---------------- grouped dep conv 54->48 (4-row stripe, bf16 in/out) ----------------
__global__ __launch_bounds__(256) void k_depconv(const bf16_t* __restrict__ fconv,
                                                 const float* __restrict__ dw,
                                                 const float* __restrict__ db,
                                                 bf16_t* __restrict__ outconv) {
  __shared__ float lds[9 * 6 * 272];  // 58752 B
  int blk = blockIdx.x;               // b*6*64 + g*64 + rq
  int rq = blk & 63;
  int g = (blk >> 6) % 6;
  int b = blk / (6 * 64);
  int yy0 = rq * 4;
  const bf16_t* fb = fconv + (size_t)(b * 54 + g * 9) * NP;
  for (int i = threadIdx.x; i < 9 * 6 * 68; i += 256) {
    int j = i / 408;
    int rem = i % 408;
    int sr = rem / 68, c4 = rem % 68;
    int iy = yy0 + sr - 1;
    float4 v = make_float4(0.f, 0.f, 0.f, 0.f);
    if ((unsigned)iy < (unsigned)NH && c4 >= 1 && c4 <= 64) {
      ushort4 u = *(const ushort4*)(fb + (size_t)j * NP + iy * NW + (c4 - 1) * 4);
      v = make_float4(bf2f(u.x), bf2f(u.y), bf2f(u.z), bf2f(u.w));
    }
    *(float4*)(&lds[(j * 6 + sr) * 272 + c4 * 4]) = v;
  }
  __syncthreads();
  int q = threadIdx.x >> 6;
  int quad = threadIdx.x & 63;
  float acc[8][4];
  #pragma unroll
  for (int o = 0; o < 8; ++o) {
    float bv = db[g * 8 + o];
    #pragma unroll
    for (int jj = 0; jj < 4; ++jj) acc[o][jj] = bv;
  }
  const float* wg = dw + (size_t)(g * 8) * 81;
  #pragma unroll
  for (int j = 0; j < 9; ++j) {
    #pragma unroll
    for (int rr = 0; rr < 3; ++rr) {
      const float* lp = &lds[((j * 6) + q + rr) * 272 + quad * 4];
      float4 va = *(const float4*)lp;
      float4 vb = *(const float4*)(lp + 4);
      float4 vc = *(const float4*)(lp + 8);
      float v[12] = {va.x, va.y, va.z, va.w, vb.x, vb.y, vb.z, vb.w,
                     vc.x, vc.y, vc.z, vc.w};
      #pragma unroll
      for (int dxi = 0; dxi < 3; ++dxi) {
        int wi = j * 9 + rr * 3 + dxi;
        #pragma unroll
        for (int o = 0; o < 8; ++o) {
          float wv = wg[o * 81 + wi];
          #pragma unroll
          for (int jj = 0; jj < 4; ++jj)
            acc[o][jj] = fmaf(v[jj + dxi + 3], wv, acc[o][jj]);
        }
      }
    }
  }
  bf16_t* ob = outconv + ((size_t)(b * NC + g * 8) * NH + yy0 + q) * NW + quad * 4;
  #pragma unroll
  for (int o = 0; o < 8; ++o)
    *(ushort4*)(ob + (size_t)o * NP) =
        make_ushort4(f2bf(acc[o][0]), f2bf(acc[o][1]), f2bf(acc[o][2]), f2bf(acc[o][3]));
}

// ---------------- fused attn@V + proj + out_conv + residual ----------------
__global__ __launch_bounds__(256, 4) void k_proj(const bf16_t* __restrict__ qkvd,
                                                 const float* __restrict__ A,
                                                 const float* __restrict__ projw,
                                                 const float* __restrict__ x,
                                                 const bf16_t* __restrict__ outconv,
                                                 float* __restrict__ x1) {
  int idx = blockIdx.x * blockDim.x + threadIdx.x;  // exact NB*NP
  int b = idx / NP, p = idx % NP;
  __shared__ float sA[288];
  for (int i = threadIdx.x; i < 288; i += 256) sA[i] = A[b * 288 + i];
  __syncthreads();
  const bf16_t* vb = qkvd + (size_t)(b * 144 + 96) * NP + p;
  float acc[48];
  #pragma unroll
  for (int o = 0; o < 48; ++o) acc[o] = 0.f;
  for (int h = 0; h < 8; ++h) {
    float v6[6];
    #pragma unroll
    for (int d = 0; d < 6; ++d) v6[d] = bf2f(vb[(size_t)(h * 6 + d) * NP]);
    #pragma unroll
    for (int c = 0; c < 6; ++c) {
      float av = 0.f;
      #pragma unroll
      for (int d = 0; d < 6; ++d) av = fmaf(sA[h * 36 + c * 6 + d], v6[d], av);
      const float* wc = projw + h * 6 + c;  // projw[o*48 + (h*6+c)]
      #pragma unroll
      for (int o = 0; o < 48; ++o) acc[o] = fmaf(wc[o * 48], av, acc[o]);
    }
  }
  const float* xb = x + (size_t)b * NC * NP + p;
  const bf16_t* ob = outconv + (size_t)b * NC * NP + p;
  float* x1b = x1 + (size_t)b * NC * NP + p;
  #pragma unroll
  for (int o = 0; o < 48; ++o)
    x1b[(size_t)o * NP] = xb[(size_t)o * NP] + acc[o] + bf2f(ob[(size_t)o * NP]);
}

// ---------------- FF: 3-dilation depthwise + gelu gate (bf16 in/out) ----------------
__global__ __launch_bounds__(256) void k_ffdw(const bf16_t* __restrict__ y,
                                              const float* __restrict__ w1,
                                              const float* __restrict__ w2,
                                              const float* __restrict__ w3,
                                              bf16_t* __restrict__ z) {
  __shared__ float lds[24 * 272];  // 26112 B
  int blk = blockIdx.x;
  int rq = blk & 63;
  int ch = (blk >> 6) % NHID;
  int b = blk / (NHID * 64);
  int yy0 = rq * 4;
  const bf16_t* yb = y + (size_t)(b * 288 + ch) * NP;
  for (int i = threadIdx.x; i < 24 * 68; i += 256) {
    int sr = i / 68, c4 = i % 68;
    int br, iy;
    if (sr < 6)       { br = 0; iy = yy0 + sr - 1; }
    else if (sr < 14) { br = 1; iy = yy0 + sr - 8; }
    else              { br = 2; iy = yy0 + sr - 17; }
    float4 v = make_float4(0.f, 0.f, 0.f, 0.f);
    if ((unsigned)iy < (unsigned)NH && c4 >= 1 && c4 <= 64) {
      ushort4 u = *(const ushort4*)(yb + (size_t)(br * NHID) * NP + iy * NW + (c4 - 1) * 4);
      v = make_float4(bf2f(u.x), bf2f(u.y), bf2f(u.z), bf2f(u.w));
    }
    *(float4*)(&lds[sr * 272 + c4 * 4]) = v;
  }
  __syncthreads();
  int q = threadIdx.x >> 6;
  int quad = threadIdx.x & 63;
  const float* wp1 = w1 + ch * 9;   // wave-uniform -> scalar loads
  const float* wp2 = w2 + ch * 9;
  const float* wp3 = w3 + ch * 9;
  float c1[4] = {0.f, 0.f, 0.f, 0.f};
  float c2[4] = {0.f, 0.f, 0.f, 0.f};
  float c3[4] = {0.f, 0.f, 0.f, 0.f};
  #pragma unroll
  for (int rr = 0; rr < 3; ++rr)
    STENCIL_ROW(0 + q + rr * 1, 1, wp1[rr * 3 + 0], wp1[rr * 3 + 1], wp1[rr * 3 + 2], c1);
  #pragma unroll
  for (int rr = 0; rr < 3; ++rr)
    STENCIL_ROW(6 + q + rr * 2, 2, wp2[rr * 3 + 0], wp2[rr * 3 + 1], wp2[rr * 3 + 2], c2);
  #pragma unroll
  for (int rr = 0; rr < 3; ++rr)
    STENCIL_ROW(14 + q + rr * 3, 3, wp3[rr * 3 + 0], wp3[rr * 3 + 1], wp3[rr * 3 + 2], c3);
  *(ushort4*)(z + (size_t)(b * NHID + ch) * NP + (yy0 + q) * NW + quad * 4) =
      make_ushort4(f2bf(gelu_f(c1[0]) * c2[0] * c3[0]),
                   f2bf(gelu_f(c1[1]) * c2[1] * c3[1]),
                   f2bf(gelu_f(c1[2]) * c2[2] * c3[2]),
                   f2bf(gelu_f(c1[3]) * c2[3] * c3[3]));
}

// ---------------- pout + residual -> d_out (streamed, acc[48], bf16 z) ----------------
__global__ __launch_bounds__(256, 4) void k_pout(const bf16_t* __restrict__ z,
                                                 const float* __restrict__ poutw,
                                                 const float* __restrict__ x1,
                                                 float* __restrict__ outp) {
  int idx = blockIdx.x * blockDim.x + threadIdx.x;  // exact NB*NP
  int b = idx / NP, p = idx % NP;
  const bf16_t* zb = z + (size_t)b * NHID * NP + p;
  float acc[48];
  #pragma unroll
  for (int o = 0; o < 48; ++o) acc[o] = 0.f;
  for (int j = 0; j < 96; ++j) {
    float zv = bf2f(zb[(size_t)j * NP]);
    const float* wc = poutw + j;  // poutw[o*96 + j]
    #pragma unroll
    for (int o = 0; o < 48; ++o) acc[o] = fmaf(wc[o * 96], zv, acc[o]);
  }
  const float* x1b = x1 + (size_t)b * NC * NP + p;
  float* ob = outp + (size_t)b * NC * NP + p;
  #pragma unroll
  for (int o = 0; o < 48; ++o)
    ob[(size_t)o * NP] = x1b[(size_t)o * NP] + acc[o];
}

// ---------------- workspace layout (float offsets; bf16 buffers use half) ----------------
constexpr size_t SZ_QKV = (size_t)NB * 144 * NP;
constexpr size_t SZ_CHW = (size_t)NB * NC * NP;
constexpr size_t OFF_QKV0 = 0;
constexpr size_t OFF_QKVD = OFF_QKV0 + SZ_QKV;         // bf16 buffers: region oversized, fine
constexpr size_t OFF_FCONV = OFF_QKVD + SZ_QKV;
constexpr size_t SZ_FCONV = (size_t)NB * 54 * NP;
constexpr size_t OFF_OUTCONV = OFF_FCONV + SZ_FCONV;
constexpr size_t OFF_X1 = OFF_OUTCONV + SZ_CHW;
constexpr size_t OFF_STATS = OFF_X1 + SZ_CHW;          // repurposed: spart (1024*48 <= NB*NP*2)
constexpr size_t OFF_T1 = OFF_STATS + (size_t)NB * NP * 2;
constexpr size_t OFF_P1 = OFF_T1 + (size_t)NB * NC * 128 * 128;
constexpr size_t OFF_T2 = OFF_P1 + (size_t)NB * NC * 64 * 64;
constexpr size_t OFF_P2 = OFF_T2 + (size_t)NB * NC * 32 * 32;
constexpr size_t OFF_T3 = OFF_P2 + (size_t)NB * NC * 16 * 16;   // reused: SB + scaled weights
constexpr size_t OFF_P3 = OFF_T3 + (size_t)NB * NC * 8 * 8;
constexpr size_t OFF_Q0M = OFF_P3 + (size_t)NB * NC * 4 * 4;
constexpr size_t OFF_NORMS = OFF_Q0M + 576;
constexpr size_t OFF_SPART = OFF_NORMS + 192;          // repurposed: A (576 floats)
constexpr size_t OFF_A = OFF_SPART + (size_t)NB * 64 * 48;

extern "C" void kernel_launch(void* const* d_in, const int* in_sizes, int n_in,
                              void* d_out, int out_size, void* d_ws, size_t ws_size,
                              hipStream_t stream) {
  const float* x     = (const float*)d_in[0];
  const float* ln1w  = (const float*)d_in[1];
  const float* ln1b  = (const float*)d_in[2];
  const float* qkvw  = (const float*)d_in[3];
  const float* qkvdw = (const float*)d_in[4];
  const float* projw = (const float*)d_in[5];
  const float* fcw   = (const float*)d_in[6];
  const float* fcb   = (const float*)d_in[7];
  const float* depw  = (const float*)d_in[8];
  const float* depb  = (const float*)d_in[9];
  const float* l2qw  = (const float*)d_in[10];
  const float* l2qb  = (const float*)d_in[11];
  const float* temp  = (const float*)d_in[12];
  const float* ln2w  = (const float*)d_in[13];
  const float* ln2b  = (const float*)d_in[14];
  const float* pinw  = (const float*)d_in[15];
  const float* dw1   = (const float*)d_in[16];
  const float* dw2   = (const float*)d_in[17];
  const float* dw3   = (const float*)d_in[18];
  const float* poutw = (const float*)d_in[19];
  const float* cvw0  = (const float*)d_in[20];
  const float* cvb0  = (const float*)d_in[21];
  const float* clw0  = (const float*)d_in[22];
  const float* clb0  = (const float*)d_in[23];
  const float* cvw1  = (const float*)d_in[24];
  const float* cvb1  = (const float*)d_in[25];
  const float* clw1  = (const float*)d_in[26];
  const float* clb1  = (const float*)d_in[27];
  const float* cvw2  = (const float*)d_in[28];
  const float* cvb2  = (const float*)d_in[29];
  const float* clw2  = (const float*)d_in[30];
  const float* clb2  = (const float*)d_in[31];

  float* ws = (float*)d_ws;
  bf16_t* qkv0 = (bf16_t*)(ws + OFF_QKV0);
  bf16_t* qkvd = (bf16_t*)(ws + OFF_QKVD);
  bf16_t* fconv = (bf16_t*)(ws + OFF_FCONV);
  bf16_t* outconv = (bf16_t*)(ws + OFF_OUTCONV);
  float* x1 = ws + OFF_X1;
  float* t1 = ws + OFF_T1;
  float* p1 = ws + OFF_P1;
  float* t2 = ws + OFF_T2;
  float* p2 = ws + OFF_P2;
  float* t3 = ws + OFF_T3;
  float* p3 = ws + OFF_P3;
  float* q0m = ws + OFF_Q0M;
  float* spart = ws + OFF_STATS;      // 1024*48 = 49152 floats (fits 262144 region)
  float* A = ws + OFF_SPART;          // 576 floats (fits old spart region)
  float* SB = ws + OFF_T3;            // 864 floats
  float* W1s = ws + OFF_T3 + 864;     // 144*48 = 6912
  float* W2s = ws + OFF_T3 + 864 + 6912;  // 288*48 = 13824 (total 21600 <= 24576 region)
  bf16_t* ybuf = (bf16_t*)(ws + OFF_QKV0);   // reuse qkv0 region (bf16, fits)
  bf16_t* zbuf = (bf16_t*)(ws + OFF_FCONV);  // reuse fconv region (bf16, fits)

  // conv-descriptor branch (ic-chunked LDS convs, 8-wave blocks)
  k_conv_s2_tile<<<512, 512, 0, stream>>>(x, cvw0, cvb0, t1, 256, 256, 128, 128);
  k_lnpool<<<32, 256, 0, stream>>>(t1, clw0, clb0, p1, 128, 128);
  k_conv_s2_tile<<<32, 512, 0, stream>>>(p1, cvw1, cvb1, t2, 64, 64, 32, 32);
  k_lnpool<<<2, 256, 0, stream>>>(t2, clw1, clb1, p2, 32, 32);
  k_conv_s2_tile<<<2, 512, 0, stream>>>(p2, cvw2, cvb2, t3, 16, 16, 8, 8);
  k_lnpool<<<1, 256, 0, stream>>>(t3, clw2, clb2, p3, 8, 8);
  k_head<<<2, 320, 0, stream>>>(p3, l2qw, l2qb, q0m);

  // LN folding setup (after conv branch frees t3 region)
  k_prep<<<4, 256, 0, stream>>>(qkvw, ln1w, ln1b, pinw, ln2w, ln2b, SB, W1s, W2s);

  // attention
  k_chmix_gemm<<<NB * 512, 256, 0, stream>>>(x, W1s, SB, SB + 144, qkv0, 144);
  k_dw144<<<18432, 256, 0, stream>>>(qkv0, qkvdw, qkvd);
  k_gram<<<NB * NHEADS * GSEG, 256, 0, stream>>>(qkvd, spart);
  k_attn<<<2, 256, 0, stream>>>(spart, temp, q0m, A);
  k_fc<<<2048, 384, 0, stream>>>(qkvd, fcw, fcb, fconv);
  k_depconv<<<768, 256, 0, stream>>>(fconv, depw, depb, outconv);
  k_proj<<<512, 256, 0, stream>>>(qkvd, A, projw, x, outconv, x1);

  // feedforward
  k_chmix_gemm<<<NB * 512, 256, 0, stream>>>(x1, W2s, SB + 288, SB + 576, ybuf, 288);
  k_ffdw<<<12288, 256, 0, stream>>>(ybuf, dw1, dw2, dw3, zbuf);
  k_pout<<<512, 256, 0, stream>>>(zbuf, poutw, x1, (float*)d_out);
}